// Round 8
// baseline (1705.568 us; speedup 1.0000x reference)
//
#include <hip/hip_runtime.h>

#define DIMC 2240
#define STOK 3584
#define ENCT 300
#define NH   20
#define HDIM 112
#define HID1 6720
#define HID2 13440
#define DD   (2240*2240)
#define SD   (3584*2240)

typedef short bf16x8 __attribute__((ext_vector_type(8)));   // guide-verified operand type
typedef float f32x4  __attribute__((ext_vector_type(4)));

__device__ __forceinline__ unsigned short f2bf(float f){
  unsigned int u = __float_as_uint(f);
  u += 0x7fffu + ((u >> 16) & 1u);          // RNE
  return (unsigned short)(u >> 16);
}
__device__ __forceinline__ float bf2f(unsigned short h){
  return __uint_as_float(((unsigned int)h) << 16);
}
__device__ __forceinline__ void gl_lds16(const unsigned short* g, unsigned short* l){
  __builtin_amdgcn_global_load_lds(
      (const __attribute__((address_space(1))) unsigned int*)(const void*)g,
      (__attribute__((address_space(3))) unsigned int*)(void*)l, 16, 0, 0);
}

// ---------------- fp32 -> bf16 convert (flat) ----------------
__global__ void cvt_k(const float4* __restrict__ src, ushort4* __restrict__ dst, int n4){
  int i = blockIdx.x*256 + threadIdx.x;
  if (i < n4){
    float4 v = src[i];
    ushort4 o; o.x = f2bf(v.x); o.y = f2bf(v.y); o.z = f2bf(v.z); o.w = f2bf(v.w);
    dst[i] = o;
  }
}

// ------- fp32 (rows x cols slice) -> bf16 TRANSPOSED [ncPad][rows], zero-padded -------
__global__ __launch_bounds__(256) void cvt_t_k(const float* __restrict__ src,
    unsigned short* __restrict__ dst, int rows, int ldsrc, int c0, int nc){
  __shared__ float tile[32][33];
  const int tx = threadIdx.x & 31, ty = threadIdx.x >> 5;   // ty 0..7
  const int colBase = blockIdx.x*32;
  #pragma unroll
  for (int i = 0; i < 4; ++i){
    int rr = blockIdx.y*32 + ty + i*8;
    int cc = colBase + tx;
    tile[ty + i*8][tx] = (cc < nc) ? src[(size_t)rr*ldsrc + c0 + cc] : 0.f;
  }
  __syncthreads();
  #pragma unroll
  for (int i = 0; i < 4; ++i){
    int n = colBase + ty + i*8;          // < ncPad by grid
    int k = blockIdx.y*32 + tx;
    dst[(size_t)n*rows + k] = f2bf(tile[tx][ty + i*8]);
  }
}

// ---------------- pack up to 3 biases into [nslots][2304] (zero pad) ----------------
__global__ void pack3_k(float* __restrict__ dst, const float* __restrict__ b0,
    const float* __restrict__ b1, const float* __restrict__ b2, int nslots){
  int i = blockIdx.x*256 + threadIdx.x;
  if (i >= nslots*2304) return;
  int slot = i / 2304, d = i - slot*2304;
  const float* src = (slot == 0) ? b0 : ((slot == 1) ? b1 : b2);
  dst[i] = (d < 2240) ? src[d] : 0.f;
}

// ---------------- mods = scale_shift_table + timestep ----------------
__global__ void mods_k(const float* __restrict__ sst, const float* __restrict__ ts, float* __restrict__ mods){
  int i = blockIdx.x*256 + threadIdx.x;
  if (i < 6*DIMC) mods[i] = sst[i] + ts[i];
}

// ---------------- LayerNorm * (1+sc) + sh -> bf16 ----------------
__global__ __launch_bounds__(256) void ln_mod_k(const float* __restrict__ x,
    const float* __restrict__ mods, int shj, int scj, unsigned short* __restrict__ out)
{
  const int s = blockIdx.x;
  const float* row = x + (size_t)s*DIMC;
  const float* sh = mods + shj*DIMC;
  const float* sc = mods + scj*DIMC;
  float sum = 0.f, sq = 0.f;
  for (int d = threadIdx.x; d < DIMC; d += 256){ float v = row[d]; sum += v; sq += v*v; }
  #pragma unroll
  for (int o = 32; o; o >>= 1){ sum += __shfl_down(sum, o); sq += __shfl_down(sq, o); }
  __shared__ float sA[4], sB[4];
  int w = threadIdx.x >> 6, l = threadIdx.x & 63;
  if (!l){ sA[w] = sum; sB[w] = sq; }
  __syncthreads();
  sum = sA[0]+sA[1]+sA[2]+sA[3];
  sq  = sB[0]+sB[1]+sB[2]+sB[3];
  float mean = sum * (1.f/DIMC);
  float rs = rsqrtf(sq*(1.f/DIMC) - mean*mean + 1e-6f);
  unsigned short* orow = out + (size_t)s*DIMC;
  for (int d = threadIdx.x; d < DIMC; d += 256){
    float v = (row[d]-mean)*rs*(1.f + sc[d]) + sh[d];
    orow[d] = f2bf(v);
  }
}

// ---------------- RMS on bf16 rows (optional ReLU / RoPE) ----------------
template<int RELU, int ROPE>
__global__ __launch_bounds__(256) void rms_bf_k(unsigned short* __restrict__ x, const float* __restrict__ nw,
    const float* __restrict__ cosb, const float* __restrict__ sinb, unsigned short* __restrict__ xr)
{
  const int s = blockIdx.x;
  unsigned short* row = x + (size_t)s*DIMC;
  float sq = 0.f;
  for (int d = threadIdx.x; d < DIMC; d += 256){ float v = bf2f(row[d]); sq += v*v; }
  #pragma unroll
  for (int o = 32; o; o >>= 1) sq += __shfl_down(sq, o);
  __shared__ float sB[4];
  int w = threadIdx.x >> 6, l = threadIdx.x & 63;
  if (!l) sB[w] = sq;
  __syncthreads();
  sq = sB[0]+sB[1]+sB[2]+sB[3];
  float rs = rsqrtf(sq*(1.f/DIMC) + 1e-5f);
  if constexpr (!ROPE){
    for (int d = threadIdx.x; d < DIMC; d += 256){
      float v = bf2f(row[d])*rs*nw[d];
      if (RELU) v = fmaxf(v, 0.f);
      row[d] = f2bf(v);
    }
  } else {
    for (int p = threadIdx.x; p < DIMC/2; p += 256){
      int d0 = 2*p, d1 = d0+1;
      float v0 = bf2f(row[d0])*rs*nw[d0];
      float v1 = bf2f(row[d1])*rs*nw[d1];
      if (RELU){ v0 = fmaxf(v0,0.f); v1 = fmaxf(v1,0.f); }
      row[d0] = f2bf(v0); row[d1] = f2bf(v1);
      int j0 = d0 % HDIM;                       // pairs stay within a head (112 even)
      float c  = cosb[(size_t)s*HDIM + j0];     // cos[0::2]
      float sn = sinb[(size_t)s*HDIM + j0 + 1]; // sin[1::2]
      xr[(size_t)s*DIMC + d0] = f2bf(v0*c - v1*sn);
      xr[(size_t)s*DIMC + d1] = f2bf(v0*sn + v1*c);
    }
  }
}

// ------- bf16 MFMA GEMM, 4-deep counted-vmcnt pipeline ------------------------------
// C = A(MxK) @ Bt^T, Bt is [Npad][K] (N-major). BK=32, 4 LDS buffers (64 KB total).
// Per K-tile: vmcnt(8) -> raw barrier -> stage tile u+3 -> ds_read -> 16 MFMA.
// Paired-row LDS layout (two 64B rows per 128B line), chunk-XOR swizzle both sides.
// K % 32 == 0 required; Bt zero-padded to Npad = gridDim.x*128 rows. PW | gridDim.x.
// EPI: 0 Cf=acc+bias | 1 Cb=bf16(silu(acc+bias)) | 2 Cb=bf16(acc+bias)
//      3 u=res+gate*(acc+bias); Cf=u; Cb=bf16(u) | 4 Cf=res+acc+bias | 5 Cf+=acc
//      6 slot-split: slot=col/2304, d=col%2304; if d<2240: Cb[slot*ldc + row*2240 + d]
template<int EPI>
__global__ __launch_bounds__(256) void gemm_bt(
  const unsigned short* __restrict__ A, const unsigned short* __restrict__ Bt,
  const float* __restrict__ bias, float* __restrict__ Cf, unsigned short* __restrict__ Cb,
  const float* __restrict__ res, const float* __restrict__ gate,
  int M, int N, int K, int ldc, int PW)
{
  __shared__ __align__(16) unsigned short Al[4*4096];   // 4 bufs x 128rows x 32cols
  __shared__ __align__(16) unsigned short Bl[4*4096];
  const int gx = gridDim.x, gy = gridDim.y;
  const int nwg = gx*gy;
  const int orig = blockIdx.y*gx + blockIdx.x;
  // bijective XCD-aware remap (m204)
  const int qq = nwg >> 3, rr = nwg & 7;
  const int xcd = orig & 7, li = orig >> 3;
  const int wg = (xcd < rr ? xcd*(qq+1) : rr*(qq+1) + (xcd-rr)*qq) + li;
  // N-panel rasterization: panel of PW n-tiles covers all gy m-rows before advancing
  const int ppw = gy*PW;
  const int panel = wg / ppw, rm = wg - panel*ppw;
  const int mrow = rm / PW;
  const int m0 = mrow*128;
  const int n0 = (panel*PW + (rm - mrow*PW))*128;

  const int t = threadIdx.x, lane = t & 63, w = t >> 6;
  const int wr = w >> 1, wc = w & 1;
  const int l16 = lane & 15, lk = lane >> 4;

  // staging geometry (paired-row layout, pre-swizzled global chunk)
  const int lr  = lane >> 3;            // line within wave's 8-line chunk
  const int hl  = (lane >> 2) & 1;      // row within line
  const int cg  = (lane & 3) ^ (lr & 3);// global chunk (inverse of read XOR)
  const unsigned short* Asrc[2];
  const unsigned short* Bsrc[2];
  #pragma unroll
  for (int i = 0; i < 2; ++i){
    int ar = m0 + i*64 + w*16 + lr*2 + hl;
    int br = n0 + i*64 + w*16 + lr*2 + hl;
    Asrc[i] = A  + (size_t)min(ar, M-1)*K + cg*8;
    Bsrc[i] = Bt + (size_t)br*K + cg*8;
  }
  const int ldsOff = w*512;             // + lane*8 implicit (gl_lds lane scatter)

  const int NT = K >> 5;                // K-tiles of 32
  // prologue: stage tiles 0,1,2
  #pragma unroll
  for (int p = 0; p < 3; ++p){
    #pragma unroll
    for (int i = 0; i < 2; ++i) gl_lds16(Asrc[i] + p*32, Al + p*4096 + i*2048 + ldsOff);
    #pragma unroll
    for (int i = 0; i < 2; ++i) gl_lds16(Bsrc[i] + p*32, Bl + p*4096 + i*2048 + ldsOff);
  }

  f32x4 acc[4][4] = {};
  for (int u = 0; u < NT; ++u){
    asm volatile("s_waitcnt vmcnt(8)" ::: "memory");  // tile u's 12-8=4.. oldest 4 landed
    __builtin_amdgcn_s_barrier();                     // cross-wave: everyone's tile-u landed
    __builtin_amdgcn_sched_barrier(0);                // pin loads/stages below the barrier
    {                                                  // stage tile u+3 (dead buffer)
      int us = u + 3; if (us > NT-1) us = NT-1;        // tail: dummy re-stage keeps counts
      int bs = (u + 3) & 3;
      #pragma unroll
      for (int i = 0; i < 2; ++i) gl_lds16(Asrc[i] + us*32, Al + bs*4096 + i*2048 + ldsOff);
      #pragma unroll
      for (int i = 0; i < 2; ++i) gl_lds16(Bsrc[i] + us*32, Bl + bs*4096 + i*2048 + ldsOff);
    }
    const unsigned short* Ab = Al + (u & 3)*4096;
    const unsigned short* Bb = Bl + (u & 3)*4096;
    bf16x8 af[4], bfr[4];
    #pragma unroll
    for (int mt = 0; mt < 4; ++mt){
      int r = wr*64 + mt*16 + l16;
      af[mt] = *reinterpret_cast<const bf16x8*>(Ab + (r>>1)*64 + (r&1)*32 + ((lk ^ ((r>>1)&3))<<3));
    }
    #pragma unroll
    for (int nt = 0; nt < 4; ++nt){
      int r = wc*64 + nt*16 + l16;
      bfr[nt] = *reinterpret_cast<const bf16x8*>(Bb + (r>>1)*64 + (r&1)*32 + ((lk ^ ((r>>1)&3))<<3));
    }
    __builtin_amdgcn_s_setprio(1);
    #pragma unroll
    for (int mt = 0; mt < 4; ++mt)
      #pragma unroll
      for (int nt = 0; nt < 4; ++nt)
        acc[mt][nt] = __builtin_amdgcn_mfma_f32_16x16x32_bf16(af[mt], bfr[nt], acc[mt][nt], 0, 0, 0);
    __builtin_amdgcn_s_setprio(0);
  }

  const int rb = m0 + wr*64 + lk*4;   // C/D: col = lane&15, row = (lane>>4)*4 + reg
  const int cb = n0 + wc*64 + l16;
  #pragma unroll
  for (int m = 0; m < 4; ++m){
    #pragma unroll
    for (int r = 0; r < 4; ++r){
      int row = rb + m*16 + r;
      if (row >= M) continue;
      #pragma unroll
      for (int n = 0; n < 4; ++n){
        int col = cb + n*16;
        if (col >= N) continue;
        float v = acc[m][n][r];
        float bv = bias ? bias[col] : 0.f;
        if constexpr (EPI == 6){
          int slot = col / 2304;
          int d = col - slot*2304;
          if (d < 2240)
            Cb[(size_t)slot*ldc + (size_t)row*2240 + d] = f2bf(v + bv);
        } else {
          size_t idx = (size_t)row*ldc + col;
          if constexpr (EPI == 0){ Cf[idx] = v + bv; }
          else if constexpr (EPI == 1){ float u = v + bv; Cb[idx] = f2bf(u / (1.f + __expf(-u))); }
          else if constexpr (EPI == 2){ Cb[idx] = f2bf(v + bv); }
          else if constexpr (EPI == 3){ float u = res[idx] + gate[col]*(v + bv); Cf[idx] = u; Cb[idx] = f2bf(u); }
          else if constexpr (EPI == 4){ Cf[idx] = res[idx] + v + bv; }
          else { Cf[idx] += v; }
        }
      }
    }
  }
}

// ---------------- linear attention helpers ----------------
__global__ void colsum_k(const unsigned short* __restrict__ k, float* __restrict__ kpart){
  int d = blockIdx.x*256 + threadIdx.x;
  if (d >= DIMC) return;
  int ch = blockIdx.y, s0 = ch*128;
  float acc = 0.f;
  for (int s = s0; s < s0+128; ++s) acc += bf2f(k[(size_t)s*DIMC + d]);
  kpart[(size_t)ch*DIMC + d] = acc;
}
__global__ void ksumred_k(const float* __restrict__ kpart, float* __restrict__ ksum){
  int d = blockIdx.x*256 + threadIdx.x;
  if (d >= DIMC) return;
  float a = 0.f;
  for (int c = 0; c < 28; ++c) a += kpart[(size_t)c*DIMC + d];
  ksum[d] = a;
}
__global__ __launch_bounds__(256) void denom_k(const unsigned short* __restrict__ q,
    const float* __restrict__ ksum, float* __restrict__ denom)
{
  int s = blockIdx.x; int w = threadIdx.x >> 6, l = threadIdx.x & 63;
  for (int h = w; h < NH; h += 4){
    const unsigned short* qb = q + (size_t)s*DIMC + h*HDIM;
    const float* kb = ksum + h*HDIM;
    float v = bf2f(qb[l])*kb[l];
    if (l < 48) v += bf2f(qb[64+l])*kb[64+l];
    #pragma unroll
    for (int o = 32; o; o >>= 1) v += __shfl_down(v, o);
    if (!l) denom[s*NH + h] = v + 1e-15f;
  }
}

// -------- MFMA scores: part[ch][h][e][d] = sum_{s in 128-chunk} V[s,h,e]*Kr[s,h,d] -----
#define SLSC 136
__device__ __forceinline__ int sc_idx(int e, int s){
  return e*SLSC + (s ^ (((e >> 3) & 7) << 3));
}
__global__ __launch_bounds__(256) void scores_k(const unsigned short* __restrict__ v,
    const unsigned short* __restrict__ kr, float* __restrict__ part)
{
  const int h = blockIdx.x, ch = blockIdx.y;
  __shared__ __align__(16) unsigned short Vt[112*SLSC];
  __shared__ __align__(16) unsigned short Kt[112*SLSC];
  const int t = threadIdx.x, lane = t & 63, w = t >> 6;
  const int l16 = lane & 15, lk = lane >> 4;
  const int sbase = ch*128;

  for (int p = t; p < 1792; p += 256){       // 128 tokens x 14 dim-octets
    int s = p / 14, oc = (p % 14) * 8;
    bf16x8 vv = *reinterpret_cast<const bf16x8*>(v  + (size_t)(sbase+s)*DIMC + h*HDIM + oc);
    bf16x8 kk = *reinterpret_cast<const bf16x8*>(kr + (size_t)(sbase+s)*DIMC + h*HDIM + oc);
    #pragma unroll
    for (int j = 0; j < 8; ++j){
      Vt[sc_idx(oc+j, s)] = (unsigned short)vv[j];
      Kt[sc_idx(oc+j, s)] = (unsigned short)kk[j];
    }
  }
  __syncthreads();

  f32x4 acc[2][7] = {};                      // wave w owns m-tiles {w, w+4}
  #pragma unroll
  for (int ks = 0; ks < 4; ++ks){
    const int sf = ks*32 + lk*8;
    bf16x8 bfrg[7];
    #pragma unroll
    for (int nt = 0; nt < 7; ++nt){
      int d = nt*16 + l16;
      bfrg[nt] = *reinterpret_cast<const bf16x8*>(&Kt[d*SLSC + (sf ^ (((d >> 3) & 7) << 3))]);
    }
    #pragma unroll
    for (int mi = 0; mi < 2; ++mi){
      int mt = w + mi*4;
      if (mt < 7){
        int e = mt*16 + l16;
        bf16x8 afrg = *reinterpret_cast<const bf16x8*>(&Vt[e*SLSC + (sf ^ (((e >> 3) & 7) << 3))]);
        #pragma unroll
        for (int nt = 0; nt < 7; ++nt)
          acc[mi][nt] = __builtin_amdgcn_mfma_f32_16x16x32_bf16(afrg, bfrg[nt], acc[mi][nt], 0, 0, 0);
      }
    }
  }

  float* pout = part + ((size_t)ch*NH + h)*12544;
  #pragma unroll
  for (int mi = 0; mi < 2; ++mi){
    int mt = w + mi*4;
    if (mt >= 7) continue;
    #pragma unroll
    for (int nt = 0; nt < 7; ++nt)
      #pragma unroll
      for (int r = 0; r < 4; ++r)
        pout[(size_t)(mt*16 + lk*4 + r)*HDIM + nt*16 + l16] = acc[mi][nt][r];
  }
}
__global__ void scred_k(const float* __restrict__ part, unsigned short* __restrict__ sc){
  int i = blockIdx.x*256 + threadIdx.x;
  if (i >= NH*HDIM*HDIM) return;
  float a = 0.f;
  #pragma unroll
  for (int c = 0; c < 28; ++c) a += part[(size_t)c*(NH*HDIM*HDIM) + i];
  sc[i] = f2bf(a);
}

// -------- MFMA linout: out[s,h*112+e] = (sum_d scores[h,e,d]*qr[s,h,d]) / denom[s,h] ---
__global__ __launch_bounds__(256) void linout_k(const unsigned short* __restrict__ qr,
    const unsigned short* __restrict__ scores, const float* __restrict__ denom,
    unsigned short* __restrict__ out)
{
  const int h = blockIdx.y;
  const int t = threadIdx.x, lane = t & 63, w = t >> 6;
  const int l16 = lane & 15, lk = lane >> 4;
  const int s0 = blockIdx.x*64 + w*16;
  const unsigned short* qrow = qr + (size_t)(s0 + l16)*DIMC + h*HDIM;
  const unsigned short* sb = scores + (size_t)h*12544;
  f32x4 acc[7] = {};
  #pragma unroll
  for (int ks = 0; ks < 4; ++ks){
    int d0 = ks*32 + lk*8;
    bf16x8 a = {};
    if (d0 < HDIM) a = *reinterpret_cast<const bf16x8*>(qrow + d0);
    #pragma unroll
    for (int nt = 0; nt < 7; ++nt){
      bf16x8 b = {};
      if (d0 < HDIM) b = *reinterpret_cast<const bf16x8*>(sb + (size_t)(nt*16 + l16)*HDIM + d0);
      acc[nt] = __builtin_amdgcn_mfma_f32_16x16x32_bf16(a, b, acc[nt], 0, 0, 0);
    }
  }
  #pragma unroll
  for (int r = 0; r < 4; ++r){
    int s = s0 + lk*4 + r;
    float dn = 1.f / denom[(size_t)s*NH + h];
    #pragma unroll
    for (int nt = 0; nt < 7; ++nt)
      out[(size_t)s*DIMC + h*HDIM + nt*16 + l16] = f2bf(acc[nt][r]*dn);
  }
}

// ---------------- fused cross-attention, MFMA (300 keys, head dim 112 padded to 128) ----
__global__ __launch_bounds__(256) void xattn_k(
    const unsigned short* __restrict__ q,   // S x DIM bf16 (rms-normed)
    const unsigned short* __restrict__ k2,  // ENCT x DIM bf16 (rms-normed)
    const unsigned short* __restrict__ v2,  // ENCT x DIM bf16
    unsigned short* __restrict__ outb)      // S x DIM bf16
{
  const int h = blockIdx.y;
  const int w = threadIdx.x >> 6, lane = threadIdx.x & 63;
  const int l16 = lane & 15, lk = lane >> 4;
  const float scale = 0.09449111825230679f;   // 1/sqrt(112)

  __shared__ __align__(16) unsigned short Kl[64][136];
  __shared__ __align__(16) unsigned short Vl[112][72];
  __shared__ __align__(16) unsigned short Pl[4][16][72];

  bf16x8 qf[4];
  const unsigned short* qbase = q + (size_t)(blockIdx.x*64 + w*16 + l16)*DIMC + h*HDIM;
  #pragma unroll
  for (int c = 0; c < 4; ++c){
    int d0 = c*32 + lk*8;
    bf16x8 z = {};
    qf[c] = (d0 < HDIM) ? *reinterpret_cast<const bf16x8*>(qbase + d0) : z;
  }

  f32x4 lg[5][4] = {};
  #pragma unroll
  for (int c = 0; c < 5; ++c){
    const int kbase = c*64;
    const int nk = (c == 4) ? (ENCT - 256) : 64;
    __syncthreads();
    #pragma unroll
    for (int it = 0; it < 4; ++it){
      int li = it*256 + threadIdx.x;
      int key = li >> 4, d0 = (li & 15) << 3;
      uint4 val = make_uint4(0u,0u,0u,0u);
      if (key < nk && d0 < HDIM)
        val = *reinterpret_cast<const uint4*>(k2 + (size_t)(kbase+key)*DIMC + h*HDIM + d0);
      *reinterpret_cast<uint4*>(&Kl[key][d0]) = val;
    }
    __syncthreads();
    #pragma unroll
    for (int nt = 0; nt < 4; ++nt){
      #pragma unroll
      for (int ks = 0; ks < 4; ++ks){
        bf16x8 kf = *reinterpret_cast<const bf16x8*>(&Kl[nt*16 + l16][ks*32 + lk*8]);
        lg[c][nt] = __builtin_amdgcn_mfma_f32_16x16x32_bf16(qf[ks], kf, lg[c][nt], 0, 0, 0);
      }
    }
  }

  float mx[4] = {-3e38f, -3e38f, -3e38f, -3e38f};
  #pragma unroll
  for (int c = 0; c < 5; ++c)
    #pragma unroll
    for (int nt = 0; nt < 4; ++nt){
      bool valid = (c*64 + nt*16 + l16) < ENCT;
      #pragma unroll
      for (int r = 0; r < 4; ++r){
        float v = valid ? lg[c][nt][r]*scale : -3e38f;
        lg[c][nt][r] = v;
        mx[r] = fmaxf(mx[r], v);
      }
    }
  #pragma unroll
  for (int o = 1; o < 16; o <<= 1)
    #pragma unroll
    for (int r = 0; r < 4; ++r) mx[r] = fmaxf(mx[r], __shfl_xor(mx[r], o));
  float sm[4] = {0.f, 0.f, 0.f, 0.f};
  #pragma unroll
  for (int c = 0; c < 5; ++c)
    #pragma unroll
    for (int nt = 0; nt < 4; ++nt)
      #pragma unroll
      for (int r = 0; r < 4; ++r){
        float e = __expf(lg[c][nt][r] - mx[r]);
        lg[c][nt][r] = e;
        sm[r] += e;
      }
  #pragma unroll
  for (int o = 1; o < 16; o <<= 1)
    #pragma unroll
    for (int r = 0; r < 4; ++r) sm[r] += __shfl_xor(sm[r], o);
  float inv[4];
  #pragma unroll
  for (int r = 0; r < 4; ++r) inv[r] = 1.f / sm[r];

  f32x4 oacc[7] = {};
  #pragma unroll
  for (int c = 0; c < 5; ++c){
    const int kbase = c*64;
    const int nk = (c == 4) ? (ENCT - 256) : 64;
    __syncthreads();
    #pragma unroll
    for (int it = 0; it < 4; ++it){
      int li = it*256 + threadIdx.x;
      if (li < 896){
        int key = li/14, d0 = (li%14)*8;
        if (key < nk){
          bf16x8 vv = *reinterpret_cast<const bf16x8*>(v2 + (size_t)(kbase+key)*DIMC + h*HDIM + d0);
          #pragma unroll
          for (int j = 0; j < 8; ++j) Vl[d0+j][key] = (unsigned short)vv[j];
        } else {
          #pragma unroll
          for (int j = 0; j < 8; ++j) Vl[d0+j][key] = 0;
        }
      }
    }
    #pragma unroll
    for (int nt = 0; nt < 4; ++nt)
      #pragma unroll
      for (int r = 0; r < 4; ++r)
        Pl[w][lk*4 + r][nt*16 + l16] = f2bf(lg[c][nt][r]);
    __syncthreads();
    #pragma unroll
    for (int ks = 0; ks < 2; ++ks){
      bf16x8 pf = *reinterpret_cast<const bf16x8*>(&Pl[w][l16][ks*32 + lk*8]);
      #pragma unroll
      for (int n = 0; n < 7; ++n){
        bf16x8 vf = *reinterpret_cast<const bf16x8*>(&Vl[n*16 + l16][ks*32 + lk*8]);
        oacc[n] = __builtin_amdgcn_mfma_f32_16x16x32_bf16(pf, vf, oacc[n], 0, 0, 0);
      }
    }
  }

  const int orow = blockIdx.x*64 + w*16 + lk*4;
  #pragma unroll
  for (int n = 0; n < 7; ++n)
    #pragma unroll
    for (int r = 0; r < 4; ++r)
      outb[(size_t)(orow + r)*DIMC + h*HDIM + n*16 + l16] = f2bf(oacc[n][r]*inv[r]);
}

// ------- depthwise 3x3 + bias + GLU(silu): 2 channels x 4 vertical outputs/thread -----
__global__ __launch_bounds__(256) void dw_k(const unsigned short* __restrict__ y1,
    const float* __restrict__ dw, const float* __restrict__ db, unsigned short* __restrict__ y2)
{
  int c = (blockIdx.y*256 + threadIdx.x)*2;
  if (c >= HID1) return;
  int bx = blockIdx.x;
  int ww = bx % 28;
  int yt = (bx / 28) & 3;
  int f  = bx / 112;
  int y0 = yt*4;

  float wa[9][2], wg[9][2];
  #pragma unroll
  for (int tp = 0; tp < 9; ++tp){
    float2 va = *reinterpret_cast<const float2*>(dw + tp*HID2 + c);
    float2 vg = *reinterpret_cast<const float2*>(dw + tp*HID2 + c + HID1);
    wa[tp][0] = va.x; wa[tp][1] = va.y;
    wg[tp][0] = vg.x; wg[tp][1] = vg.y;
  }
  float2 ba = *reinterpret_cast<const float2*>(db + c);
  float2 bg = *reinterpret_cast<const float2*>(db + c + HID1);
  float a0[4], a1[4], g0[4], g1[4];
  #pragma unroll
  for (int r = 0; r < 4; ++r){ a0[r] = ba.x; a1[r] = ba.y; g0[r] = bg.x; g1[r] = bg.y; }

  #pragma unroll
  for (int dy6 = 0; dy6 < 6; ++dy6){
    int y = y0 - 1 + dy6;
    if ((unsigned)y >= 16u) continue;
    #pragma unroll
    for (int dx = 0; dx < 3; ++dx){
      int x = ww + dx - 1;
      if ((unsigned)x >= 28u) continue;
      size_t base = ((size_t)(f*16 + y)*28 + x)*HID2;
      unsigned int a01 = *reinterpret_cast<const unsigned int*>(y1 + base + c);
      unsigned int g01 = *reinterpret_cast<const unsigned int*>(y1 + base + c + HID1);
      float fa0 = bf2f((unsigned short)(a01 & 0xffffu));
      float fa1 = bf2f((unsigned short)(a01 >> 16));
      float fg0 = bf2f((unsigned short)(g01 & 0xffffu));
      float fg1 = bf2f((unsigned short)(g01 >> 16));
      #pragma unroll
      for (int r = 0; r < 4; ++r){
        int kdy = dy6 - r;                    // compile-time after unroll
        if (kdy < 0 || kdy > 2) continue;
        int tp = kdy*3 + dx;
        a0[r] += fa0*wa[tp][0]; a1[r] += fa1*wa[tp][1];
        g0[r] += fg0*wg[tp][0]; g1[r] += fg1*wg[tp][1];
      }
    }
  }
  #pragma unroll
  for (int r = 0; r < 4; ++r){
    float s0 = g0[r] / (1.f + __expf(-g0[r]));
    float s1 = g1[r] / (1.f + __expf(-g1[r]));
    int pos = (f*16 + y0 + r)*28 + ww;
    unsigned int o = (unsigned int)f2bf(a0[r]*s0) | ((unsigned int)f2bf(a1[r]*s1) << 16);
    *reinterpret_cast<unsigned int*>(y2 + (size_t)pos*HID1 + c) = o;
  }
}

// ---------------- final: out = x2 + g_mlp*(y3 + tc) ----------------
__global__ void final_k(const float* __restrict__ x2, const unsigned short* __restrict__ y3,
    const float* __restrict__ tc, const float* __restrict__ mods, float* __restrict__ out)
{
  int i = blockIdx.x*256 + threadIdx.x;
  if (i >= SD) return;
  int d = i % DIMC;
  out[i] = x2[i] + mods[5*DIMC + d]*(bf2f(y3[i]) + tc[i]);
}

extern "C" void kernel_launch(void* const* d_in, const int* in_sizes, int n_in,
                              void* d_out, int out_size, void* d_ws, size_t ws_size,
                              hipStream_t stream)
{
  const float* hid   = (const float*)d_in[0];
  const float* enc   = (const float*)d_in[1];
  const float* tstep = (const float*)d_in[2];
  const float* fcos  = (const float*)d_in[3];
  const float* fsin  = (const float*)d_in[4];
  const float* sst   = (const float*)d_in[5];
  const float *a1_qw=(const float*)d_in[6],  *a1_qb=(const float*)d_in[7];
  const float *a1_kw=(const float*)d_in[8],  *a1_kb=(const float*)d_in[9];
  const float *a1_vw=(const float*)d_in[10], *a1_vb=(const float*)d_in[11];
  const float *a1_nq=(const float*)d_in[12], *a1_nk=(const float*)d_in[13];
  const float *a1_ow=(const float*)d_in[14], *a1_ob=(const float*)d_in[15];
  const float *a2_qw=(const float*)d_in[16], *a2_qb=(const float*)d_in[17];
  const float *a2_kw=(const float*)d_in[18], *a2_kb=(const float*)d_in[19];
  const float *a2_vw=(const float*)d_in[20], *a2_vb=(const float*)d_in[21];
  const float *a2_nq=(const float*)d_in[22], *a2_nk=(const float*)d_in[23];
  const float *a2_ow=(const float*)d_in[24], *a2_ob=(const float*)d_in[25];
  const float *ff_inv_w=(const float*)d_in[26], *ff_inv_b=(const float*)d_in[27];
  const float *ff_dw=(const float*)d_in[28], *ff_db=(const float*)d_in[29];
  const float *ff_pw=(const float*)d_in[30];
  const float *ff_tw=(const float*)d_in[31];
  float* out = (float*)d_out;

  // ---- workspace plan (~213 MB total; all sizes 256-multiple) ----
  const size_t SLOTB = (size_t)SD*2;        // 16,056,320 B  (one bf16 S x DIM slot)
  char* ws = (char*)d_ws;
  size_t off = 0;
  auto alloc = [&](size_t n){ void* p = ws + off; off += (n + 255) & ~(size_t)255; return p; };

  char* P = (char*)alloc(6*SLOTB);          // 6 bf16 activation slots (96.3 MB)
  float* x1    = (float*)alloc((size_t)SD*4);     // fp32 residual (32.1 MB)
  unsigned short* nh2b = (unsigned short*)alloc(SLOTB); // MUST follow x1 (y2b spans both)
  float* x2    = (float*)alloc((size_t)SD*4);
  unsigned short* k2b = (unsigned short*)alloc((size_t)ENCT*DIMC*2);  // k2b+v2b contiguous
  unsigned short* v2b = (unsigned short*)alloc((size_t)ENCT*DIMC*2);
  unsigned short* encb = (unsigned short*)alloc((size_t)ENCT*DIMC*2);
  float* modsb = (float*)alloc(6*DIMC*4);
  float* ksum  = (float*)alloc(DIMC*4);
  float* kpart = (float*)alloc((size_t)28*DIMC*4);
  float* denom = (float*)alloc((size_t)STOK*NH*4);
  unsigned short* scorb = (unsigned short*)alloc((size_t)NH*HDIM*HDIM*2);
  float* bias3 = (float*)alloc(3*2304*4);
  unsigned short* Wbig = (unsigned short*)alloc((size_t)6912*DIMC*2);  // 31 MB weight staging

  // P-slot aliases (lifetimes verified disjoint)
  unsigned short* P0 = (unsigned short*)P;                 // nhb | y1b[0:] | y3b
  unsigned short* P1 = (unsigned short*)(P + 1*SLOTB);     // qb | spart | lob | y1b | tc[0:]
  unsigned short* P2 = (unsigned short*)(P + 2*SLOTB);     // kb | spart | x1b | y1b | tc[1:]
  unsigned short* P3 = (unsigned short*)(P + 3*SLOTB);     // vb | q2b | y1b
  unsigned short* P4 = (unsigned short*)(P + 4*SLOTB);     // qrb | crb | y1b
  unsigned short* P5 = (unsigned short*)(P + 5*SLOTB);     // krb | y1b
  unsigned short* nhb = P0;
  unsigned short* y1b = P0;                                // 96.34 MB = slots 0..5 exactly
  unsigned short* y2b = (unsigned short*)x1;               // 48.17 MB = x1 + nh2b exactly
  unsigned short* y3b = P0;
  float* tc = (float*)(P + 1*SLOTB);                       // 32.1 MB = slots 1..2
  float* spart = (float*)P1;   // 28 x NH x 112 x 112 fp32 = 28.1 MB, q/k dead by then

  auto cvt = [&](const float* s, unsigned short* d, size_t n){
    int n4 = (int)(n/4);
    cvt_k<<<dim3((n4+255)/256), 256, 0, stream>>>((const float4*)s, (ushort4*)d, n4);
  };
  auto cvtT = [&](const float* s, unsigned short* d, int rows, int ldsrc, int c0, int nc, int ncPad){
    cvt_t_k<<<dim3(ncPad/32, rows/32), 256, 0, stream>>>(s, d, rows, ldsrc, c0, nc);
  };
  auto gemm_grid = [&](int M, int Npad){ return dim3(Npad/128, (M+127)/128); };

  mods_k<<<dim3((6*DIMC+255)/256), 256, 0, stream>>>(sst, tstep, modsb);
  cvt(enc, encb, (size_t)ENCT*DIMC);

  // ---- attn1: fused QKV ----
  ln_mod_k<<<dim3(STOK), 256, 0, stream>>>(hid, modsb, 0, 1, nhb);
  pack3_k<<<dim3((3*2304+255)/256), 256, 0, stream>>>(bias3, a1_qb, a1_kb, a1_vb, 3);
  cvtT(a1_qw, Wbig + (size_t)0*2304*DIMC, DIMC, DIMC, 0, DIMC, 2304);
  cvtT(a1_kw, Wbig + (size_t)1*2304*DIMC, DIMC, DIMC, 0, DIMC, 2304);
  cvtT(a1_vw, Wbig + (size_t)2*2304*DIMC, DIMC, DIMC, 0, DIMC, 2304);
  gemm_bt<6><<<gemm_grid(STOK, 6912), 256, 0, stream>>>(nhb, Wbig, bias3, nullptr, P1,
                                                        nullptr, nullptr, STOK, 6912, DIMC, SD, 6);
  rms_bf_k<1,1><<<dim3(STOK), 256, 0, stream>>>(P1, a1_nq, fcos, fsin, P4);
  rms_bf_k<1,1><<<dim3(STOK), 256, 0, stream>>>(P2, a1_nk, fcos, fsin, P5);
  colsum_k<<<dim3(9, 28), 256, 0, stream>>>(P2, kpart);
  ksumred_k<<<dim3(9), 256, 0, stream>>>(kpart, ksum);
  denom_k<<<dim3(STOK), 256, 0, stream>>>(P1, ksum, denom);
  // q (P1) and k (P2) are dead now -> spart may overwrite them
  scores_k<<<dim3(NH, 28), 256, 0, stream>>>(P3, P5, spart);
  scred_k<<<dim3((NH*HDIM*HDIM+255)/256), 256, 0, stream>>>(spart, scorb);
  linout_k<<<dim3(STOK/64, NH), 256, 0, stream>>>(P4, scorb, denom, P1);   // lob -> P1
  dim3 gMN = gemm_grid(STOK, 2304);
  cvtT(a1_ow, Wbig, DIMC, DIMC, 0, DIMC, 2304);
  gemm_bt<3><<<gMN, 256, 0, stream>>>(P1, Wbig, a1_ob, x1, P2, hid, modsb + 2*DIMC, STOK, DIMC, DIMC, DIMC, 6);

  // ---- cross attn ----
  cvtT(a2_qw, Wbig, DIMC, DIMC, 0, DIMC, 2304);
  gemm_bt<2><<<gMN, 256, 0, stream>>>(P2, Wbig, a2_qb, nullptr, P3, nullptr, nullptr, STOK, DIMC, DIMC, DIMC, 6);
  pack3_k<<<dim3((2*2304+255)/256), 256, 0, stream>>>(bias3, a2_kb, a2_vb, a2_vb, 2);
  cvtT(a2_kw, Wbig + (size_t)0*2304*DIMC, DIMC, DIMC, 0, DIMC, 2304);
  cvtT(a2_vw, Wbig + (size_t)1*2304*DIMC, DIMC, DIMC, 0, DIMC, 2304);
  gemm_bt<6><<<gemm_grid(ENCT, 4608), 256, 0, stream>>>(encb, Wbig, bias3, nullptr, k2b,
                                                        nullptr, nullptr, ENCT, 4608, DIMC, ENCT*DIMC, 6);
  rms_bf_k<0,0><<<dim3(STOK), 256, 0, stream>>>(P3, a2_nq, nullptr, nullptr, nullptr);
  rms_bf_k<0,0><<<dim3(ENCT), 256, 0, stream>>>(k2b, a2_nk, nullptr, nullptr, nullptr);
  xattn_k<<<dim3(STOK/64, NH), 256, 0, stream>>>(P3, k2b, v2b, P4);   // crb -> P4
  cvtT(a2_ow, Wbig, DIMC, DIMC, 0, DIMC, 2304);
  gemm_bt<4><<<gMN, 256, 0, stream>>>(P4, Wbig, a2_ob, x2, nullptr, x1, nullptr, STOK, DIMC, DIMC, DIMC, 6);

  // ---- FF ----
  ln_mod_k<<<dim3(STOK), 256, 0, stream>>>(x2, modsb, 3, 4, nh2b);
  for (int q = 0; q < 2; ++q){                 // ff_inv in 2 column slices of 6720
    int c0 = q*6720;
    cvtT(ff_inv_w, Wbig, DIMC, HID2, c0, 6720, 6912);
    gemm_bt<1><<<gemm_grid(STOK, 6912), 256, 0, stream>>>(nh2b, Wbig, ff_inv_b + c0, nullptr, y1b + c0,
                                                          nullptr, nullptr, STOK, 6720, DIMC, HID2, 6);
  }
  dw_k<<<dim3(896, 14), 256, 0, stream>>>(y1b, ff_dw, ff_db, y2b);
  cvtT(ff_pw, Wbig, HID1, DIMC, 0, DIMC, 2304);   // point conv in one GEMM (K=6720)
  gemm_bt<2><<<gMN, 256, 0, stream>>>(y2b, Wbig, nullptr, nullptr, y3b,
                                      nullptr, nullptr, STOK, DIMC, HID1, DIMC, 2);
  // temporal conv: tc = y3 @ W1 (center) then shifted accumulates
  cvtT(ff_tw + (size_t)DD, Wbig, DIMC, DIMC, 0, DIMC, 2304);
  gemm_bt<0><<<gMN, 256, 0, stream>>>(y3b, Wbig, nullptr, tc, nullptr, nullptr, nullptr, STOK, DIMC, DIMC, DIMC, 6);
  dim3 gT = gemm_grid(3136, 2304);
  cvtT(ff_tw, Wbig, DIMC, DIMC, 0, DIMC, 2304);
  gemm_bt<5><<<gT, 256, 0, stream>>>(y3b, Wbig, nullptr, tc + (size_t)448*DIMC, nullptr, nullptr, nullptr, 3136, DIMC, DIMC, DIMC, 6);
  cvtT(ff_tw + (size_t)2*DD, Wbig, DIMC, DIMC, 0, DIMC, 2304);
  gemm_bt<5><<<gT, 256, 0, stream>>>(y3b + (size_t)448*DIMC, Wbig, nullptr, tc, nullptr, nullptr, nullptr, 3136, DIMC, DIMC, DIMC, 6);

  // out = x2 + g_mlp*(y3 + tc)
  final_k<<<dim3((SD+255)/256), 256, 0, stream>>>(x2, y3b, tc, modsb, out);
}

// Round 9
// 1486.342 us; speedup vs baseline: 1.1475x; 1.1475x over previous
//
#include <hip/hip_runtime.h>

#define DIMC 2240
#define STOK 3584
#define ENCT 300
#define NH   20
#define HDIM 112
#define HID1 6720
#define HID2 13440
#define DD   (2240*2240)
#define SD   (3584*2240)

typedef short bf16x8 __attribute__((ext_vector_type(8)));   // guide-verified operand type
typedef float f32x4  __attribute__((ext_vector_type(4)));

__device__ __forceinline__ unsigned short f2bf(float f){
  unsigned int u = __float_as_uint(f);
  u += 0x7fffu + ((u >> 16) & 1u);          // RNE
  return (unsigned short)(u >> 16);
}
__device__ __forceinline__ float bf2f(unsigned short h){
  return __uint_as_float(((unsigned int)h) << 16);
}
__device__ __forceinline__ void gl_lds16(const unsigned short* g, unsigned short* l){
  __builtin_amdgcn_global_load_lds(
      (const __attribute__((address_space(1))) unsigned int*)(const void*)g,
      (__attribute__((address_space(3))) unsigned int*)(void*)l, 16, 0, 0);
}

// ---------------- fp32 -> bf16 convert (flat) ----------------
__global__ void cvt_k(const float4* __restrict__ src, ushort4* __restrict__ dst, int n4){
  int i = blockIdx.x*256 + threadIdx.x;
  if (i < n4){
    float4 v = src[i];
    ushort4 o; o.x = f2bf(v.x); o.y = f2bf(v.y); o.z = f2bf(v.z); o.w = f2bf(v.w);
    dst[i] = o;
  }
}

// ------- fp32 (rows x cols slice) -> bf16 TRANSPOSED [ncPad][rows], zero-padded -------
__global__ __launch_bounds__(256) void cvt_t_k(const float* __restrict__ src,
    unsigned short* __restrict__ dst, int rows, int ldsrc, int c0, int nc){
  __shared__ float tile[32][33];
  const int tx = threadIdx.x & 31, ty = threadIdx.x >> 5;   // ty 0..7
  const int colBase = blockIdx.x*32;
  #pragma unroll
  for (int i = 0; i < 4; ++i){
    int rr = blockIdx.y*32 + ty + i*8;
    int cc = colBase + tx;
    tile[ty + i*8][tx] = (cc < nc) ? src[(size_t)rr*ldsrc + c0 + cc] : 0.f;
  }
  __syncthreads();
  #pragma unroll
  for (int i = 0; i < 4; ++i){
    int n = colBase + ty + i*8;          // < ncPad by grid
    int k = blockIdx.y*32 + tx;
    dst[(size_t)n*rows + k] = f2bf(tile[tx][ty + i*8]);
  }
}

// ---------------- pack up to 3 biases into [nslots][2304] (zero pad) ----------------
__global__ void pack3_k(float* __restrict__ dst, const float* __restrict__ b0,
    const float* __restrict__ b1, const float* __restrict__ b2, int nslots){
  int i = blockIdx.x*256 + threadIdx.x;
  if (i >= nslots*2304) return;
  int slot = i / 2304, d = i - slot*2304;
  const float* src = (slot == 0) ? b0 : ((slot == 1) ? b1 : b2);
  dst[i] = (d < 2240) ? src[d] : 0.f;
}

// ---------------- mods = scale_shift_table + timestep ----------------
__global__ void mods_k(const float* __restrict__ sst, const float* __restrict__ ts, float* __restrict__ mods){
  int i = blockIdx.x*256 + threadIdx.x;
  if (i < 6*DIMC) mods[i] = sst[i] + ts[i];
}

// ---------------- LayerNorm * (1+sc) + sh -> bf16 (float4-vectorized) ----------------
__global__ __launch_bounds__(256) void ln_mod_k(const float* __restrict__ x,
    const float* __restrict__ mods, int shj, int scj, unsigned short* __restrict__ out)
{
  const int s = blockIdx.x;
  const float4* row4 = reinterpret_cast<const float4*>(x + (size_t)s*DIMC);
  const float4* sh4 = reinterpret_cast<const float4*>(mods + shj*DIMC);
  const float4* sc4 = reinterpret_cast<const float4*>(mods + scj*DIMC);
  float sum = 0.f, sq = 0.f;
  for (int o = threadIdx.x; o < 560; o += 256){
    float4 v = row4[o];
    sum += v.x + v.y + v.z + v.w;
    sq  += v.x*v.x + v.y*v.y + v.z*v.z + v.w*v.w;
  }
  #pragma unroll
  for (int o = 32; o; o >>= 1){ sum += __shfl_down(sum, o); sq += __shfl_down(sq, o); }
  __shared__ float sA[4], sB[4];
  int w = threadIdx.x >> 6, l = threadIdx.x & 63;
  if (!l){ sA[w] = sum; sB[w] = sq; }
  __syncthreads();
  sum = sA[0]+sA[1]+sA[2]+sA[3];
  sq  = sB[0]+sB[1]+sB[2]+sB[3];
  float mean = sum * (1.f/DIMC);
  float rs = rsqrtf(sq*(1.f/DIMC) - mean*mean + 1e-6f);
  unsigned short* orow = out + (size_t)s*DIMC;
  for (int o = threadIdx.x; o < 560; o += 256){
    float4 v = row4[o], sc = sc4[o], sh = sh4[o];
    ushort4 r;
    r.x = f2bf((v.x-mean)*rs*(1.f + sc.x) + sh.x);
    r.y = f2bf((v.y-mean)*rs*(1.f + sc.y) + sh.y);
    r.z = f2bf((v.z-mean)*rs*(1.f + sc.z) + sh.z);
    r.w = f2bf((v.w-mean)*rs*(1.f + sc.w) + sh.w);
    *reinterpret_cast<ushort4*>(orow + o*4) = r;
  }
}

// ---------------- RMS on bf16 rows (optional ReLU / RoPE), uint4-vectorized ----------
template<int RELU, int ROPE>
__global__ __launch_bounds__(256) void rms_bf_k(unsigned short* __restrict__ x, const float* __restrict__ nw,
    const float* __restrict__ cosb, const float* __restrict__ sinb, unsigned short* __restrict__ xr)
{
  const int s = blockIdx.x;
  unsigned short* row = x + (size_t)s*DIMC;
  float sq = 0.f;
  for (int o = threadIdx.x; o < 280; o += 256){     // 280 octets of 8 bf16
    uint4 v = *reinterpret_cast<const uint4*>(row + o*8);
    unsigned int uu[4] = {v.x, v.y, v.z, v.w};
    #pragma unroll
    for (int j = 0; j < 4; ++j){
      float lo = bf2f((unsigned short)(uu[j] & 0xffffu));
      float hi = bf2f((unsigned short)(uu[j] >> 16));
      sq += lo*lo + hi*hi;
    }
  }
  #pragma unroll
  for (int o = 32; o; o >>= 1) sq += __shfl_down(sq, o);
  __shared__ float sB[4];
  int w = threadIdx.x >> 6, l = threadIdx.x & 63;
  if (!l) sB[w] = sq;
  __syncthreads();
  sq = sB[0]+sB[1]+sB[2]+sB[3];
  float rs = rsqrtf(sq*(1.f/DIMC) + 1e-5f);
  for (int o = threadIdx.x; o < 280; o += 256){
    uint4 v = *reinterpret_cast<const uint4*>(row + o*8);
    unsigned int uu[4] = {v.x, v.y, v.z, v.w};
    float4 n0 = *reinterpret_cast<const float4*>(nw + o*8);
    float4 n1 = *reinterpret_cast<const float4*>(nw + o*8 + 4);
    float nn[8] = {n0.x,n0.y,n0.z,n0.w,n1.x,n1.y,n1.z,n1.w};
    float vals[8];
    #pragma unroll
    for (int j = 0; j < 4; ++j){
      vals[2*j]   = bf2f((unsigned short)(uu[j] & 0xffffu))*rs*nn[2*j];
      vals[2*j+1] = bf2f((unsigned short)(uu[j] >> 16))*rs*nn[2*j+1];
    }
    if constexpr (RELU){
      #pragma unroll
      for (int j = 0; j < 8; ++j) vals[j] = fmaxf(vals[j], 0.f);
    }
    uint4 o1;
    unsigned int* po = &o1.x;
    #pragma unroll
    for (int j = 0; j < 4; ++j)
      po[j] = (unsigned int)f2bf(vals[2*j]) | ((unsigned int)f2bf(vals[2*j+1]) << 16);
    *reinterpret_cast<uint4*>(row + o*8) = o1;
    if constexpr (ROPE){
      int jb = (o*8) % HDIM;                      // octet stays within a head (112%8==0)
      uint4 o2;
      unsigned int* pr = &o2.x;
      #pragma unroll
      for (int p = 0; p < 4; ++p){
        float c  = cosb[(size_t)s*HDIM + jb + 2*p];
        float sn = sinb[(size_t)s*HDIM + jb + 2*p + 1];
        float r0 = vals[2*p]*c - vals[2*p+1]*sn;
        float r1 = vals[2*p]*sn + vals[2*p+1]*c;
        pr[p] = (unsigned int)f2bf(r0) | ((unsigned int)f2bf(r1) << 16);
      }
      *reinterpret_cast<uint4*>(xr + (size_t)s*DIMC + o*8) = o2;
    }
  }
}

// ------- bf16 MFMA GEMM: C = A(MxK) @ Bt^T, Bt is [Npad][K] (N-major), BK=64 ---------
// (round-7 proven version) Both-sides swizzle; K % 64 == 0; PW | gridDim.x.
// EPI: 0 Cf=acc+bias | 1 Cb=bf16(silu(acc+bias)) | 2 Cb=bf16(acc+bias)
//      3 u=res+gate*(acc+bias); Cf=u; Cb=bf16(u) | 4 Cf=res+acc+bias | 5 Cf+=acc
//      6 slot-split: slot=col/2304, d=col%2304; if d<2240: Cb[slot*ldc + row*2240 + d]
template<int EPI>
__global__ __launch_bounds__(256) void gemm_bt(
  const unsigned short* __restrict__ A, const unsigned short* __restrict__ Bt,
  const float* __restrict__ bias, float* __restrict__ Cf, unsigned short* __restrict__ Cb,
  const float* __restrict__ res, const float* __restrict__ gate,
  int M, int N, int K, int ldc, int PW)
{
  __shared__ __align__(16) unsigned short Al[128*64];
  __shared__ __align__(16) unsigned short Bl[128*64];
  const int gx = gridDim.x, gy = gridDim.y;
  const int nwg = gx*gy;
  const int orig = blockIdx.y*gx + blockIdx.x;
  // bijective XCD-aware remap (m204)
  const int qq = nwg >> 3, rr = nwg & 7;
  const int xcd = orig & 7, li = orig >> 3;
  const int wg = (xcd < rr ? xcd*(qq+1) : rr*(qq+1) + (xcd-rr)*qq) + li;
  // N-panel rasterization: panel of PW n-tiles covers all gy m-rows before advancing
  const int ppw = gy*PW;
  const int panel = wg / ppw, rm = wg - panel*ppw;
  const int mrow = rm / PW;
  const int m0 = mrow*128;
  const int n0 = (panel*PW + (rm - mrow*PW))*128;

  const int t = threadIdx.x, lane = t & 63, w = t >> 6;
  const int wr = w >> 1, wc = w & 1;
  const int l16 = lane & 15, lk = lane >> 4;

  // staging: per wave 4 A-chunks + 4 B-chunks (each 1KB = 8 rows x 128B), swizzled src
  const int lr8 = lane >> 3;           // row within 8-row block (== row&7)
  const int sc  = (lane & 7) ^ lr8;    // pre-swizzled source chunk
  const unsigned short* Aps[4];
  const unsigned short* Bps[4];
  #pragma unroll
  for (int i = 0; i < 4; ++i){
    int ar = m0 + w*32 + i*8 + lr8;
    int br = n0 + w*32 + i*8 + lr8;
    Aps[i] = A  + (size_t)min(ar, M-1)*K + sc*8;
    Bps[i] = Bt + (size_t)br*K + sc*8;
  }
  unsigned short* Ad = Al + w*2048;
  unsigned short* Bd = Bl + w*2048;

  f32x4 acc[4][4] = {};
  for (int k0 = 0; k0 < K; k0 += 64){
    __syncthreads();
    #pragma unroll
    for (int i = 0; i < 4; ++i){
      gl_lds16(Aps[i] + k0, Ad + i*512);
      gl_lds16(Bps[i] + k0, Bd + i*512);
    }
    __syncthreads();
    #pragma unroll
    for (int kk = 0; kk < 2; ++kk){
      bf16x8 af[4], bfr[4];
      const int chb = (kk*4 + lk) ^ (l16 & 7);   // swizzled read chunk
      #pragma unroll
      for (int m = 0; m < 4; ++m)
        af[m] = *reinterpret_cast<const bf16x8*>(Al + (wr*64 + m*16 + l16)*64 + chb*8);
      #pragma unroll
      for (int n = 0; n < 4; ++n)
        bfr[n] = *reinterpret_cast<const bf16x8*>(Bl + (wc*64 + n*16 + l16)*64 + chb*8);
      #pragma unroll
      for (int m = 0; m < 4; ++m)
        #pragma unroll
        for (int n = 0; n < 4; ++n)
          acc[m][n] = __builtin_amdgcn_mfma_f32_16x16x32_bf16(af[m], bfr[n], acc[m][n], 0, 0, 0);
    }
  }

  const int rb = m0 + wr*64 + lk*4;   // C/D: col = lane&15, row = (lane>>4)*4 + reg
  const int cb = n0 + wc*64 + l16;
  #pragma unroll
  for (int m = 0; m < 4; ++m){
    #pragma unroll
    for (int r = 0; r < 4; ++r){
      int row = rb + m*16 + r;
      if (row >= M) continue;
      #pragma unroll
      for (int n = 0; n < 4; ++n){
        int col = cb + n*16;
        if (col >= N) continue;
        float v = acc[m][n][r];
        float bv = bias ? bias[col] : 0.f;
        if constexpr (EPI == 6){
          int slot = col / 2304;
          int d = col - slot*2304;
          if (d < 2240)
            Cb[(size_t)slot*ldc + (size_t)row*2240 + d] = f2bf(v + bv);
        } else {
          size_t idx = (size_t)row*ldc + col;
          if constexpr (EPI == 0){ Cf[idx] = v + bv; }
          else if constexpr (EPI == 1){ float u = v + bv; Cb[idx] = f2bf(u / (1.f + __expf(-u))); }
          else if constexpr (EPI == 2){ Cb[idx] = f2bf(v + bv); }
          else if constexpr (EPI == 3){ float u = res[idx] + gate[col]*(v + bv); Cf[idx] = u; Cb[idx] = f2bf(u); }
          else if constexpr (EPI == 4){ Cf[idx] = res[idx] + v + bv; }
          else { Cf[idx] += v; }
        }
      }
    }
  }
}

// ---------------- linear attention helpers ----------------
__global__ void colsum_k(const unsigned short* __restrict__ k, float* __restrict__ kpart){
  int d = blockIdx.x*256 + threadIdx.x;
  if (d >= DIMC) return;
  int ch = blockIdx.y, s0 = ch*128;
  float acc = 0.f;
  for (int s = s0; s < s0+128; ++s) acc += bf2f(k[(size_t)s*DIMC + d]);
  kpart[(size_t)ch*DIMC + d] = acc;
}
__global__ void ksumred_k(const float* __restrict__ kpart, float* __restrict__ ksum){
  int d = blockIdx.x*256 + threadIdx.x;
  if (d >= DIMC) return;
  float a = 0.f;
  for (int c = 0; c < 28; ++c) a += kpart[(size_t)c*DIMC + d];
  ksum[d] = a;
}
__global__ __launch_bounds__(256) void denom_k(const unsigned short* __restrict__ q,
    const float* __restrict__ ksum, float* __restrict__ denom)
{
  int s = blockIdx.x; int w = threadIdx.x >> 6, l = threadIdx.x & 63;
  for (int h = w; h < NH; h += 4){
    const unsigned short* qb = q + (size_t)s*DIMC + h*HDIM;
    const float* kb = ksum + h*HDIM;
    float v = bf2f(qb[l])*kb[l];
    if (l < 48) v += bf2f(qb[64+l])*kb[64+l];
    #pragma unroll
    for (int o = 32; o; o >>= 1) v += __shfl_down(v, o);
    if (!l) denom[s*NH + h] = v + 1e-15f;
  }
}

// -------- MFMA scores: part[ch][h][e][d] = sum_{s in 128-chunk} V[s,h,e]*Kr[s,h,d] -----
#define SLSC 136
__device__ __forceinline__ int sc_idx(int e, int s){
  return e*SLSC + (s ^ (((e >> 3) & 7) << 3));
}
__global__ __launch_bounds__(256) void scores_k(const unsigned short* __restrict__ v,
    const unsigned short* __restrict__ kr, float* __restrict__ part)
{
  const int h = blockIdx.x, ch = blockIdx.y;
  __shared__ __align__(16) unsigned short Vt[112*SLSC];
  __shared__ __align__(16) unsigned short Kt[112*SLSC];
  const int t = threadIdx.x, lane = t & 63, w = t >> 6;
  const int l16 = lane & 15, lk = lane >> 4;
  const int sbase = ch*128;

  for (int p = t; p < 1792; p += 256){       // 128 tokens x 14 dim-octets
    int s = p / 14, oc = (p % 14) * 8;
    bf16x8 vv = *reinterpret_cast<const bf16x8*>(v  + (size_t)(sbase+s)*DIMC + h*HDIM + oc);
    bf16x8 kk = *reinterpret_cast<const bf16x8*>(kr + (size_t)(sbase+s)*DIMC + h*HDIM + oc);
    #pragma unroll
    for (int j = 0; j < 8; ++j){
      Vt[sc_idx(oc+j, s)] = (unsigned short)vv[j];
      Kt[sc_idx(oc+j, s)] = (unsigned short)kk[j];
    }
  }
  __syncthreads();

  f32x4 acc[2][7] = {};                      // wave w owns m-tiles {w, w+4}
  #pragma unroll
  for (int ks = 0; ks < 4; ++ks){
    const int sf = ks*32 + lk*8;
    bf16x8 bfrg[7];
    #pragma unroll
    for (int nt = 0; nt < 7; ++nt){
      int d = nt*16 + l16;
      bfrg[nt] = *reinterpret_cast<const bf16x8*>(&Kt[d*SLSC + (sf ^ (((d >> 3) & 7) << 3))]);
    }
    #pragma unroll
    for (int mi = 0; mi < 2; ++mi){
      int mt = w + mi*4;
      if (mt < 7){
        int e = mt*16 + l16;
        bf16x8 afrg = *reinterpret_cast<const bf16x8*>(&Vt[e*SLSC + (sf ^ (((e >> 3) & 7) << 3))]);
        #pragma unroll
        for (int nt = 0; nt < 7; ++nt)
          acc[mi][nt] = __builtin_amdgcn_mfma_f32_16x16x32_bf16(afrg, bfrg[nt], acc[mi][nt], 0, 0, 0);
      }
    }
  }

  float* pout = part + ((size_t)ch*NH + h)*12544;
  #pragma unroll
  for (int mi = 0; mi < 2; ++mi){
    int mt = w + mi*4;
    if (mt >= 7) continue;
    #pragma unroll
    for (int nt = 0; nt < 7; ++nt)
      #pragma unroll
      for (int r = 0; r < 4; ++r)
        pout[(size_t)(mt*16 + lk*4 + r)*HDIM + nt*16 + l16] = acc[mi][nt][r];
  }
}
__global__ void scred_k(const float* __restrict__ part, unsigned short* __restrict__ sc){
  int i = blockIdx.x*256 + threadIdx.x;
  if (i >= NH*HDIM*HDIM) return;
  float a = 0.f;
  #pragma unroll
  for (int c = 0; c < 28; ++c) a += part[(size_t)c*(NH*HDIM*HDIM) + i];
  sc[i] = f2bf(a);
}

// -------- MFMA linout: out[s,h*112+e] = (sum_d scores[h,e,d]*qr[s,h,d]) / denom[s,h] ---
__global__ __launch_bounds__(256) void linout_k(const unsigned short* __restrict__ qr,
    const unsigned short* __restrict__ scores, const float* __restrict__ denom,
    unsigned short* __restrict__ out)
{
  const int h = blockIdx.y;
  const int t = threadIdx.x, lane = t & 63, w = t >> 6;
  const int l16 = lane & 15, lk = lane >> 4;
  const int s0 = blockIdx.x*64 + w*16;
  const unsigned short* qrow = qr + (size_t)(s0 + l16)*DIMC + h*HDIM;
  const unsigned short* sb = scores + (size_t)h*12544;
  f32x4 acc[7] = {};
  #pragma unroll
  for (int ks = 0; ks < 4; ++ks){
    int d0 = ks*32 + lk*8;
    bf16x8 a = {};
    if (d0 < HDIM) a = *reinterpret_cast<const bf16x8*>(qrow + d0);
    #pragma unroll
    for (int nt = 0; nt < 7; ++nt){
      bf16x8 b = {};
      if (d0 < HDIM) b = *reinterpret_cast<const bf16x8*>(sb + (size_t)(nt*16 + l16)*HDIM + d0);
      acc[nt] = __builtin_amdgcn_mfma_f32_16x16x32_bf16(a, b, acc[nt], 0, 0, 0);
    }
  }
  #pragma unroll
  for (int r = 0; r < 4; ++r){
    int s = s0 + lk*4 + r;
    float dn = 1.f / denom[(size_t)s*NH + h];
    #pragma unroll
    for (int nt = 0; nt < 7; ++nt)
      out[(size_t)s*DIMC + h*HDIM + nt*16 + l16] = f2bf(acc[nt][r]*dn);
  }
}

// ---------------- fused cross-attention, MFMA (300 keys, head dim 112 padded to 128) ----
__global__ __launch_bounds__(256) void xattn_k(
    const unsigned short* __restrict__ q,   // S x DIM bf16 (rms-normed)
    const unsigned short* __restrict__ k2,  // ENCT x DIM bf16 (rms-normed)
    const unsigned short* __restrict__ v2,  // ENCT x DIM bf16
    unsigned short* __restrict__ outb)      // S x DIM bf16
{
  const int h = blockIdx.y;
  const int w = threadIdx.x >> 6, lane = threadIdx.x & 63;
  const int l16 = lane & 15, lk = lane >> 4;
  const float scale = 0.09449111825230679f;   // 1/sqrt(112)

  __shared__ __align__(16) unsigned short Kl[64][136];
  __shared__ __align__(16) unsigned short Vl[112][72];
  __shared__ __align__(16) unsigned short Pl[4][16][72];

  bf16x8 qf[4];
  const unsigned short* qbase = q + (size_t)(blockIdx.x*64 + w*16 + l16)*DIMC + h*HDIM;
  #pragma unroll
  for (int c = 0; c < 4; ++c){
    int d0 = c*32 + lk*8;
    bf16x8 z = {};
    qf[c] = (d0 < HDIM) ? *reinterpret_cast<const bf16x8*>(qbase + d0) : z;
  }

  f32x4 lg[5][4] = {};
  #pragma unroll
  for (int c = 0; c < 5; ++c){
    const int kbase = c*64;
    const int nk = (c == 4) ? (ENCT - 256) : 64;
    __syncthreads();
    #pragma unroll
    for (int it = 0; it < 4; ++it){
      int li = it*256 + threadIdx.x;
      int key = li >> 4, d0 = (li & 15) << 3;
      uint4 val = make_uint4(0u,0u,0u,0u);
      if (key < nk && d0 < HDIM)
        val = *reinterpret_cast<const uint4*>(k2 + (size_t)(kbase+key)*DIMC + h*HDIM + d0);
      *reinterpret_cast<uint4*>(&Kl[key][d0]) = val;
    }
    __syncthreads();
    #pragma unroll
    for (int nt = 0; nt < 4; ++nt){
      #pragma unroll
      for (int ks = 0; ks < 4; ++ks){
        bf16x8 kf = *reinterpret_cast<const bf16x8*>(&Kl[nt*16 + l16][ks*32 + lk*8]);
        lg[c][nt] = __builtin_amdgcn_mfma_f32_16x16x32_bf16(qf[ks], kf, lg[c][nt], 0, 0, 0);
      }
    }
  }

  float mx[4] = {-3e38f, -3e38f, -3e38f, -3e38f};
  #pragma unroll
  for (int c = 0; c < 5; ++c)
    #pragma unroll
    for (int nt = 0; nt < 4; ++nt){
      bool valid = (c*64 + nt*16 + l16) < ENCT;
      #pragma unroll
      for (int r = 0; r < 4; ++r){
        float v = valid ? lg[c][nt][r]*scale : -3e38f;
        lg[c][nt][r] = v;
        mx[r] = fmaxf(mx[r], v);
      }
    }
  #pragma unroll
  for (int o = 1; o < 16; o <<= 1)
    #pragma unroll
    for (int r = 0; r < 4; ++r) mx[r] = fmaxf(mx[r], __shfl_xor(mx[r], o));
  float sm[4] = {0.f, 0.f, 0.f, 0.f};
  #pragma unroll
  for (int c = 0; c < 5; ++c)
    #pragma unroll
    for (int nt = 0; nt < 4; ++nt)
      #pragma unroll
      for (int r = 0; r < 4; ++r){
        float e = __expf(lg[c][nt][r] - mx[r]);
        lg[c][nt][r] = e;
        sm[r] += e;
      }
  #pragma unroll
  for (int o = 1; o < 16; o <<= 1)
    #pragma unroll
    for (int r = 0; r < 4; ++r) sm[r] += __shfl_xor(sm[r], o);
  float inv[4];
  #pragma unroll
  for (int r = 0; r < 4; ++r) inv[r] = 1.f / sm[r];

  f32x4 oacc[7] = {};
  #pragma unroll
  for (int c = 0; c < 5; ++c){
    const int kbase = c*64;
    const int nk = (c == 4) ? (ENCT - 256) : 64;
    __syncthreads();
    #pragma unroll
    for (int it = 0; it < 4; ++it){
      int li = it*256 + threadIdx.x;
      if (li < 896){
        int key = li/14, d0 = (li%14)*8;
        if (key < nk){
          bf16x8 vv = *reinterpret_cast<const bf16x8*>(v2 + (size_t)(kbase+key)*DIMC + h*HDIM + d0);
          #pragma unroll
          for (int j = 0; j < 8; ++j) Vl[d0+j][key] = (unsigned short)vv[j];
        } else {
          #pragma unroll
          for (int j = 0; j < 8; ++j) Vl[d0+j][key] = 0;
        }
      }
    }
    #pragma unroll
    for (int nt = 0; nt < 4; ++nt)
      #pragma unroll
      for (int r = 0; r < 4; ++r)
        Pl[w][lk*4 + r][nt*16 + l16] = f2bf(lg[c][nt][r]);
    __syncthreads();
    #pragma unroll
    for (int ks = 0; ks < 2; ++ks){
      bf16x8 pf = *reinterpret_cast<const bf16x8*>(&Pl[w][l16][ks*32 + lk*8]);
      #pragma unroll
      for (int n = 0; n < 7; ++n){
        bf16x8 vf = *reinterpret_cast<const bf16x8*>(&Vl[n*16 + l16][ks*32 + lk*8]);
        oacc[n] = __builtin_amdgcn_mfma_f32_16x16x32_bf16(pf, vf, oacc[n], 0, 0, 0);
      }
    }
  }

  const int orow = blockIdx.x*64 + w*16 + lk*4;
  #pragma unroll
  for (int n = 0; n < 7; ++n)
    #pragma unroll
    for (int r = 0; r < 4; ++r)
      outb[(size_t)(orow + r)*DIMC + h*HDIM + n*16 + l16] = f2bf(oacc[n][r]*inv[r]);
}

// ------- depthwise 3x3 + bias + GLU(silu): 2 ch x 4 rows x 2 cols per thread ----------
// grid.x = f(8) x ytile(4) x xpair(14) = 448, grid.y = 14
__global__ __launch_bounds__(256) void dw_k(const unsigned short* __restrict__ y1,
    const float* __restrict__ dw, const float* __restrict__ db, unsigned short* __restrict__ y2)
{
  int c = (blockIdx.y*256 + threadIdx.x)*2;
  if (c >= HID1) return;
  int bx = blockIdx.x;
  int xp = bx % 14;
  int yt = (bx / 14) & 3;
  int f  = bx / 56;
  int x0 = xp*2, y0 = yt*4;

  float wa[9][2], wg[9][2];
  #pragma unroll
  for (int tp = 0; tp < 9; ++tp){
    float2 va = *reinterpret_cast<const float2*>(dw + tp*HID2 + c);
    float2 vg = *reinterpret_cast<const float2*>(dw + tp*HID2 + c + HID1);
    wa[tp][0] = va.x; wa[tp][1] = va.y;
    wg[tp][0] = vg.x; wg[tp][1] = vg.y;
  }
  float2 ba = *reinterpret_cast<const float2*>(db + c);
  float2 bg = *reinterpret_cast<const float2*>(db + c + HID1);
  float a[4][2][2], g[4][2][2];
  #pragma unroll
  for (int r = 0; r < 4; ++r)
    #pragma unroll
    for (int cc = 0; cc < 2; ++cc){
      a[r][cc][0] = ba.x; a[r][cc][1] = ba.y;
      g[r][cc][0] = bg.x; g[r][cc][1] = bg.y;
    }

  #pragma unroll
  for (int dy6 = 0; dy6 < 6; ++dy6){
    int y = y0 - 1 + dy6;
    if ((unsigned)y >= 16u) continue;
    #pragma unroll
    for (int dxc = 0; dxc < 4; ++dxc){
      int x = x0 - 1 + dxc;
      if ((unsigned)x >= 28u) continue;
      size_t base = ((size_t)(f*16 + y)*28 + x)*HID2;
      unsigned int a01 = *reinterpret_cast<const unsigned int*>(y1 + base + c);
      unsigned int g01 = *reinterpret_cast<const unsigned int*>(y1 + base + c + HID1);
      float fa0 = bf2f((unsigned short)(a01 & 0xffffu));
      float fa1 = bf2f((unsigned short)(a01 >> 16));
      float fg0 = bf2f((unsigned short)(g01 & 0xffffu));
      float fg1 = bf2f((unsigned short)(g01 >> 16));
      #pragma unroll
      for (int r = 0; r < 4; ++r){
        int kdy = dy6 - r;                    // compile-time after unroll
        if (kdy < 0 || kdy > 2) continue;
        #pragma unroll
        for (int cc = 0; cc < 2; ++cc){
          int kdx = dxc - cc;
          if (kdx < 0 || kdx > 2) continue;
          int tp = kdy*3 + kdx;
          a[r][cc][0] += fa0*wa[tp][0]; a[r][cc][1] += fa1*wa[tp][1];
          g[r][cc][0] += fg0*wg[tp][0]; g[r][cc][1] += fg1*wg[tp][1];
        }
      }
    }
  }
  #pragma unroll
  for (int r = 0; r < 4; ++r)
    #pragma unroll
    for (int cc = 0; cc < 2; ++cc){
      float s0 = g[r][cc][0] / (1.f + __expf(-g[r][cc][0]));
      float s1 = g[r][cc][1] / (1.f + __expf(-g[r][cc][1]));
      int pos = (f*16 + y0 + r)*28 + x0 + cc;
      unsigned int o = (unsigned int)f2bf(a[r][cc][0]*s0) | ((unsigned int)f2bf(a[r][cc][1]*s1) << 16);
      *reinterpret_cast<unsigned int*>(y2 + (size_t)pos*HID1 + c) = o;
    }
}

// ---------------- final: out = x2 + g_mlp*(y3 + tc), 4 elems/thread ----------------
__global__ void final_k(const float* __restrict__ x2, const unsigned short* __restrict__ y3,
    const float* __restrict__ tc, const float* __restrict__ mods, float* __restrict__ out)
{
  int i4 = (blockIdx.x*256 + threadIdx.x)*4;
  if (i4 >= SD) return;
  int d = i4 % DIMC;
  float4 xv = *reinterpret_cast<const float4*>(x2 + i4);
  float4 tv = *reinterpret_cast<const float4*>(tc + i4);
  float4 gv = *reinterpret_cast<const float4*>(mods + 5*DIMC + d);
  ushort4 yv = *reinterpret_cast<const ushort4*>(y3 + i4);
  float4 o;
  o.x = xv.x + gv.x*(bf2f(yv.x) + tv.x);
  o.y = xv.y + gv.y*(bf2f(yv.y) + tv.y);
  o.z = xv.z + gv.z*(bf2f(yv.z) + tv.z);
  o.w = xv.w + gv.w*(bf2f(yv.w) + tv.w);
  *reinterpret_cast<float4*>(out + i4) = o;
}

extern "C" void kernel_launch(void* const* d_in, const int* in_sizes, int n_in,
                              void* d_out, int out_size, void* d_ws, size_t ws_size,
                              hipStream_t stream)
{
  const float* hid   = (const float*)d_in[0];
  const float* enc   = (const float*)d_in[1];
  const float* tstep = (const float*)d_in[2];
  const float* fcos  = (const float*)d_in[3];
  const float* fsin  = (const float*)d_in[4];
  const float* sst   = (const float*)d_in[5];
  const float *a1_qw=(const float*)d_in[6],  *a1_qb=(const float*)d_in[7];
  const float *a1_kw=(const float*)d_in[8],  *a1_kb=(const float*)d_in[9];
  const float *a1_vw=(const float*)d_in[10], *a1_vb=(const float*)d_in[11];
  const float *a1_nq=(const float*)d_in[12], *a1_nk=(const float*)d_in[13];
  const float *a1_ow=(const float*)d_in[14], *a1_ob=(const float*)d_in[15];
  const float *a2_qw=(const float*)d_in[16], *a2_qb=(const float*)d_in[17];
  const float *a2_kw=(const float*)d_in[18], *a2_kb=(const float*)d_in[19];
  const float *a2_vw=(const float*)d_in[20], *a2_vb=(const float*)d_in[21];
  const float *a2_nq=(const float*)d_in[22], *a2_nk=(const float*)d_in[23];
  const float *a2_ow=(const float*)d_in[24], *a2_ob=(const float*)d_in[25];
  const float *ff_inv_w=(const float*)d_in[26], *ff_inv_b=(const float*)d_in[27];
  const float *ff_dw=(const float*)d_in[28], *ff_db=(const float*)d_in[29];
  const float *ff_pw=(const float*)d_in[30];
  const float *ff_tw=(const float*)d_in[31];
  float* out = (float*)d_out;

  // ---- workspace plan (~213 MB total; all sizes 256-multiple) ----
  const size_t SLOTB = (size_t)SD*2;        // 16,056,320 B  (one bf16 S x DIM slot)
  char* ws = (char*)d_ws;
  size_t off = 0;
  auto alloc = [&](size_t n){ void* p = ws + off; off += (n + 255) & ~(size_t)255; return p; };

  char* P = (char*)alloc(6*SLOTB);          // 6 bf16 activation slots (96.3 MB)
  float* x1    = (float*)alloc((size_t)SD*4);     // fp32 residual (32.1 MB)
  unsigned short* nh2b = (unsigned short*)alloc(SLOTB); // MUST follow x1 (y2b spans both)
  float* x2    = (float*)alloc((size_t)SD*4);
  unsigned short* k2b = (unsigned short*)alloc((size_t)ENCT*DIMC*2);  // k2b+v2b contiguous
  unsigned short* v2b = (unsigned short*)alloc((size_t)ENCT*DIMC*2);
  unsigned short* encb = (unsigned short*)alloc((size_t)ENCT*DIMC*2);
  float* modsb = (float*)alloc(6*DIMC*4);
  float* ksum  = (float*)alloc(DIMC*4);
  float* kpart = (float*)alloc((size_t)28*DIMC*4);
  float* denom = (float*)alloc((size_t)STOK*NH*4);
  unsigned short* scorb = (unsigned short*)alloc((size_t)NH*HDIM*HDIM*2);
  float* bias3 = (float*)alloc(3*2304*4);
  unsigned short* Wbig = (unsigned short*)alloc((size_t)6912*DIMC*2);  // 31 MB weight staging

  // P-slot aliases (lifetimes verified disjoint)
  unsigned short* P0 = (unsigned short*)P;                 // nhb | y1b[0:] | y3b
  unsigned short* P1 = (unsigned short*)(P + 1*SLOTB);     // qb | spart | lob | y1b | tc[0:]
  unsigned short* P2 = (unsigned short*)(P + 2*SLOTB);     // kb | spart | x1b | y1b | tc[1:]
  unsigned short* P3 = (unsigned short*)(P + 3*SLOTB);     // vb | q2b | y1b
  unsigned short* P4 = (unsigned short*)(P + 4*SLOTB);     // qrb | crb | y1b
  unsigned short* P5 = (unsigned short*)(P + 5*SLOTB);     // krb | y1b
  unsigned short* nhb = P0;
  unsigned short* y1b = P0;                                // 96.34 MB = slots 0..5 exactly
  unsigned short* y2b = (unsigned short*)x1;               // 48.17 MB = x1 + nh2b exactly
  unsigned short* y3b = P0;
  float* tc = (float*)(P + 1*SLOTB);                       // 32.1 MB = slots 1..2
  float* spart = (float*)P1;   // 28 x NH x 112 x 112 fp32 = 28.1 MB, q/k dead by then

  auto cvt = [&](const float* s, unsigned short* d, size_t n){
    int n4 = (int)(n/4);
    cvt_k<<<dim3((n4+255)/256), 256, 0, stream>>>((const float4*)s, (ushort4*)d, n4);
  };
  auto cvtT = [&](const float* s, unsigned short* d, int rows, int ldsrc, int c0, int nc, int ncPad){
    cvt_t_k<<<dim3(ncPad/32, rows/32), 256, 0, stream>>>(s, d, rows, ldsrc, c0, nc);
  };
  auto gemm_grid = [&](int M, int Npad){ return dim3(Npad/128, (M+127)/128); };

  mods_k<<<dim3((6*DIMC+255)/256), 256, 0, stream>>>(sst, tstep, modsb);
  cvt(enc, encb, (size_t)ENCT*DIMC);

  // ---- attn1: fused QKV ----
  ln_mod_k<<<dim3(STOK), 256, 0, stream>>>(hid, modsb, 0, 1, nhb);
  pack3_k<<<dim3((3*2304+255)/256), 256, 0, stream>>>(bias3, a1_qb, a1_kb, a1_vb, 3);
  cvtT(a1_qw, Wbig + (size_t)0*2304*DIMC, DIMC, DIMC, 0, DIMC, 2304);
  cvtT(a1_kw, Wbig + (size_t)1*2304*DIMC, DIMC, DIMC, 0, DIMC, 2304);
  cvtT(a1_vw, Wbig + (size_t)2*2304*DIMC, DIMC, DIMC, 0, DIMC, 2304);
  gemm_bt<6><<<gemm_grid(STOK, 6912), 256, 0, stream>>>(nhb, Wbig, bias3, nullptr, P1,
                                                        nullptr, nullptr, STOK, 6912, DIMC, SD, 6);
  rms_bf_k<1,1><<<dim3(STOK), 256, 0, stream>>>(P1, a1_nq, fcos, fsin, P4);
  rms_bf_k<1,1><<<dim3(STOK), 256, 0, stream>>>(P2, a1_nk, fcos, fsin, P5);
  colsum_k<<<dim3(9, 28), 256, 0, stream>>>(P2, kpart);
  ksumred_k<<<dim3(9), 256, 0, stream>>>(kpart, ksum);
  denom_k<<<dim3(STOK), 256, 0, stream>>>(P1, ksum, denom);
  // q (P1) and k (P2) are dead now -> spart may overwrite them
  scores_k<<<dim3(NH, 28), 256, 0, stream>>>(P3, P5, spart);
  scred_k<<<dim3((NH*HDIM*HDIM+255)/256), 256, 0, stream>>>(spart, scorb);
  linout_k<<<dim3(STOK/64, NH), 256, 0, stream>>>(P4, scorb, denom, P1);   // lob -> P1
  dim3 gMN = gemm_grid(STOK, 2304);
  cvtT(a1_ow, Wbig, DIMC, DIMC, 0, DIMC, 2304);
  gemm_bt<3><<<gMN, 256, 0, stream>>>(P1, Wbig, a1_ob, x1, P2, hid, modsb + 2*DIMC, STOK, DIMC, DIMC, DIMC, 6);

  // ---- cross attn ----
  cvtT(a2_qw, Wbig, DIMC, DIMC, 0, DIMC, 2304);
  gemm_bt<2><<<gMN, 256, 0, stream>>>(P2, Wbig, a2_qb, nullptr, P3, nullptr, nullptr, STOK, DIMC, DIMC, DIMC, 6);
  pack3_k<<<dim3((2*2304+255)/256), 256, 0, stream>>>(bias3, a2_kb, a2_vb, a2_vb, 2);
  cvtT(a2_kw, Wbig + (size_t)0*2304*DIMC, DIMC, DIMC, 0, DIMC, 2304);
  cvtT(a2_vw, Wbig + (size_t)1*2304*DIMC, DIMC, DIMC, 0, DIMC, 2304);
  gemm_bt<6><<<gemm_grid(ENCT, 4608), 256, 0, stream>>>(encb, Wbig, bias3, nullptr, k2b,
                                                        nullptr, nullptr, ENCT, 4608, DIMC, ENCT*DIMC, 6);
  rms_bf_k<0,0><<<dim3(STOK), 256, 0, stream>>>(P3, a2_nq, nullptr, nullptr, nullptr);
  rms_bf_k<0,0><<<dim3(ENCT), 256, 0, stream>>>(k2b, a2_nk, nullptr, nullptr, nullptr);
  xattn_k<<<dim3(STOK/64, NH), 256, 0, stream>>>(P3, k2b, v2b, P4);   // crb -> P4
  cvtT(a2_ow, Wbig, DIMC, DIMC, 0, DIMC, 2304);
  gemm_bt<4><<<gMN, 256, 0, stream>>>(P4, Wbig, a2_ob, x2, nullptr, x1, nullptr, STOK, DIMC, DIMC, DIMC, 6);

  // ---- FF ----
  ln_mod_k<<<dim3(STOK), 256, 0, stream>>>(x2, modsb, 3, 4, nh2b);
  for (int q = 0; q < 2; ++q){                 // ff_inv in 2 column slices of 6720
    int c0 = q*6720;
    cvtT(ff_inv_w, Wbig, DIMC, HID2, c0, 6720, 6912);
    gemm_bt<1><<<gemm_grid(STOK, 6912), 256, 0, stream>>>(nh2b, Wbig, ff_inv_b + c0, nullptr, y1b + c0,
                                                          nullptr, nullptr, STOK, 6720, DIMC, HID2, 6);
  }
  dw_k<<<dim3(448, 14), 256, 0, stream>>>(y1b, ff_dw, ff_db, y2b);
  cvtT(ff_pw, Wbig, HID1, DIMC, 0, DIMC, 2304);   // point conv in one GEMM (K=6720)
  gemm_bt<2><<<gMN, 256, 0, stream>>>(y2b, Wbig, nullptr, nullptr, y3b,
                                      nullptr, nullptr, STOK, DIMC, HID1, DIMC, 2);
  // temporal conv: tc = y3 @ W1 (center) then shifted accumulates
  cvtT(ff_tw + (size_t)DD, Wbig, DIMC, DIMC, 0, DIMC, 2304);
  gemm_bt<0><<<gMN, 256, 0, stream>>>(y3b, Wbig, nullptr, tc, nullptr, nullptr, nullptr, STOK, DIMC, DIMC, DIMC, 6);
  dim3 gT = gemm_grid(3136, 2304);
  cvtT(ff_tw, Wbig, DIMC, DIMC, 0, DIMC, 2304);
  gemm_bt<5><<<gT, 256, 0, stream>>>(y3b, Wbig, nullptr, tc + (size_t)448*DIMC, nullptr, nullptr, nullptr, 3136, DIMC, DIMC, DIMC, 6);
  cvtT(ff_tw + (size_t)2*DD, Wbig, DIMC, DIMC, 0, DIMC, 2304);
  gemm_bt<5><<<gT, 256, 0, stream>>>(y3b + (size_t)448*DIMC, Wbig, nullptr, tc, nullptr, nullptr, nullptr, 3136, DIMC, DIMC, DIMC, 6);

  // out = x2 + g_mlp*(y3 + tc)
  final_k<<<dim3((SD/4+255)/256), 256, 0, stream>>>(x2, y3b, tc, modsb, out);
}

// Round 11
// 1359.869 us; speedup vs baseline: 1.2542x; 1.0930x over previous
//
#include <hip/hip_runtime.h>

#define DIMC 2240
#define STOK 3584
#define ENCT 300
#define NH   20
#define HDIM 112
#define HID1 6720
#define HID2 13440
#define DD   (2240*2240)
#define SD   (3584*2240)

typedef short bf16x8 __attribute__((ext_vector_type(8)));   // guide-verified operand type
typedef float f32x4  __attribute__((ext_vector_type(4)));

__device__ __forceinline__ unsigned short f2bf(float f){
  unsigned int u = __float_as_uint(f);
  u += 0x7fffu + ((u >> 16) & 1u);          // RNE
  return (unsigned short)(u >> 16);
}
__device__ __forceinline__ float bf2f(unsigned short h){
  return __uint_as_float(((unsigned int)h) << 16);
}
__device__ __forceinline__ void gl_lds16(const unsigned short* g, unsigned short* l){
  __builtin_amdgcn_global_load_lds(
      (const __attribute__((address_space(1))) unsigned int*)(const void*)g,
      (__attribute__((address_space(3))) unsigned int*)(void*)l, 16, 0, 0);
}

// ---------------- fp32 -> bf16 convert (flat) ----------------
__global__ void cvt_k(const float4* __restrict__ src, ushort4* __restrict__ dst, int n4){
  int i = blockIdx.x*256 + threadIdx.x;
  if (i < n4){
    float4 v = src[i];
    ushort4 o; o.x = f2bf(v.x); o.y = f2bf(v.y); o.z = f2bf(v.z); o.w = f2bf(v.w);
    dst[i] = o;
  }
}

// -- fp32 (rows x cols slice) -> bf16 TRANSPOSED [ncPad][ldd], zero-padded, multi-src --
// blockIdx.z selects src s0/s1/s2; dst offset z*dzoff. dst[n*ldd + k].
__global__ __launch_bounds__(256) void cvtT3_k(const float* __restrict__ s0,
    const float* __restrict__ s1, const float* __restrict__ s2,
    unsigned short* __restrict__ dst, int rows, int ldsrc, int c0, int nc,
    int ldd, long long dzoff){
  const float* src = (blockIdx.z == 0) ? s0 : ((blockIdx.z == 1) ? s1 : s2);
  unsigned short* d = dst + (size_t)blockIdx.z * (size_t)dzoff;
  __shared__ float tile[32][33];
  const int tx = threadIdx.x & 31, ty = threadIdx.x >> 5;   // ty 0..7
  const int colBase = blockIdx.x*32;
  #pragma unroll
  for (int i = 0; i < 4; ++i){
    int rr = blockIdx.y*32 + ty + i*8;
    int cc = colBase + tx;
    tile[ty + i*8][tx] = (cc < nc) ? src[(size_t)rr*ldsrc + c0 + cc] : 0.f;
  }
  __syncthreads();
  #pragma unroll
  for (int i = 0; i < 4; ++i){
    int n = colBase + ty + i*8;          // < ncPad by grid
    int k = blockIdx.y*32 + tx;
    d[(size_t)n*ldd + k] = f2bf(tile[tx][ty + i*8]);
  }
}

// ---------------- zero the two 448-row margins of y3pad ----------------
__global__ void zpad_k(unsigned short* __restrict__ m0, unsigned short* __restrict__ m1){
  int i = blockIdx.x*256 + threadIdx.x;       // uint4 index; 448*2240/8 = 125440
  if (i < 125440){
    reinterpret_cast<uint4*>(m0)[i] = make_uint4(0u,0u,0u,0u);
    reinterpret_cast<uint4*>(m1)[i] = make_uint4(0u,0u,0u,0u);
  }
}

// ---------------- pack up to 3 biases into [nslots][2304] (zero pad) ----------------
__global__ void pack3_k(float* __restrict__ dst, const float* __restrict__ b0,
    const float* __restrict__ b1, const float* __restrict__ b2, int nslots){
  int i = blockIdx.x*256 + threadIdx.x;
  if (i >= nslots*2304) return;
  int slot = i / 2304, d = i - slot*2304;
  const float* src = (slot == 0) ? b0 : ((slot == 1) ? b1 : b2);
  dst[i] = (d < 2240) ? src[d] : 0.f;
}

// ---------------- mods = scale_shift_table + timestep ----------------
__global__ void mods_k(const float* __restrict__ sst, const float* __restrict__ ts, float* __restrict__ mods){
  int i = blockIdx.x*256 + threadIdx.x;
  if (i < 6*DIMC) mods[i] = sst[i] + ts[i];
}

// ---------------- LayerNorm * (1+sc) + sh -> bf16 (float4-vectorized) ----------------
__global__ __launch_bounds__(256) void ln_mod_k(const float* __restrict__ x,
    const float* __restrict__ mods, int shj, int scj, unsigned short* __restrict__ out)
{
  const int s = blockIdx.x;
  const float4* row4 = reinterpret_cast<const float4*>(x + (size_t)s*DIMC);
  const float4* sh4 = reinterpret_cast<const float4*>(mods + shj*DIMC);
  const float4* sc4 = reinterpret_cast<const float4*>(mods + scj*DIMC);
  float sum = 0.f, sq = 0.f;
  for (int o = threadIdx.x; o < 560; o += 256){
    float4 v = row4[o];
    sum += v.x + v.y + v.z + v.w;
    sq  += v.x*v.x + v.y*v.y + v.z*v.z + v.w*v.w;
  }
  #pragma unroll
  for (int o = 32; o; o >>= 1){ sum += __shfl_down(sum, o); sq += __shfl_down(sq, o); }
  __shared__ float sA[4], sB[4];
  int w = threadIdx.x >> 6, l = threadIdx.x & 63;
  if (!l){ sA[w] = sum; sB[w] = sq; }
  __syncthreads();
  sum = sA[0]+sA[1]+sA[2]+sA[3];
  sq  = sB[0]+sB[1]+sB[2]+sB[3];
  float mean = sum * (1.f/DIMC);
  float rs = rsqrtf(sq*(1.f/DIMC) - mean*mean + 1e-6f);
  unsigned short* orow = out + (size_t)s*DIMC;
  for (int o = threadIdx.x; o < 560; o += 256){
    float4 v = row4[o], sc = sc4[o], sh = sh4[o];
    ushort4 r;
    r.x = f2bf((v.x-mean)*rs*(1.f + sc.x) + sh.x);
    r.y = f2bf((v.y-mean)*rs*(1.f + sc.y) + sh.y);
    r.z = f2bf((v.z-mean)*rs*(1.f + sc.z) + sh.z);
    r.w = f2bf((v.w-mean)*rs*(1.f + sc.w) + sh.w);
    *reinterpret_cast<ushort4*>(orow + o*4) = r;
  }
}

// ---------------- RMS on bf16 rows (optional ReLU / RoPE), uint4-vectorized ----------
template<int RELU, int ROPE>
__global__ __launch_bounds__(256) void rms_bf_k(unsigned short* __restrict__ x, const float* __restrict__ nw,
    const float* __restrict__ cosb, const float* __restrict__ sinb, unsigned short* __restrict__ xr)
{
  const int s = blockIdx.x;
  unsigned short* row = x + (size_t)s*DIMC;
  float sq = 0.f;
  for (int o = threadIdx.x; o < 280; o += 256){     // 280 octets of 8 bf16
    uint4 v = *reinterpret_cast<const uint4*>(row + o*8);
    unsigned int uu[4] = {v.x, v.y, v.z, v.w};
    #pragma unroll
    for (int j = 0; j < 4; ++j){
      float lo = bf2f((unsigned short)(uu[j] & 0xffffu));
      float hi = bf2f((unsigned short)(uu[j] >> 16));
      sq += lo*lo + hi*hi;
    }
  }
  #pragma unroll
  for (int o = 32; o; o >>= 1) sq += __shfl_down(sq, o);
  __shared__ float sB[4];
  int w = threadIdx.x >> 6, l = threadIdx.x & 63;
  if (!l) sB[w] = sq;
  __syncthreads();
  sq = sB[0]+sB[1]+sB[2]+sB[3];
  float rs = rsqrtf(sq*(1.f/DIMC) + 1e-5f);
  for (int o = threadIdx.x; o < 280; o += 256){
    uint4 v = *reinterpret_cast<const uint4*>(row + o*8);
    unsigned int uu[4] = {v.x, v.y, v.z, v.w};
    float4 n0 = *reinterpret_cast<const float4*>(nw + o*8);
    float4 n1 = *reinterpret_cast<const float4*>(nw + o*8 + 4);
    float nn[8] = {n0.x,n0.y,n0.z,n0.w,n1.x,n1.y,n1.z,n1.w};
    float vals[8];
    #pragma unroll
    for (int j = 0; j < 4; ++j){
      vals[2*j]   = bf2f((unsigned short)(uu[j] & 0xffffu))*rs*nn[2*j];
      vals[2*j+1] = bf2f((unsigned short)(uu[j] >> 16))*rs*nn[2*j+1];
    }
    if constexpr (RELU){
      #pragma unroll
      for (int j = 0; j < 8; ++j) vals[j] = fmaxf(vals[j], 0.f);
    }
    uint4 o1;
    unsigned int* po = &o1.x;
    #pragma unroll
    for (int j = 0; j < 4; ++j)
      po[j] = (unsigned int)f2bf(vals[2*j]) | ((unsigned int)f2bf(vals[2*j+1]) << 16);
    *reinterpret_cast<uint4*>(row + o*8) = o1;
    if constexpr (ROPE){
      int jb = (o*8) % HDIM;                      // octet stays within a head (112%8==0)
      uint4 o2;
      unsigned int* pr = &o2.x;
      #pragma unroll
      for (int p = 0; p < 4; ++p){
        float c  = cosb[(size_t)s*HDIM + jb + 2*p];
        float sn = sinb[(size_t)s*HDIM + jb + 2*p + 1];
        float r0 = vals[2*p]*c - vals[2*p+1]*sn;
        float r1 = vals[2*p]*sn + vals[2*p+1]*c;
        pr[p] = (unsigned int)f2bf(r0) | ((unsigned int)f2bf(r1) << 16);
      }
      *reinterpret_cast<uint4*>(xr + (size_t)s*DIMC + o*8) = o2;
    }
  }
}

// ------- bf16 MFMA GEMM: C = A(MxK) @ Bt^T, Bt is [Npad][K] (N-major), BK=64 ---------
// (round-7 proven structure) Both-sides swizzle; K % 64 == 0; PW | gridDim.x.
// lda: A row stride. tcsh=1: temporal-conv mode — K-section sec (2240 wide) reads A at
// row + sec*448; A must point at the PADDED base (row 0 = center_row - 448).
// EPI: 0 Cf=acc+bias | 1 Cb=bf16(silu(acc+bias)) | 2 Cb=bf16(acc+bias)
//      3 u=res+gate*(acc+bias); Cf=u; Cb=bf16(u) | 4 Cf=res+acc+bias | 5 Cf+=acc
//      6 slot-split: slot=col/2304, d=col%2304; if d<2240: Cb[slot*ldc + row*2240 + d]
template<int EPI>
__global__ __launch_bounds__(256) void gemm_bt(
  const unsigned short* __restrict__ A, const unsigned short* __restrict__ Bt,
  const float* __restrict__ bias, float* __restrict__ Cf, unsigned short* __restrict__ Cb,
  const float* __restrict__ res, const float* __restrict__ gate,
  int M, int N, int K, int ldc, int PW, int lda, int tcsh)
{
  __shared__ __align__(16) unsigned short Al[128*64];
  __shared__ __align__(16) unsigned short Bl[128*64];
  const int gx = gridDim.x, gy = gridDim.y;
  const int nwg = gx*gy;
  const int orig = blockIdx.y*gx + blockIdx.x;
  // bijective XCD-aware remap (m204)
  const int qq = nwg >> 3, rr = nwg & 7;
  const int xcd = orig & 7, li = orig >> 3;
  const int wg = (xcd < rr ? xcd*(qq+1) : rr*(qq+1) + (xcd-rr)*qq) + li;
  // N-panel rasterization: panel of PW n-tiles covers all gy m-rows before advancing
  const int ppw = gy*PW;
  const int panel = wg / ppw, rm = wg - panel*ppw;
  const int mrow = rm / PW;
  const int m0 = mrow*128;
  const int n0 = (panel*PW + (rm - mrow*PW))*128;

  const int t = threadIdx.x, lane = t & 63, w = t >> 6;
  const int wr = w >> 1, wc = w & 1;
  const int l16 = lane & 15, lk = lane >> 4;

  // staging: per wave 4 A-chunks + 4 B-chunks (each 1KB = 8 rows x 128B), swizzled src
  const int lr8 = lane >> 3;           // row within 8-row block (== row&7)
  const int sc  = (lane & 7) ^ lr8;    // pre-swizzled source chunk
  const unsigned short* Aps[4];
  const unsigned short* Bps[4];
  #pragma unroll
  for (int i = 0; i < 4; ++i){
    int ar = m0 + w*32 + i*8 + lr8;
    int br = n0 + w*32 + i*8 + lr8;
    Aps[i] = A  + (size_t)min(ar, M-1)*lda + sc*8;
    Bps[i] = Bt + (size_t)br*K + sc*8;
  }
  unsigned short* Ad = Al + w*2048;
  unsigned short* Bd = Bl + w*2048;

  f32x4 acc[4][4] = {};
  for (int k0 = 0; k0 < K; k0 += 64){
    size_t aoff;
    if (tcsh){
      int sec = (k0 >= 4480) ? 2 : ((k0 >= 2240) ? 1 : 0);
      aoff = (size_t)(sec*448)*lda + (unsigned)(k0 - sec*2240);
    } else {
      aoff = (size_t)k0;
    }
    __syncthreads();
    #pragma unroll
    for (int i = 0; i < 4; ++i){
      gl_lds16(Aps[i] + aoff, Ad + i*512);
      gl_lds16(Bps[i] + k0,   Bd + i*512);
    }
    __syncthreads();
    #pragma unroll
    for (int kk = 0; kk < 2; ++kk){
      bf16x8 af[4], bfr[4];
      const int chb = (kk*4 + lk) ^ (l16 & 7);   // swizzled read chunk
      #pragma unroll
      for (int m = 0; m < 4; ++m)
        af[m] = *reinterpret_cast<const bf16x8*>(Al + (wr*64 + m*16 + l16)*64 + chb*8);
      #pragma unroll
      for (int n = 0; n < 4; ++n)
        bfr[n] = *reinterpret_cast<const bf16x8*>(Bl + (wc*64 + n*16 + l16)*64 + chb*8);
      #pragma unroll
      for (int m = 0; m < 4; ++m)
        #pragma unroll
        for (int n = 0; n < 4; ++n)
          acc[m][n] = __builtin_amdgcn_mfma_f32_16x16x32_bf16(af[m], bfr[n], acc[m][n], 0, 0, 0);
    }
  }

  const int rb = m0 + wr*64 + lk*4;   // C/D: col = lane&15, row = (lane>>4)*4 + reg
  const int cb = n0 + wc*64 + l16;
  #pragma unroll
  for (int m = 0; m < 4; ++m){
    #pragma unroll
    for (int r = 0; r < 4; ++r){
      int row = rb + m*16 + r;
      if (row >= M) continue;
      #pragma unroll
      for (int n = 0; n < 4; ++n){
        int col = cb + n*16;
        if (col >= N) continue;
        float v = acc[m][n][r];
        float bv = bias ? bias[col] : 0.f;
        if constexpr (EPI == 6){
          int slot = col / 2304;
          int d = col - slot*2304;
          if (d < 2240)
            Cb[(size_t)slot*ldc + (size_t)row*2240 + d] = f2bf(v + bv);
        } else {
          size_t idx = (size_t)row*ldc + col;
          if constexpr (EPI == 0){ Cf[idx] = v + bv; }
          else if constexpr (EPI == 1){ float u = v + bv; Cb[idx] = f2bf(u / (1.f + __expf(-u))); }
          else if constexpr (EPI == 2){ Cb[idx] = f2bf(v + bv); }
          else if constexpr (EPI == 3){ float u = res[idx] + gate[col]*(v + bv); Cf[idx] = u; Cb[idx] = f2bf(u); }
          else if constexpr (EPI == 4){ Cf[idx] = res[idx] + v + bv; }
          else { Cf[idx] += v; }
        }
      }
    }
  }
}

// ---------------- linear attention helpers ----------------
__global__ void colsum_k(const unsigned short* __restrict__ k, float* __restrict__ kpart){
  int d = blockIdx.x*256 + threadIdx.x;
  if (d >= DIMC) return;
  int ch = blockIdx.y, s0 = ch*128;
  float acc = 0.f;
  for (int s = s0; s < s0+128; ++s) acc += bf2f(k[(size_t)s*DIMC + d]);
  kpart[(size_t)ch*DIMC + d] = acc;
}
__global__ void ksumred_k(const float* __restrict__ kpart, float* __restrict__ ksum){
  int d = blockIdx.x*256 + threadIdx.x;
  if (d >= DIMC) return;
  float a = 0.f;
  for (int c = 0; c < 28; ++c) a += kpart[(size_t)c*DIMC + d];
  ksum[d] = a;
}
__global__ __launch_bounds__(256) void denom_k(const unsigned short* __restrict__ q,
    const float* __restrict__ ksum, float* __restrict__ denom)
{
  int s = blockIdx.x; int w = threadIdx.x >> 6, l = threadIdx.x & 63;
  for (int h = w; h < NH; h += 4){
    const unsigned short* qb = q + (size_t)s*DIMC + h*HDIM;
    const float* kb = ksum + h*HDIM;
    float v = bf2f(qb[l])*kb[l];
    if (l < 48) v += bf2f(qb[64+l])*kb[64+l];
    #pragma unroll
    for (int o = 32; o; o >>= 1) v += __shfl_down(v, o);
    if (!l) denom[s*NH + h] = v + 1e-15f;
  }
}

// -------- MFMA scores: part[ch][h][e][d] = sum_{s in 128-chunk} V[s,h,e]*Kr[s,h,d] -----
#define SLSC 136
__device__ __forceinline__ int sc_idx(int e, int s){
  return e*SLSC + (s ^ (((e >> 3) & 7) << 3));
}
__global__ __launch_bounds__(256) void scores_k(const unsigned short* __restrict__ v,
    const unsigned short* __restrict__ kr, float* __restrict__ part)
{
  const int h = blockIdx.x, ch = blockIdx.y;
  __shared__ __align__(16) unsigned short Vt[112*SLSC];
  __shared__ __align__(16) unsigned short Kt[112*SLSC];
  const int t = threadIdx.x, lane = t & 63, w = t >> 6;
  const int l16 = lane & 15, lk = lane >> 4;
  const int sbase = ch*128;

  for (int p = t; p < 1792; p += 256){       // 128 tokens x 14 dim-octets
    int s = p / 14, oc = (p % 14) * 8;
    bf16x8 vv = *reinterpret_cast<const bf16x8*>(v  + (size_t)(sbase+s)*DIMC + h*HDIM + oc);
    bf16x8 kk = *reinterpret_cast<const bf16x8*>(kr + (size_t)(sbase+s)*DIMC + h*HDIM + oc);
    #pragma unroll
    for (int j = 0; j < 8; ++j){
      Vt[sc_idx(oc+j, s)] = (unsigned short)vv[j];
      Kt[sc_idx(oc+j, s)] = (unsigned short)kk[j];
    }
  }
  __syncthreads();

  f32x4 acc[2][7] = {};                      // wave w owns m-tiles {w, w+4}
  #pragma unroll
  for (int ks = 0; ks < 4; ++ks){
    const int sf = ks*32 + lk*8;
    bf16x8 bfrg[7];
    #pragma unroll
    for (int nt = 0; nt < 7; ++nt){
      int d = nt*16 + l16;
      bfrg[nt] = *reinterpret_cast<const bf16x8*>(&Kt[d*SLSC + (sf ^ (((d >> 3) & 7) << 3))]);
    }
    #pragma unroll
    for (int mi = 0; mi < 2; ++mi){
      int mt = w + mi*4;
      if (mt < 7){
        int e = mt*16 + l16;
        bf16x8 afrg = *reinterpret_cast<const bf16x8*>(&Vt[e*SLSC + (sf ^ (((e >> 3) & 7) << 3))]);
        #pragma unroll
        for (int nt = 0; nt < 7; ++nt)
          acc[mi][nt] = __builtin_amdgcn_mfma_f32_16x16x32_bf16(afrg, bfrg[nt], acc[mi][nt], 0, 0, 0);
      }
    }
  }

  float* pout = part + ((size_t)ch*NH + h)*12544;
  #pragma unroll
  for (int mi = 0; mi < 2; ++mi){
    int mt = w + mi*4;
    if (mt >= 7) continue;
    #pragma unroll
    for (int nt = 0; nt < 7; ++nt)
      #pragma unroll
      for (int r = 0; r < 4; ++r)
        pout[(size_t)(mt*16 + lk*4 + r)*HDIM + nt*16 + l16] = acc[mi][nt][r];
  }
}
__global__ void scred_k(const float* __restrict__ part, unsigned short* __restrict__ sc){
  int i = blockIdx.x*256 + threadIdx.x;
  if (i >= NH*HDIM*HDIM) return;
  float a = 0.f;
  #pragma unroll
  for (int c = 0; c < 28; ++c) a += part[(size_t)c*(NH*HDIM*HDIM) + i];
  sc[i] = f2bf(a);
}

// -------- MFMA linout: out[s,h*112+e] = (sum_d scores[h,e,d]*qr[s,h,d]) / denom[s,h] ---
__global__ __launch_bounds__(256) void linout_k(const unsigned short* __restrict__ qr,
    const unsigned short* __restrict__ scores, const float* __restrict__ denom,
    unsigned short* __restrict__ out)
{
  const int h = blockIdx.y;
  const int t = threadIdx.x, lane = t & 63, w = t >> 6;
  const int l16 = lane & 15, lk = lane >> 4;
  const int s0 = blockIdx.x*64 + w*16;
  const unsigned short* qrow = qr + (size_t)(s0 + l16)*DIMC + h*HDIM;
  const unsigned short* sb = scores + (size_t)h*12544;
  f32x4 acc[7] = {};
  #pragma unroll
  for (int ks = 0; ks < 4; ++ks){
    int d0 = ks*32 + lk*8;
    bf16x8 a = {};
    if (d0 < HDIM) a = *reinterpret_cast<const bf16x8*>(qrow + d0);
    #pragma unroll
    for (int nt = 0; nt < 7; ++nt){
      bf16x8 b = {};
      if (d0 < HDIM) b = *reinterpret_cast<const bf16x8*>(sb + (size_t)(nt*16 + l16)*HDIM + d0);
      acc[nt] = __builtin_amdgcn_mfma_f32_16x16x32_bf16(a, b, acc[nt], 0, 0, 0);
    }
  }
  #pragma unroll
  for (int r = 0; r < 4; ++r){
    int s = s0 + lk*4 + r;
    float dn = 1.f / denom[(size_t)s*NH + h];
    #pragma unroll
    for (int nt = 0; nt < 7; ++nt)
      out[(size_t)s*DIMC + h*HDIM + nt*16 + l16] = f2bf(acc[nt][r]*dn);
  }
}

// ---------------- fused cross-attention, MFMA (300 keys, head dim 112 padded to 128) ----
__global__ __launch_bounds__(256) void xattn_k(
    const unsigned short* __restrict__ q,   // S x DIM bf16 (rms-normed)
    const unsigned short* __restrict__ k2,  // ENCT x DIM bf16 (rms-normed)
    const unsigned short* __restrict__ v2,  // ENCT x DIM bf16
    unsigned short* __restrict__ outb)      // S x DIM bf16
{
  const int h = blockIdx.y;
  const int w = threadIdx.x >> 6, lane = threadIdx.x & 63;
  const int l16 = lane & 15, lk = lane >> 4;
  const float scale = 0.09449111825230679f;   // 1/sqrt(112)

  __shared__ __align__(16) unsigned short Kl[64][136];
  __shared__ __align__(16) unsigned short Vl[112][72];
  __shared__ __align__(16) unsigned short Pl[4][16][72];

  bf16x8 qf[4];
  const unsigned short* qbase = q + (size_t)(blockIdx.x*64 + w*16 + l16)*DIMC + h*HDIM;
  #pragma unroll
  for (int c = 0; c < 4; ++c){
    int d0 = c*32 + lk*8;
    bf16x8 z = {};
    qf[c] = (d0 < HDIM) ? *reinterpret_cast<const bf16x8*>(qbase + d0) : z;
  }

  f32x4 lg[5][4] = {};
  #pragma unroll
  for (int c = 0; c < 5; ++c){
    const int kbase = c*64;
    const int nk = (c == 4) ? (ENCT - 256) : 64;
    __syncthreads();
    #pragma unroll
    for (int it = 0; it < 4; ++it){
      int li = it*256 + threadIdx.x;
      int key = li >> 4, d0 = (li & 15) << 3;
      uint4 val = make_uint4(0u,0u,0u,0u);
      if (key < nk && d0 < HDIM)
        val = *reinterpret_cast<const uint4*>(k2 + (size_t)(kbase+key)*DIMC + h*HDIM + d0);
      *reinterpret_cast<uint4*>(&Kl[key][d0]) = val;
    }
    __syncthreads();
    #pragma unroll
    for (int nt = 0; nt < 4; ++nt){
      #pragma unroll
      for (int ks = 0; ks < 4; ++ks){
        bf16x8 kf = *reinterpret_cast<const bf16x8*>(&Kl[nt*16 + l16][ks*32 + lk*8]);
        lg[c][nt] = __builtin_amdgcn_mfma_f32_16x16x32_bf16(qf[ks], kf, lg[c][nt], 0, 0, 0);
      }
    }
  }

  float mx[4] = {-3e38f, -3e38f, -3e38f, -3e38f};
  #pragma unroll
  for (int c = 0; c < 5; ++c)
    #pragma unroll
    for (int nt = 0; nt < 4; ++nt){
      bool valid = (c*64 + nt*16 + l16) < ENCT;
      #pragma unroll
      for (int r = 0; r < 4; ++r){
        float v = valid ? lg[c][nt][r]*scale : -3e38f;
        lg[c][nt][r] = v;
        mx[r] = fmaxf(mx[r], v);
      }
    }
  #pragma unroll
  for (int o = 1; o < 16; o <<= 1)
    #pragma unroll
    for (int r = 0; r < 4; ++r) mx[r] = fmaxf(mx[r], __shfl_xor(mx[r], o));
  float sm[4] = {0.f, 0.f, 0.f, 0.f};
  #pragma unroll
  for (int c = 0; c < 5; ++c)
    #pragma unroll
    for (int nt = 0; nt < 4; ++nt)
      #pragma unroll
      for (int r = 0; r < 4; ++r){
        float e = __expf(lg[c][nt][r] - mx[r]);
        lg[c][nt][r] = e;
        sm[r] += e;
      }
  #pragma unroll
  for (int o = 1; o < 16; o <<= 1)
    #pragma unroll
    for (int r = 0; r < 4; ++r) sm[r] += __shfl_xor(sm[r], o);
  float inv[4];
  #pragma unroll
  for (int r = 0; r < 4; ++r) inv[r] = 1.f / sm[r];

  f32x4 oacc[7] = {};
  #pragma unroll
  for (int c = 0; c < 5; ++c){
    const int kbase = c*64;
    const int nk = (c == 4) ? (ENCT - 256) : 64;
    __syncthreads();
    #pragma unroll
    for (int it = 0; it < 4; ++it){
      int li = it*256 + threadIdx.x;
      if (li < 896){
        int key = li/14, d0 = (li%14)*8;
        if (key < nk){
          bf16x8 vv = *reinterpret_cast<const bf16x8*>(v2 + (size_t)(kbase+key)*DIMC + h*HDIM + d0);
          #pragma unroll
          for (int j = 0; j < 8; ++j) Vl[d0+j][key] = (unsigned short)vv[j];
        } else {
          #pragma unroll
          for (int j = 0; j < 8; ++j) Vl[d0+j][key] = 0;
        }
      }
    }
    #pragma unroll
    for (int nt = 0; nt < 4; ++nt)
      #pragma unroll
      for (int r = 0; r < 4; ++r)
        Pl[w][lk*4 + r][nt*16 + l16] = f2bf(lg[c][nt][r]);
    __syncthreads();
    #pragma unroll
    for (int ks = 0; ks < 2; ++ks){
      bf16x8 pf = *reinterpret_cast<const bf16x8*>(&Pl[w][l16][ks*32 + lk*8]);
      #pragma unroll
      for (int n = 0; n < 7; ++n){
        bf16x8 vf = *reinterpret_cast<const bf16x8*>(&Vl[n*16 + l16][ks*32 + lk*8]);
        oacc[n] = __builtin_amdgcn_mfma_f32_16x16x32_bf16(pf, vf, oacc[n], 0, 0, 0);
      }
    }
  }

  const int orow = blockIdx.x*64 + w*16 + lk*4;
  #pragma unroll
  for (int n = 0; n < 7; ++n)
    #pragma unroll
    for (int r = 0; r < 4; ++r)
      outb[(size_t)(orow + r)*DIMC + h*HDIM + n*16 + l16] = f2bf(oacc[n][r]*inv[r]);
}

// ------- depthwise 3x3 + bias + GLU(silu): 2 ch x 4 rows x 2 cols per thread ----------
// grid.x = f(8) x ytile(4) x xpair(14) = 448, grid.y = 14
__global__ __launch_bounds__(256) void dw_k(const unsigned short* __restrict__ y1,
    const float* __restrict__ dw, const float* __restrict__ db, unsigned short* __restrict__ y2)
{
  int c = (blockIdx.y*256 + threadIdx.x)*2;
  if (c >= HID1) return;
  int bx = blockIdx.x;
  int xp = bx % 14;
  int yt = (bx / 14) & 3;
  int f  = bx / 56;
  int x0 = xp*2, y0 = yt*4;

  float wa[9][2], wg[9][2];
  #pragma unroll
  for (int tp = 0; tp < 9; ++tp){
    float2 va = *reinterpret_cast<const float2*>(dw + tp*HID2 + c);
    float2 vg = *reinterpret_cast<const float2*>(dw + tp*HID2 + c + HID1);
    wa[tp][0] = va.x; wa[tp][1] = va.y;
    wg[tp][0] = vg.x; wg[tp][1] = vg.y;
  }
  float2 ba = *reinterpret_cast<const float2*>(db + c);
  float2 bg = *reinterpret_cast<const float2*>(db + c + HID1);
  float a[4][2][2], g[4][2][2];
  #pragma unroll
  for (int r = 0; r < 4; ++r)
    #pragma unroll
    for (int cc = 0; cc < 2; ++cc){
      a[r][cc][0] = ba.x; a[r][cc][1] = ba.y;
      g[r][cc][0] = bg.x; g[r][cc][1] = bg.y;
    }

  #pragma unroll
  for (int dy6 = 0; dy6 < 6; ++dy6){
    int y = y0 - 1 + dy6;
    if ((unsigned)y >= 16u) continue;
    #pragma unroll
    for (int dxc = 0; dxc < 4; ++dxc){
      int x = x0 - 1 + dxc;
      if ((unsigned)x >= 28u) continue;
      size_t base = ((size_t)(f*16 + y)*28 + x)*HID2;
      unsigned int a01 = *reinterpret_cast<const unsigned int*>(y1 + base + c);
      unsigned int g01 = *reinterpret_cast<const unsigned int*>(y1 + base + c + HID1);
      float fa0 = bf2f((unsigned short)(a01 & 0xffffu));
      float fa1 = bf2f((unsigned short)(a01 >> 16));
      float fg0 = bf2f((unsigned short)(g01 & 0xffffu));
      float fg1 = bf2f((unsigned short)(g01 >> 16));
      #pragma unroll
      for (int r = 0; r < 4; ++r){
        int kdy = dy6 - r;                    // compile-time after unroll
        if (kdy < 0 || kdy > 2) continue;
        #pragma unroll
        for (int cc = 0; cc < 2; ++cc){
          int kdx = dxc - cc;
          if (kdx < 0 || kdx > 2) continue;
          int tp = kdy*3 + kdx;
          a[r][cc][0] += fa0*wa[tp][0]; a[r][cc][1] += fa1*wa[tp][1];
          g[r][cc][0] += fg0*wg[tp][0]; g[r][cc][1] += fg1*wg[tp][1];
        }
      }
    }
  }
  #pragma unroll
  for (int r = 0; r < 4; ++r)
    #pragma unroll
    for (int cc = 0; cc < 2; ++cc){
      float s0 = g[r][cc][0] / (1.f + __expf(-g[r][cc][0]));
      float s1 = g[r][cc][1] / (1.f + __expf(-g[r][cc][1]));
      int pos = (f*16 + y0 + r)*28 + x0 + cc;
      unsigned int o = (unsigned int)f2bf(a[r][cc][0]*s0) | ((unsigned int)f2bf(a[r][cc][1]*s1) << 16);
      *reinterpret_cast<unsigned int*>(y2 + (size_t)pos*HID1 + c) = o;
    }
}

// ---------------- final: out = x2 + g_mlp*(y3 + tc), 4 elems/thread ----------------
__global__ void final_k(const float* __restrict__ x2, const unsigned short* __restrict__ y3,
    const float* __restrict__ tc, const float* __restrict__ mods, float* __restrict__ out)
{
  int i4 = (blockIdx.x*256 + threadIdx.x)*4;
  if (i4 >= SD) return;
  int d = i4 % DIMC;
  float4 xv = *reinterpret_cast<const float4*>(x2 + i4);
  float4 tv = *reinterpret_cast<const float4*>(tc + i4);
  float4 gv = *reinterpret_cast<const float4*>(mods + 5*DIMC + d);
  ushort4 yv = *reinterpret_cast<const ushort4*>(y3 + i4);
  float4 o;
  o.x = xv.x + gv.x*(bf2f(yv.x) + tv.x);
  o.y = xv.y + gv.y*(bf2f(yv.y) + tv.y);
  o.z = xv.z + gv.z*(bf2f(yv.z) + tv.z);
  o.w = xv.w + gv.w*(bf2f(yv.w) + tv.w);
  *reinterpret_cast<float4*>(out + i4) = o;
}

extern "C" void kernel_launch(void* const* d_in, const int* in_sizes, int n_in,
                              void* d_out, int out_size, void* d_ws, size_t ws_size,
                              hipStream_t stream)
{
  const float* hid   = (const float*)d_in[0];
  const float* enc   = (const float*)d_in[1];
  const float* tstep = (const float*)d_in[2];
  const float* fcos  = (const float*)d_in[3];
  const float* fsin  = (const float*)d_in[4];
  const float* sst   = (const float*)d_in[5];
  const float *a1_qw=(const float*)d_in[6],  *a1_qb=(const float*)d_in[7];
  const float *a1_kw=(const float*)d_in[8],  *a1_kb=(const float*)d_in[9];
  const float *a1_vw=(const float*)d_in[10], *a1_vb=(const float*)d_in[11];
  const float *a1_nq=(const float*)d_in[12], *a1_nk=(const float*)d_in[13];
  const float *a1_ow=(const float*)d_in[14], *a1_ob=(const float*)d_in[15];
  const float *a2_qw=(const float*)d_in[16], *a2_qb=(const float*)d_in[17];
  const float *a2_kw=(const float*)d_in[18], *a2_kb=(const float*)d_in[19];
  const float *a2_vw=(const float*)d_in[20], *a2_vb=(const float*)d_in[21];
  const float *a2_nq=(const float*)d_in[22], *a2_nk=(const float*)d_in[23];
  const float *a2_ow=(const float*)d_in[24], *a2_ob=(const float*)d_in[25];
  const float *ff_inv_w=(const float*)d_in[26], *ff_inv_b=(const float*)d_in[27];
  const float *ff_dw=(const float*)d_in[28], *ff_db=(const float*)d_in[29];
  const float *ff_pw=(const float*)d_in[30];
  const float *ff_tw=(const float*)d_in[31];
  float* out = (float*)d_out;

  // ---- workspace plan (~213 MB total; all sizes 256-multiple) ----
  const size_t SLOTB = (size_t)SD*2;        // 16,056,320 B  (one bf16 S x DIM slot)
  char* ws = (char*)d_ws;
  size_t off = 0;
  auto alloc = [&](size_t n){ void* p = ws + off; off += (n + 255) & ~(size_t)255; return p; };

  char* P = (char*)alloc(6*SLOTB);          // 6 bf16 activation slots (96.3 MB)
  float* x1    = (float*)alloc((size_t)SD*4);     // fp32 residual (32.1 MB)
  unsigned short* nh2b = (unsigned short*)alloc(SLOTB); // MUST follow x1 (y2b spans both)
  float* x2    = (float*)alloc((size_t)SD*4);
  unsigned short* k2b = (unsigned short*)alloc((size_t)ENCT*DIMC*2);  // k2b+v2b contiguous
  unsigned short* v2b = (unsigned short*)alloc((size_t)ENCT*DIMC*2);
  unsigned short* encb = (unsigned short*)alloc((size_t)ENCT*DIMC*2);
  float* modsb = (float*)alloc(6*DIMC*4);
  float* ksum  = (float*)alloc(DIMC*4);
  float* kpart = (float*)alloc((size_t)28*DIMC*4);
  float* denom = (float*)alloc((size_t)STOK*NH*4);
  unsigned short* scorb = (unsigned short*)alloc((size_t)NH*HDIM*HDIM*2);
  float* bias3 = (float*)alloc(3*2304*4);
  unsigned short* Wbig = (unsigned short*)alloc((size_t)6912*DIMC*2);  // 31 MB weight staging

  // P-slot aliases (lifetimes verified disjoint)
  unsigned short* P0 = (unsigned short*)P;                 // nhb | y1b[0:] | y3pad
  unsigned short* P1 = (unsigned short*)(P + 1*SLOTB);     // qb | spart | lob | y1b | y3pad tail
  unsigned short* P2 = (unsigned short*)(P + 2*SLOTB);     // kb | spart | x1b | y1b | tc[0:]
  unsigned short* P3 = (unsigned short*)(P + 3*SLOTB);     // vb | q2b | y1b | tc[1:]
  unsigned short* P4 = (unsigned short*)(P + 4*SLOTB);     // qrb | crb | y1b
  unsigned short* P5 = (unsigned short*)(P + 5*SLOTB);     // krb | y1b
  unsigned short* nhb = P0;
  unsigned short* y1b = P0;                                // 96.34 MB = slots 0..5 exactly
  unsigned short* y2b = (unsigned short*)x1;               // 48.17 MB = x1 + nh2b exactly
  unsigned short* y3pad = P0;                              // (448+3584+448) x 2240 = 20.1 MB
  unsigned short* y3  = y3pad + (size_t)448*DIMC;          // center: point-conv output
  float* tc = (float*)(P + 2*SLOTB);                       // 32.1 MB = slots 2..3
  float* spart = (float*)P1;   // 28 x NH x 112 x 112 fp32 = 28.1 MB, q/k dead by then

  auto cvt = [&](const float* s, unsigned short* d, size_t n){
    int n4 = (int)(n/4);
    cvt_k<<<dim3((n4+255)/256), 256, 0, stream>>>((const float4*)s, (ushort4*)d, n4);
  };
  // multi-source transpose-convert: z in [0,nz) -> dst + z*dzoff, [ncPad x ldd]
  auto cvtT3 = [&](const float* s0, const float* s1, const float* s2, unsigned short* d,
                   int rows, int ldsrc, int c0, int nc, int ncPad, int ldd, long long dzoff, int nz){
    cvtT3_k<<<dim3(ncPad/32, rows/32, nz), 256, 0, stream>>>(s0, s1, s2, d, rows, ldsrc, c0, nc, ldd, dzoff);
  };
  auto gemm_grid = [&](int M, int Npad){ return dim3(Npad/128, (M+127)/128); };

  mods_k<<<dim3((6*DIMC+255)/256), 256, 0, stream>>>(sst, tstep, modsb);
  cvt(enc, encb, (size_t)ENCT*DIMC);

  // ---- attn1: fused QKV ----
  ln_mod_k<<<dim3(STOK), 256, 0, stream>>>(hid, modsb, 0, 1, nhb);
  pack3_k<<<dim3((3*2304+255)/256), 256, 0, stream>>>(bias3, a1_qb, a1_kb, a1_vb, 3);
  cvtT3(a1_qw, a1_kw, a1_vw, Wbig, DIMC, DIMC, 0, DIMC, 2304, DIMC, (long long)2304*DIMC, 3);
  gemm_bt<6><<<gemm_grid(STOK, 6912), 256, 0, stream>>>(nhb, Wbig, bias3, nullptr, P1,
                                                        nullptr, nullptr, STOK, 6912, DIMC, SD, 6, DIMC, 0);
  rms_bf_k<1,1><<<dim3(STOK), 256, 0, stream>>>(P1, a1_nq, fcos, fsin, P4);
  rms_bf_k<1,1><<<dim3(STOK), 256, 0, stream>>>(P2, a1_nk, fcos, fsin, P5);
  colsum_k<<<dim3(9, 28), 256, 0, stream>>>(P2, kpart);
  ksumred_k<<<dim3(9), 256, 0, stream>>>(kpart, ksum);
  denom_k<<<dim3(STOK), 256, 0, stream>>>(P1, ksum, denom);
  // q (P1) and k (P2) are dead now -> spart may overwrite them
  scores_k<<<dim3(NH, 28), 256, 0, stream>>>(P3, P5, spart);
  scred_k<<<dim3((NH*HDIM*HDIM+255)/256), 256, 0, stream>>>(spart, scorb);
  linout_k<<<dim3(STOK/64, NH), 256, 0, stream>>>(P4, scorb, denom, P1);   // lob -> P1
  dim3 gMN = gemm_grid(STOK, 2304);
  cvtT3(a1_ow, a1_ow, a1_ow, Wbig, DIMC, DIMC, 0, DIMC, 2304, DIMC, 0, 1);
  gemm_bt<3><<<gMN, 256, 0, stream>>>(P1, Wbig, a1_ob, x1, P2, hid, modsb + 2*DIMC, STOK, DIMC, DIMC, DIMC, 6, DIMC, 0);

  // ---- cross attn ----
  cvtT3(a2_qw, a2_qw, a2_qw, Wbig, DIMC, DIMC, 0, DIMC, 2304, DIMC, 0, 1);
  gemm_bt<2><<<gMN, 256, 0, stream>>>(P2, Wbig, a2_qb, nullptr, P3, nullptr, nullptr, STOK, DIMC, DIMC, DIMC, 6, DIMC, 0);
  pack3_k<<<dim3((2*2304+255)/256), 256, 0, stream>>>(bias3, a2_kb, a2_vb, a2_vb, 2);
  cvtT3(a2_kw, a2_vw, a2_vw, Wbig, DIMC, DIMC, 0, DIMC, 2304, DIMC, (long long)2304*DIMC, 2);
  gemm_bt<6><<<gemm_grid(ENCT, 4608), 256, 0, stream>>>(encb, Wbig, bias3, nullptr, k2b,
                                                        nullptr, nullptr, ENCT, 4608, DIMC, ENCT*DIMC, 6, DIMC, 0);
  rms_bf_k<0,0><<<dim3(STOK), 256, 0, stream>>>(P3, a2_nq, nullptr, nullptr, nullptr);
  rms_bf_k<0,0><<<dim3(ENCT), 256, 0, stream>>>(k2b, a2_nk, nullptr, nullptr, nullptr);
  xattn_k<<<dim3(STOK/64, NH), 256, 0, stream>>>(P3, k2b, v2b, P4);   // crb -> P4
  cvtT3(a2_ow, a2_ow, a2_ow, Wbig, DIMC, DIMC, 0, DIMC, 2304, DIMC, 0, 1);
  gemm_bt<4><<<gMN, 256, 0, stream>>>(P4, Wbig, a2_ob, x2, nullptr, x1, nullptr, STOK, DIMC, DIMC, DIMC, 6, DIMC, 0);

  // ---- FF ----
  ln_mod_k<<<dim3(STOK), 256, 0, stream>>>(x2, modsb, 3, 4, nh2b);
  for (int q = 0; q < 2; ++q){                 // ff_inv in 2 column slices of 6720
    int c0 = q*6720;
    cvtT3(ff_inv_w, ff_inv_w, ff_inv_w, Wbig, DIMC, HID2, c0, 6720, 6912, DIMC, 0, 1);
    gemm_bt<1><<<gemm_grid(STOK, 6912), 256, 0, stream>>>(nh2b, Wbig, ff_inv_b + c0, nullptr, y1b + c0,
                                                          nullptr, nullptr, STOK, 6720, DIMC, HID2, 6, DIMC, 0);
  }
  dw_k<<<dim3(448, 14), 256, 0, stream>>>(y1b, ff_dw, ff_db, y2b);
  // y1b dead -> y3pad margins may be zeroed now
  zpad_k<<<dim3(490), 256, 0, stream>>>(y3pad, y3pad + (size_t)(448 + STOK)*DIMC);
  cvtT3(ff_pw, ff_pw, ff_pw, Wbig, HID1, DIMC, 0, DIMC, 2304, HID1, 0, 1);   // point conv weights
  gemm_bt<2><<<gMN, 256, 0, stream>>>(y2b, Wbig, nullptr, nullptr, y3,
                                      nullptr, nullptr, STOK, DIMC, HID1, DIMC, 2, HID1, 0);
  // temporal conv: ONE K=6720 GEMM; A = PADDED base so section sec reads y3[r+(sec-1)*448]
  cvtT3(ff_tw, ff_tw + (size_t)DD, ff_tw + (size_t)2*DD, Wbig,
        DIMC, DIMC, 0, DIMC, 2304, 6720, 2240LL, 3);   // Bt [2304][6720], col-sec = W_sec
  gemm_bt<0><<<gMN, 256, 0, stream>>>(y3pad, Wbig, nullptr, tc, nullptr, nullptr, nullptr,
                                      STOK, DIMC, 6720, DIMC, 6, DIMC, 1);

  // out = x2 + g_mlp*(y3 + tc)
  final_k<<<dim3((SD/4+255)/256), 256, 0, stream>>>(x2, y3, tc, modsb, out);
}

// Round 12
// 1358.147 us; speedup vs baseline: 1.2558x; 1.0013x over previous
//
#include <hip/hip_runtime.h>

#define DIMC 2240
#define STOK 3584
#define ENCT 300
#define NH   20
#define HDIM 112
#define HID1 6720
#define HID2 13440
#define DD   (2240*2240)
#define SD   (3584*2240)

typedef short bf16x8 __attribute__((ext_vector_type(8)));   // guide-verified operand type
typedef float f32x4  __attribute__((ext_vector_type(4)));

__device__ __forceinline__ unsigned short f2bf(float f){
  unsigned int u = __float_as_uint(f);
  u += 0x7fffu + ((u >> 16) & 1u);          // RNE
  return (unsigned short)(u >> 16);
}
__device__ __forceinline__ float bf2f(unsigned short h){
  return __uint_as_float(((unsigned int)h) << 16);
}
__device__ __forceinline__ void gl_lds16(const unsigned short* g, unsigned short* l){
  __builtin_amdgcn_global_load_lds(
      (const __attribute__((address_space(1))) unsigned int*)(const void*)g,
      (__attribute__((address_space(3))) unsigned int*)(void*)l, 16, 0, 0);
}

// ---------------- fp32 -> bf16 convert (flat) ----------------
__global__ void cvt_k(const float4* __restrict__ src, ushort4* __restrict__ dst, int n4){
  int i = blockIdx.x*256 + threadIdx.x;
  if (i < n4){
    float4 v = src[i];
    ushort4 o; o.x = f2bf(v.x); o.y = f2bf(v.y); o.z = f2bf(v.z); o.w = f2bf(v.w);
    dst[i] = o;
  }
}

// -- fp32 (rows x cols slice) -> bf16 TRANSPOSED [ncPad][ldd], zero-padded, multi-src --
// blockIdx.z selects src s0/s1/s2; dst offset z*dzoff. dst[n*ldd + k].
__global__ __launch_bounds__(256) void cvtT3_k(const float* __restrict__ s0,
    const float* __restrict__ s1, const float* __restrict__ s2,
    unsigned short* __restrict__ dst, int rows, int ldsrc, int c0, int nc,
    int ldd, long long dzoff){
  const float* src = (blockIdx.z == 0) ? s0 : ((blockIdx.z == 1) ? s1 : s2);
  unsigned short* d = dst + (size_t)blockIdx.z * (size_t)dzoff;
  __shared__ float tile[32][33];
  const int tx = threadIdx.x & 31, ty = threadIdx.x >> 5;   // ty 0..7
  const int colBase = blockIdx.x*32;
  #pragma unroll
  for (int i = 0; i < 4; ++i){
    int rr = blockIdx.y*32 + ty + i*8;
    int cc = colBase + tx;
    tile[ty + i*8][tx] = (cc < nc) ? src[(size_t)rr*ldsrc + c0 + cc] : 0.f;
  }
  __syncthreads();
  #pragma unroll
  for (int i = 0; i < 4; ++i){
    int n = colBase + ty + i*8;          // < ncPad by grid
    int k = blockIdx.y*32 + tx;
    d[(size_t)n*ldd + k] = f2bf(tile[tx][ty + i*8]);
  }
}

// ---------------- zero the two 448-row margins of y3pad ----------------
__global__ void zpad_k(unsigned short* __restrict__ m0, unsigned short* __restrict__ m1){
  int i = blockIdx.x*256 + threadIdx.x;       // uint4 index; 448*2240/8 = 125440
  if (i < 125440){
    reinterpret_cast<uint4*>(m0)[i] = make_uint4(0u,0u,0u,0u);
    reinterpret_cast<uint4*>(m1)[i] = make_uint4(0u,0u,0u,0u);
  }
}

// ---------------- pack up to 3 biases into [nslots][2304] (zero pad) ----------------
__global__ void pack3_k(float* __restrict__ dst, const float* __restrict__ b0,
    const float* __restrict__ b1, const float* __restrict__ b2, int nslots){
  int i = blockIdx.x*256 + threadIdx.x;
  if (i >= nslots*2304) return;
  int slot = i / 2304, d = i - slot*2304;
  const float* src = (slot == 0) ? b0 : ((slot == 1) ? b1 : b2);
  dst[i] = (d < 2240) ? src[d] : 0.f;
}

// ---------------- mods = scale_shift_table + timestep ----------------
__global__ void mods_k(const float* __restrict__ sst, const float* __restrict__ ts, float* __restrict__ mods){
  int i = blockIdx.x*256 + threadIdx.x;
  if (i < 6*DIMC) mods[i] = sst[i] + ts[i];
}

// ---------------- LayerNorm * (1+sc) + sh -> bf16 (float4-vectorized) ----------------
__global__ __launch_bounds__(256) void ln_mod_k(const float* __restrict__ x,
    const float* __restrict__ mods, int shj, int scj, unsigned short* __restrict__ out)
{
  const int s = blockIdx.x;
  const float4* row4 = reinterpret_cast<const float4*>(x + (size_t)s*DIMC);
  const float4* sh4 = reinterpret_cast<const float4*>(mods + shj*DIMC);
  const float4* sc4 = reinterpret_cast<const float4*>(mods + scj*DIMC);
  float sum = 0.f, sq = 0.f;
  for (int o = threadIdx.x; o < 560; o += 256){
    float4 v = row4[o];
    sum += v.x + v.y + v.z + v.w;
    sq  += v.x*v.x + v.y*v.y + v.z*v.z + v.w*v.w;
  }
  #pragma unroll
  for (int o = 32; o; o >>= 1){ sum += __shfl_down(sum, o); sq += __shfl_down(sq, o); }
  __shared__ float sA[4], sB[4];
  int w = threadIdx.x >> 6, l = threadIdx.x & 63;
  if (!l){ sA[w] = sum; sB[w] = sq; }
  __syncthreads();
  sum = sA[0]+sA[1]+sA[2]+sA[3];
  sq  = sB[0]+sB[1]+sB[2]+sB[3];
  float mean = sum * (1.f/DIMC);
  float rs = rsqrtf(sq*(1.f/DIMC) - mean*mean + 1e-6f);
  unsigned short* orow = out + (size_t)s*DIMC;
  for (int o = threadIdx.x; o < 560; o += 256){
    float4 v = row4[o], sc = sc4[o], sh = sh4[o];
    ushort4 r;
    r.x = f2bf((v.x-mean)*rs*(1.f + sc.x) + sh.x);
    r.y = f2bf((v.y-mean)*rs*(1.f + sc.y) + sh.y);
    r.z = f2bf((v.z-mean)*rs*(1.f + sc.z) + sh.z);
    r.w = f2bf((v.w-mean)*rs*(1.f + sc.w) + sh.w);
    *reinterpret_cast<ushort4*>(orow + o*4) = r;
  }
}

// ---------------- RMS on bf16 rows (optional ReLU / RoPE), uint4-vectorized ----------
template<int RELU, int ROPE>
__global__ __launch_bounds__(256) void rms_bf_k(unsigned short* __restrict__ x, const float* __restrict__ nw,
    const float* __restrict__ cosb, const float* __restrict__ sinb, unsigned short* __restrict__ xr)
{
  const int s = blockIdx.x;
  unsigned short* row = x + (size_t)s*DIMC;
  float sq = 0.f;
  for (int o = threadIdx.x; o < 280; o += 256){     // 280 octets of 8 bf16
    uint4 v = *reinterpret_cast<const uint4*>(row + o*8);
    unsigned int uu[4] = {v.x, v.y, v.z, v.w};
    #pragma unroll
    for (int j = 0; j < 4; ++j){
      float lo = bf2f((unsigned short)(uu[j] & 0xffffu));
      float hi = bf2f((unsigned short)(uu[j] >> 16));
      sq += lo*lo + hi*hi;
    }
  }
  #pragma unroll
  for (int o = 32; o; o >>= 1) sq += __shfl_down(sq, o);
  __shared__ float sB[4];
  int w = threadIdx.x >> 6, l = threadIdx.x & 63;
  if (!l) sB[w] = sq;
  __syncthreads();
  sq = sB[0]+sB[1]+sB[2]+sB[3];
  float rs = rsqrtf(sq*(1.f/DIMC) + 1e-5f);
  for (int o = threadIdx.x; o < 280; o += 256){
    uint4 v = *reinterpret_cast<const uint4*>(row + o*8);
    unsigned int uu[4] = {v.x, v.y, v.z, v.w};
    float4 n0 = *reinterpret_cast<const float4*>(nw + o*8);
    float4 n1 = *reinterpret_cast<const float4*>(nw + o*8 + 4);
    float nn[8] = {n0.x,n0.y,n0.z,n0.w,n1.x,n1.y,n1.z,n1.w};
    float vals[8];
    #pragma unroll
    for (int j = 0; j < 4; ++j){
      vals[2*j]   = bf2f((unsigned short)(uu[j] & 0xffffu))*rs*nn[2*j];
      vals[2*j+1] = bf2f((unsigned short)(uu[j] >> 16))*rs*nn[2*j+1];
    }
    if constexpr (RELU){
      #pragma unroll
      for (int j = 0; j < 8; ++j) vals[j] = fmaxf(vals[j], 0.f);
    }
    uint4 o1;
    unsigned int* po = &o1.x;
    #pragma unroll
    for (int j = 0; j < 4; ++j)
      po[j] = (unsigned int)f2bf(vals[2*j]) | ((unsigned int)f2bf(vals[2*j+1]) << 16);
    *reinterpret_cast<uint4*>(row + o*8) = o1;
    if constexpr (ROPE){
      int jb = (o*8) % HDIM;                      // octet stays within a head (112%8==0)
      uint4 o2;
      unsigned int* pr = &o2.x;
      #pragma unroll
      for (int p = 0; p < 4; ++p){
        float c  = cosb[(size_t)s*HDIM + jb + 2*p];
        float sn = sinb[(size_t)s*HDIM + jb + 2*p + 1];
        float r0 = vals[2*p]*c - vals[2*p+1]*sn;
        float r1 = vals[2*p]*sn + vals[2*p+1]*c;
        pr[p] = (unsigned int)f2bf(r0) | ((unsigned int)f2bf(r1) << 16);
      }
      *reinterpret_cast<uint4*>(xr + (size_t)s*DIMC + o*8) = o2;
    }
  }
}

// ------- bf16 MFMA GEMM: C = A(MxK) @ Bt^T, Bt is [Npad][K] (N-major), BK=64 ---------
// (round-7 proven structure) Both-sides swizzle; K % 64 == 0; PW | gridDim.x.
// lda: A row stride. tcsh=1: temporal-conv mode — K-section sec (2240 wide) reads A at
// row + sec*448; A must point at the PADDED base (row 0 = center_row - 448).
// EPI: 0 Cf=acc+bias | 1 Cb=bf16(silu(acc+bias)) | 2 Cb=bf16(acc+bias)
//      3 u=res+gate*(acc+bias); Cf=u; Cb=bf16(u) | 4 Cf=res+acc+bias | 5 Cf+=acc
//      6 slot-split: slot=col/2304, d=col%2304; if d<2240: Cb[slot*ldc + row*2240 + d]
//      7 Cf = res + gate[col]*(bf2f(Cb[idx]) + acc)   (fused temporal-conv + final)
template<int EPI>
__global__ __launch_bounds__(256) void gemm_bt(
  const unsigned short* __restrict__ A, const unsigned short* __restrict__ Bt,
  const float* __restrict__ bias, float* __restrict__ Cf, unsigned short* __restrict__ Cb,
  const float* __restrict__ res, const float* __restrict__ gate,
  int M, int N, int K, int ldc, int PW, int lda, int tcsh)
{
  __shared__ __align__(16) unsigned short Al[128*64];
  __shared__ __align__(16) unsigned short Bl[128*64];
  const int gx = gridDim.x, gy = gridDim.y;
  const int nwg = gx*gy;
  const int orig = blockIdx.y*gx + blockIdx.x;
  // bijective XCD-aware remap (m204)
  const int qq = nwg >> 3, rr = nwg & 7;
  const int xcd = orig & 7, li = orig >> 3;
  const int wg = (xcd < rr ? xcd*(qq+1) : rr*(qq+1) + (xcd-rr)*qq) + li;
  // N-panel rasterization: panel of PW n-tiles covers all gy m-rows before advancing
  const int ppw = gy*PW;
  const int panel = wg / ppw, rm = wg - panel*ppw;
  const int mrow = rm / PW;
  const int m0 = mrow*128;
  const int n0 = (panel*PW + (rm - mrow*PW))*128;

  const int t = threadIdx.x, lane = t & 63, w = t >> 6;
  const int wr = w >> 1, wc = w & 1;
  const int l16 = lane & 15, lk = lane >> 4;

  // staging: per wave 4 A-chunks + 4 B-chunks (each 1KB = 8 rows x 128B), swizzled src
  const int lr8 = lane >> 3;           // row within 8-row block (== row&7)
  const int sc  = (lane & 7) ^ lr8;    // pre-swizzled source chunk
  const unsigned short* Aps[4];
  const unsigned short* Bps[4];
  #pragma unroll
  for (int i = 0; i < 4; ++i){
    int ar = m0 + w*32 + i*8 + lr8;
    int br = n0 + w*32 + i*8 + lr8;
    Aps[i] = A  + (size_t)min(ar, M-1)*lda + sc*8;
    Bps[i] = Bt + (size_t)br*K + sc*8;
  }
  unsigned short* Ad = Al + w*2048;
  unsigned short* Bd = Bl + w*2048;

  f32x4 acc[4][4] = {};
  for (int k0 = 0; k0 < K; k0 += 64){
    size_t aoff;
    if (tcsh){
      int sec = (k0 >= 4480) ? 2 : ((k0 >= 2240) ? 1 : 0);
      aoff = (size_t)(sec*448)*lda + (unsigned)(k0 - sec*2240);
    } else {
      aoff = (size_t)k0;
    }
    __syncthreads();
    #pragma unroll
    for (int i = 0; i < 4; ++i){
      gl_lds16(Aps[i] + aoff, Ad + i*512);
      gl_lds16(Bps[i] + k0,   Bd + i*512);
    }
    __syncthreads();
    #pragma unroll
    for (int kk = 0; kk < 2; ++kk){
      bf16x8 af[4], bfr[4];
      const int chb = (kk*4 + lk) ^ (l16 & 7);   // swizzled read chunk
      #pragma unroll
      for (int m = 0; m < 4; ++m)
        af[m] = *reinterpret_cast<const bf16x8*>(Al + (wr*64 + m*16 + l16)*64 + chb*8);
      #pragma unroll
      for (int n = 0; n < 4; ++n)
        bfr[n] = *reinterpret_cast<const bf16x8*>(Bl + (wc*64 + n*16 + l16)*64 + chb*8);
      #pragma unroll
      for (int m = 0; m < 4; ++m)
        #pragma unroll
        for (int n = 0; n < 4; ++n)
          acc[m][n] = __builtin_amdgcn_mfma_f32_16x16x32_bf16(af[m], bfr[n], acc[m][n], 0, 0, 0);
    }
  }

  const int rb = m0 + wr*64 + lk*4;   // C/D: col = lane&15, row = (lane>>4)*4 + reg
  const int cb = n0 + wc*64 + l16;
  #pragma unroll
  for (int m = 0; m < 4; ++m){
    #pragma unroll
    for (int r = 0; r < 4; ++r){
      int row = rb + m*16 + r;
      if (row >= M) continue;
      #pragma unroll
      for (int n = 0; n < 4; ++n){
        int col = cb + n*16;
        if (col >= N) continue;
        float v = acc[m][n][r];
        float bv = bias ? bias[col] : 0.f;
        if constexpr (EPI == 6){
          int slot = col / 2304;
          int d = col - slot*2304;
          if (d < 2240)
            Cb[(size_t)slot*ldc + (size_t)row*2240 + d] = f2bf(v + bv);
        } else {
          size_t idx = (size_t)row*ldc + col;
          if constexpr (EPI == 0){ Cf[idx] = v + bv; }
          else if constexpr (EPI == 1){ float u = v + bv; Cb[idx] = f2bf(u / (1.f + __expf(-u))); }
          else if constexpr (EPI == 2){ Cb[idx] = f2bf(v + bv); }
          else if constexpr (EPI == 3){ float u = res[idx] + gate[col]*(v + bv); Cf[idx] = u; Cb[idx] = f2bf(u); }
          else if constexpr (EPI == 4){ Cf[idx] = res[idx] + v + bv; }
          else if constexpr (EPI == 7){ Cf[idx] = res[idx] + gate[col]*(bf2f(Cb[idx]) + v); }
          else { Cf[idx] += v; }
        }
      }
    }
  }
}

// ---------------- linear attention helpers ----------------
__global__ void colsum_k(const unsigned short* __restrict__ k, float* __restrict__ kpart){
  int d = blockIdx.x*256 + threadIdx.x;
  if (d >= DIMC) return;
  int ch = blockIdx.y, s0 = ch*128;
  float acc = 0.f;
  for (int s = s0; s < s0+128; ++s) acc += bf2f(k[(size_t)s*DIMC + d]);
  kpart[(size_t)ch*DIMC + d] = acc;
}
__global__ void ksumred_k(const float* __restrict__ kpart, float* __restrict__ ksum){
  int d = blockIdx.x*256 + threadIdx.x;
  if (d >= DIMC) return;
  float a = 0.f;
  for (int c = 0; c < 28; ++c) a += kpart[(size_t)c*DIMC + d];
  ksum[d] = a;
}
__global__ __launch_bounds__(256) void denom_k(const unsigned short* __restrict__ q,
    const float* __restrict__ ksum, float* __restrict__ denom)
{
  int s = blockIdx.x; int w = threadIdx.x >> 6, l = threadIdx.x & 63;
  for (int h = w; h < NH; h += 4){
    const unsigned short* qb = q + (size_t)s*DIMC + h*HDIM;
    const float* kb = ksum + h*HDIM;
    float v = bf2f(qb[l])*kb[l];
    if (l < 48) v += bf2f(qb[64+l])*kb[64+l];
    #pragma unroll
    for (int o = 32; o; o >>= 1) v += __shfl_down(v, o);
    if (!l) denom[s*NH + h] = v + 1e-15f;
  }
}

// -------- MFMA scores: part[ch][h][e][d] = sum_{s in 128-chunk} V[s,h,e]*Kr[s,h,d] -----
#define SLSC 136
__device__ __forceinline__ int sc_idx(int e, int s){
  return e*SLSC + (s ^ (((e >> 3) & 7) << 3));
}
__global__ __launch_bounds__(256) void scores_k(const unsigned short* __restrict__ v,
    const unsigned short* __restrict__ kr, float* __restrict__ part)
{
  const int h = blockIdx.x, ch = blockIdx.y;
  __shared__ __align__(16) unsigned short Vt[112*SLSC];
  __shared__ __align__(16) unsigned short Kt[112*SLSC];
  const int t = threadIdx.x, lane = t & 63, w = t >> 6;
  const int l16 = lane & 15, lk = lane >> 4;
  const int sbase = ch*128;

  for (int p = t; p < 1792; p += 256){       // 128 tokens x 14 dim-octets
    int s = p / 14, oc = (p % 14) * 8;
    bf16x8 vv = *reinterpret_cast<const bf16x8*>(v  + (size_t)(sbase+s)*DIMC + h*HDIM + oc);
    bf16x8 kk = *reinterpret_cast<const bf16x8*>(kr + (size_t)(sbase+s)*DIMC + h*HDIM + oc);
    #pragma unroll
    for (int j = 0; j < 8; ++j){
      Vt[sc_idx(oc+j, s)] = (unsigned short)vv[j];
      Kt[sc_idx(oc+j, s)] = (unsigned short)kk[j];
    }
  }
  __syncthreads();

  f32x4 acc[2][7] = {};                      // wave w owns m-tiles {w, w+4}
  #pragma unroll
  for (int ks = 0; ks < 4; ++ks){
    const int sf = ks*32 + lk*8;
    bf16x8 bfrg[7];
    #pragma unroll
    for (int nt = 0; nt < 7; ++nt){
      int d = nt*16 + l16;
      bfrg[nt] = *reinterpret_cast<const bf16x8*>(&Kt[d*SLSC + (sf ^ (((d >> 3) & 7) << 3))]);
    }
    #pragma unroll
    for (int mi = 0; mi < 2; ++mi){
      int mt = w + mi*4;
      if (mt < 7){
        int e = mt*16 + l16;
        bf16x8 afrg = *reinterpret_cast<const bf16x8*>(&Vt[e*SLSC + (sf ^ (((e >> 3) & 7) << 3))]);
        #pragma unroll
        for (int nt = 0; nt < 7; ++nt)
          acc[mi][nt] = __builtin_amdgcn_mfma_f32_16x16x32_bf16(afrg, bfrg[nt], acc[mi][nt], 0, 0, 0);
      }
    }
  }

  float* pout = part + ((size_t)ch*NH + h)*12544;
  #pragma unroll
  for (int mi = 0; mi < 2; ++mi){
    int mt = w + mi*4;
    if (mt >= 7) continue;
    #pragma unroll
    for (int nt = 0; nt < 7; ++nt)
      #pragma unroll
      for (int r = 0; r < 4; ++r)
        pout[(size_t)(mt*16 + lk*4 + r)*HDIM + nt*16 + l16] = acc[mi][nt][r];
  }
}
__global__ void scred_k(const float* __restrict__ part, unsigned short* __restrict__ sc){
  int i = blockIdx.x*256 + threadIdx.x;
  if (i >= NH*HDIM*HDIM) return;
  float a = 0.f;
  #pragma unroll
  for (int c = 0; c < 28; ++c) a += part[(size_t)c*(NH*HDIM*HDIM) + i];
  sc[i] = f2bf(a);
}

// -------- MFMA linout: out[s,h*112+e] = (sum_d scores[h,e,d]*qr[s,h,d]) / denom[s,h] ---
__global__ __launch_bounds__(256) void linout_k(const unsigned short* __restrict__ qr,
    const unsigned short* __restrict__ scores, const float* __restrict__ denom,
    unsigned short* __restrict__ out)
{
  const int h = blockIdx.y;
  const int t = threadIdx.x, lane = t & 63, w = t >> 6;
  const int l16 = lane & 15, lk = lane >> 4;
  const int s0 = blockIdx.x*64 + w*16;
  const unsigned short* qrow = qr + (size_t)(s0 + l16)*DIMC + h*HDIM;
  const unsigned short* sb = scores + (size_t)h*12544;
  f32x4 acc[7] = {};
  #pragma unroll
  for (int ks = 0; ks < 4; ++ks){
    int d0 = ks*32 + lk*8;
    bf16x8 a = {};
    if (d0 < HDIM) a = *reinterpret_cast<const bf16x8*>(qrow + d0);
    #pragma unroll
    for (int nt = 0; nt < 7; ++nt){
      bf16x8 b = {};
      if (d0 < HDIM) b = *reinterpret_cast<const bf16x8*>(sb + (size_t)(nt*16 + l16)*HDIM + d0);
      acc[nt] = __builtin_amdgcn_mfma_f32_16x16x32_bf16(a, b, acc[nt], 0, 0, 0);
    }
  }
  #pragma unroll
  for (int r = 0; r < 4; ++r){
    int s = s0 + lk*4 + r;
    float dn = 1.f / denom[(size_t)s*NH + h];
    #pragma unroll
    for (int nt = 0; nt < 7; ++nt)
      out[(size_t)s*DIMC + h*HDIM + nt*16 + l16] = f2bf(acc[nt][r]*dn);
  }
}

// ---------------- fused cross-attention, MFMA (300 keys, head dim 112 padded to 128) ----
__global__ __launch_bounds__(256) void xattn_k(
    const unsigned short* __restrict__ q,   // S x DIM bf16 (rms-normed)
    const unsigned short* __restrict__ k2,  // ENCT x DIM bf16 (rms-normed)
    const unsigned short* __restrict__ v2,  // ENCT x DIM bf16
    unsigned short* __restrict__ outb)      // S x DIM bf16
{
  const int h = blockIdx.y;
  const int w = threadIdx.x >> 6, lane = threadIdx.x & 63;
  const int l16 = lane & 15, lk = lane >> 4;
  const float scale = 0.09449111825230679f;   // 1/sqrt(112)

  __shared__ __align__(16) unsigned short Kl[64][136];
  __shared__ __align__(16) unsigned short Vl[112][72];
  __shared__ __align__(16) unsigned short Pl[4][16][72];

  bf16x8 qf[4];
  const unsigned short* qbase = q + (size_t)(blockIdx.x*64 + w*16 + l16)*DIMC + h*HDIM;
  #pragma unroll
  for (int c = 0; c < 4; ++c){
    int d0 = c*32 + lk*8;
    bf16x8 z = {};
    qf[c] = (d0 < HDIM) ? *reinterpret_cast<const bf16x8*>(qbase + d0) : z;
  }

  f32x4 lg[5][4] = {};
  #pragma unroll
  for (int c = 0; c < 5; ++c){
    const int kbase = c*64;
    const int nk = (c == 4) ? (ENCT - 256) : 64;
    __syncthreads();
    #pragma unroll
    for (int it = 0; it < 4; ++it){
      int li = it*256 + threadIdx.x;
      int key = li >> 4, d0 = (li & 15) << 3;
      uint4 val = make_uint4(0u,0u,0u,0u);
      if (key < nk && d0 < HDIM)
        val = *reinterpret_cast<const uint4*>(k2 + (size_t)(kbase+key)*DIMC + h*HDIM + d0);
      *reinterpret_cast<uint4*>(&Kl[key][d0]) = val;
    }
    __syncthreads();
    #pragma unroll
    for (int nt = 0; nt < 4; ++nt){
      #pragma unroll
      for (int ks = 0; ks < 4; ++ks){
        bf16x8 kf = *reinterpret_cast<const bf16x8*>(&Kl[nt*16 + l16][ks*32 + lk*8]);
        lg[c][nt] = __builtin_amdgcn_mfma_f32_16x16x32_bf16(qf[ks], kf, lg[c][nt], 0, 0, 0);
      }
    }
  }

  float mx[4] = {-3e38f, -3e38f, -3e38f, -3e38f};
  #pragma unroll
  for (int c = 0; c < 5; ++c)
    #pragma unroll
    for (int nt = 0; nt < 4; ++nt){
      bool valid = (c*64 + nt*16 + l16) < ENCT;
      #pragma unroll
      for (int r = 0; r < 4; ++r){
        float v = valid ? lg[c][nt][r]*scale : -3e38f;
        lg[c][nt][r] = v;
        mx[r] = fmaxf(mx[r], v);
      }
    }
  #pragma unroll
  for (int o = 1; o < 16; o <<= 1)
    #pragma unroll
    for (int r = 0; r < 4; ++r) mx[r] = fmaxf(mx[r], __shfl_xor(mx[r], o));
  float sm[4] = {0.f, 0.f, 0.f, 0.f};
  #pragma unroll
  for (int c = 0; c < 5; ++c)
    #pragma unroll
    for (int nt = 0; nt < 4; ++nt)
      #pragma unroll
      for (int r = 0; r < 4; ++r){
        float e = __expf(lg[c][nt][r] - mx[r]);
        lg[c][nt][r] = e;
        sm[r] += e;
      }
  #pragma unroll
  for (int o = 1; o < 16; o <<= 1)
    #pragma unroll
    for (int r = 0; r < 4; ++r) sm[r] += __shfl_xor(sm[r], o);
  float inv[4];
  #pragma unroll
  for (int r = 0; r < 4; ++r) inv[r] = 1.f / sm[r];

  f32x4 oacc[7] = {};
  #pragma unroll
  for (int c = 0; c < 5; ++c){
    const int kbase = c*64;
    const int nk = (c == 4) ? (ENCT - 256) : 64;
    __syncthreads();
    #pragma unroll
    for (int it = 0; it < 4; ++it){
      int li = it*256 + threadIdx.x;
      if (li < 896){
        int key = li/14, d0 = (li%14)*8;
        if (key < nk){
          bf16x8 vv = *reinterpret_cast<const bf16x8*>(v2 + (size_t)(kbase+key)*DIMC + h*HDIM + d0);
          #pragma unroll
          for (int j = 0; j < 8; ++j) Vl[d0+j][key] = (unsigned short)vv[j];
        } else {
          #pragma unroll
          for (int j = 0; j < 8; ++j) Vl[d0+j][key] = 0;
        }
      }
    }
    #pragma unroll
    for (int nt = 0; nt < 4; ++nt)
      #pragma unroll
      for (int r = 0; r < 4; ++r)
        Pl[w][lk*4 + r][nt*16 + l16] = f2bf(lg[c][nt][r]);
    __syncthreads();
    #pragma unroll
    for (int ks = 0; ks < 2; ++ks){
      bf16x8 pf = *reinterpret_cast<const bf16x8*>(&Pl[w][l16][ks*32 + lk*8]);
      #pragma unroll
      for (int n = 0; n < 7; ++n){
        bf16x8 vf = *reinterpret_cast<const bf16x8*>(&Vl[n*16 + l16][ks*32 + lk*8]);
        oacc[n] = __builtin_amdgcn_mfma_f32_16x16x32_bf16(pf, vf, oacc[n], 0, 0, 0);
      }
    }
  }

  const int orow = blockIdx.x*64 + w*16 + lk*4;
  #pragma unroll
  for (int n = 0; n < 7; ++n)
    #pragma unroll
    for (int r = 0; r < 4; ++r)
      outb[(size_t)(orow + r)*DIMC + h*HDIM + n*16 + l16] = f2bf(oacc[n][r]*inv[r]);
}

// ------- depthwise 3x3 + bias + GLU(silu): 2 ch x 4 rows x 4 cols per thread ----------
// grid.x = f(8) x ytile(4) x xquad(7) = 224, grid.y = 14
__global__ __launch_bounds__(256) void dw_k(const unsigned short* __restrict__ y1,
    const float* __restrict__ dw, const float* __restrict__ db, unsigned short* __restrict__ y2)
{
  int c = (blockIdx.y*256 + threadIdx.x)*2;
  if (c >= HID1) return;
  int bx = blockIdx.x;
  int xq = bx % 7;
  int yt = (bx / 7) & 3;
  int f  = bx / 28;
  int x0 = xq*4, y0 = yt*4;

  float wa[9][2], wg[9][2];
  #pragma unroll
  for (int tp = 0; tp < 9; ++tp){
    float2 va = *reinterpret_cast<const float2*>(dw + tp*HID2 + c);
    float2 vg = *reinterpret_cast<const float2*>(dw + tp*HID2 + c + HID1);
    wa[tp][0] = va.x; wa[tp][1] = va.y;
    wg[tp][0] = vg.x; wg[tp][1] = vg.y;
  }
  float2 ba = *reinterpret_cast<const float2*>(db + c);
  float2 bg = *reinterpret_cast<const float2*>(db + c + HID1);
  float a[4][4][2], g[4][4][2];
  #pragma unroll
  for (int r = 0; r < 4; ++r)
    #pragma unroll
    for (int cc = 0; cc < 4; ++cc){
      a[r][cc][0] = ba.x; a[r][cc][1] = ba.y;
      g[r][cc][0] = bg.x; g[r][cc][1] = bg.y;
    }

  #pragma unroll
  for (int dy6 = 0; dy6 < 6; ++dy6){
    int y = y0 - 1 + dy6;
    if ((unsigned)y >= 16u) continue;
    #pragma unroll
    for (int dxc = 0; dxc < 6; ++dxc){
      int x = x0 - 1 + dxc;
      if ((unsigned)x >= 28u) continue;
      size_t base = ((size_t)(f*16 + y)*28 + x)*HID2;
      unsigned int a01 = *reinterpret_cast<const unsigned int*>(y1 + base + c);
      unsigned int g01 = *reinterpret_cast<const unsigned int*>(y1 + base + c + HID1);
      float fa0 = bf2f((unsigned short)(a01 & 0xffffu));
      float fa1 = bf2f((unsigned short)(a01 >> 16));
      float fg0 = bf2f((unsigned short)(g01 & 0xffffu));
      float fg1 = bf2f((unsigned short)(g01 >> 16));
      #pragma unroll
      for (int r = 0; r < 4; ++r){
        int kdy = dy6 - r;                    // compile-time after unroll
        if (kdy < 0 || kdy > 2) continue;
        #pragma unroll
        for (int cc = 0; cc < 4; ++cc){
          int kdx = dxc - cc;
          if (kdx < 0 || kdx > 2) continue;
          int tp = kdy*3 + kdx;
          a[r][cc][0] += fa0*wa[tp][0]; a[r][cc][1] += fa1*wa[tp][1];
          g[r][cc][0] += fg0*wg[tp][0]; g[r][cc][1] += fg1*wg[tp][1];
        }
      }
    }
  }
  #pragma unroll
  for (int r = 0; r < 4; ++r)
    #pragma unroll
    for (int cc = 0; cc < 4; ++cc){
      float s0 = g[r][cc][0] / (1.f + __expf(-g[r][cc][0]));
      float s1 = g[r][cc][1] / (1.f + __expf(-g[r][cc][1]));
      int pos = (f*16 + y0 + r)*28 + x0 + cc;
      unsigned int o = (unsigned int)f2bf(a[r][cc][0]*s0) | ((unsigned int)f2bf(a[r][cc][1]*s1) << 16);
      *reinterpret_cast<unsigned int*>(y2 + (size_t)pos*HID1 + c) = o;
    }
}

extern "C" void kernel_launch(void* const* d_in, const int* in_sizes, int n_in,
                              void* d_out, int out_size, void* d_ws, size_t ws_size,
                              hipStream_t stream)
{
  const float* hid   = (const float*)d_in[0];
  const float* enc   = (const float*)d_in[1];
  const float* tstep = (const float*)d_in[2];
  const float* fcos  = (const float*)d_in[3];
  const float* fsin  = (const float*)d_in[4];
  const float* sst   = (const float*)d_in[5];
  const float *a1_qw=(const float*)d_in[6],  *a1_qb=(const float*)d_in[7];
  const float *a1_kw=(const float*)d_in[8],  *a1_kb=(const float*)d_in[9];
  const float *a1_vw=(const float*)d_in[10], *a1_vb=(const float*)d_in[11];
  const float *a1_nq=(const float*)d_in[12], *a1_nk=(const float*)d_in[13];
  const float *a1_ow=(const float*)d_in[14], *a1_ob=(const float*)d_in[15];
  const float *a2_qw=(const float*)d_in[16], *a2_qb=(const float*)d_in[17];
  const float *a2_kw=(const float*)d_in[18], *a2_kb=(const float*)d_in[19];
  const float *a2_vw=(const float*)d_in[20], *a2_vb=(const float*)d_in[21];
  const float *a2_nq=(const float*)d_in[22], *a2_nk=(const float*)d_in[23];
  const float *a2_ow=(const float*)d_in[24], *a2_ob=(const float*)d_in[25];
  const float *ff_inv_w=(const float*)d_in[26], *ff_inv_b=(const float*)d_in[27];
  const float *ff_dw=(const float*)d_in[28], *ff_db=(const float*)d_in[29];
  const float *ff_pw=(const float*)d_in[30];
  const float *ff_tw=(const float*)d_in[31];
  float* out = (float*)d_out;

  // ---- workspace plan (~213 MB total; all sizes 256-multiple) ----
  const size_t SLOTB = (size_t)SD*2;        // 16,056,320 B  (one bf16 S x DIM slot)
  char* ws = (char*)d_ws;
  size_t off = 0;
  auto alloc = [&](size_t n){ void* p = ws + off; off += (n + 255) & ~(size_t)255; return p; };

  char* P = (char*)alloc(6*SLOTB);          // 6 bf16 activation slots (96.3 MB)
  float* x1    = (float*)alloc((size_t)SD*4);     // fp32 residual (32.1 MB)
  unsigned short* nh2b = (unsigned short*)alloc(SLOTB); // MUST follow x1 (y2b spans both)
  float* x2    = (float*)alloc((size_t)SD*4);
  unsigned short* k2b = (unsigned short*)alloc((size_t)ENCT*DIMC*2);  // k2b+v2b contiguous
  unsigned short* v2b = (unsigned short*)alloc((size_t)ENCT*DIMC*2);
  unsigned short* encb = (unsigned short*)alloc((size_t)ENCT*DIMC*2);
  float* modsb = (float*)alloc(6*DIMC*4);
  float* ksum  = (float*)alloc(DIMC*4);
  float* kpart = (float*)alloc((size_t)28*DIMC*4);
  float* denom = (float*)alloc((size_t)STOK*NH*4);
  unsigned short* scorb = (unsigned short*)alloc((size_t)NH*HDIM*HDIM*2);
  float* bias3 = (float*)alloc(3*2304*4);
  unsigned short* Wbig = (unsigned short*)alloc((size_t)6912*DIMC*2);  // 31 MB weight staging

  // P-slot aliases (lifetimes verified disjoint)
  unsigned short* P0 = (unsigned short*)P;                 // nhb | y1b[0:] | y3pad
  unsigned short* P1 = (unsigned short*)(P + 1*SLOTB);     // qb | spart | lob | y1b | y3pad tail
  unsigned short* P2 = (unsigned short*)(P + 2*SLOTB);     // kb | spart | x1b | y1b
  unsigned short* P3 = (unsigned short*)(P + 3*SLOTB);     // vb | q2b | y1b
  unsigned short* P4 = (unsigned short*)(P + 4*SLOTB);     // qrb | crb | y1b
  unsigned short* P5 = (unsigned short*)(P + 5*SLOTB);     // krb | y1b
  unsigned short* nhb = P0;
  unsigned short* y1b = P0;                                // 96.34 MB = slots 0..5 exactly
  unsigned short* y2b = (unsigned short*)x1;               // 48.17 MB = x1 + nh2b exactly
  unsigned short* y3pad = P0;                              // (448+3584+448) x 2240 = 20.1 MB
  unsigned short* y3  = y3pad + (size_t)448*DIMC;          // center: point-conv output
  float* spart = (float*)P1;   // 28 x NH x 112 x 112 fp32 = 28.1 MB, q/k dead by then

  auto cvt = [&](const float* s, unsigned short* d, size_t n){
    int n4 = (int)(n/4);
    cvt_k<<<dim3((n4+255)/256), 256, 0, stream>>>((const float4*)s, (ushort4*)d, n4);
  };
  // multi-source transpose-convert: z in [0,nz) -> dst + z*dzoff, [ncPad x ldd]
  auto cvtT3 = [&](const float* s0, const float* s1, const float* s2, unsigned short* d,
                   int rows, int ldsrc, int c0, int nc, int ncPad, int ldd, long long dzoff, int nz){
    cvtT3_k<<<dim3(ncPad/32, rows/32, nz), 256, 0, stream>>>(s0, s1, s2, d, rows, ldsrc, c0, nc, ldd, dzoff);
  };
  auto gemm_grid = [&](int M, int Npad){ return dim3(Npad/128, (M+127)/128); };
  const long long WSLOT = (long long)2304*DIMC;

  mods_k<<<dim3((6*DIMC+255)/256), 256, 0, stream>>>(sst, tstep, modsb);
  cvt(enc, encb, (size_t)ENCT*DIMC);

  // ---- attn1: fused QKV ----
  ln_mod_k<<<dim3(STOK), 256, 0, stream>>>(hid, modsb, 0, 1, nhb);
  pack3_k<<<dim3((3*2304+255)/256), 256, 0, stream>>>(bias3, a1_qb, a1_kb, a1_vb, 3);
  cvtT3(a1_qw, a1_kw, a1_vw, Wbig, DIMC, DIMC, 0, DIMC, 2304, DIMC, WSLOT, 3);
  gemm_bt<6><<<gemm_grid(STOK, 6912), 256, 0, stream>>>(nhb, Wbig, bias3, nullptr, P1,
                                                        nullptr, nullptr, STOK, 6912, DIMC, SD, 6, DIMC, 0);
  rms_bf_k<1,1><<<dim3(STOK), 256, 0, stream>>>(P1, a1_nq, fcos, fsin, P4);
  rms_bf_k<1,1><<<dim3(STOK), 256, 0, stream>>>(P2, a1_nk, fcos, fsin, P5);
  colsum_k<<<dim3(9, 28), 256, 0, stream>>>(P2, kpart);
  ksumred_k<<<dim3(9), 256, 0, stream>>>(kpart, ksum);
  denom_k<<<dim3(STOK), 256, 0, stream>>>(P1, ksum, denom);
  // q (P1) and k (P2) are dead now -> spart may overwrite them
  scores_k<<<dim3(NH, 28), 256, 0, stream>>>(P3, P5, spart);
  scred_k<<<dim3((NH*HDIM*HDIM+255)/256), 256, 0, stream>>>(spart, scorb);
  linout_k<<<dim3(STOK/64, NH), 256, 0, stream>>>(P4, scorb, denom, P1);   // lob -> P1
  dim3 gMN = gemm_grid(STOK, 2304);
  // batch-convert the three DIM x DIM weights: slot0=a1_ow, slot1=a2_qw, slot2=a2_ow
  cvtT3(a1_ow, a2_qw, a2_ow, Wbig, DIMC, DIMC, 0, DIMC, 2304, DIMC, WSLOT, 3);
  gemm_bt<3><<<gMN, 256, 0, stream>>>(P1, Wbig, a1_ob, x1, P2, hid, modsb + 2*DIMC, STOK, DIMC, DIMC, DIMC, 6, DIMC, 0);

  // ---- cross attn ----
  gemm_bt<2><<<gMN, 256, 0, stream>>>(P2, Wbig + WSLOT, a2_qb, nullptr, P3, nullptr, nullptr, STOK, DIMC, DIMC, DIMC, 6, DIMC, 0);
  pack3_k<<<dim3((2*2304+255)/256), 256, 0, stream>>>(bias3, a2_kb, a2_vb, a2_vb, 2);
  cvtT3(a2_kw, a2_vw, a2_vw, Wbig, DIMC, DIMC, 0, DIMC, 2304, DIMC, WSLOT, 2);   // slots 0,1 (dead)
  gemm_bt<6><<<gemm_grid(ENCT, 4608), 256, 0, stream>>>(encb, Wbig, bias3, nullptr, k2b,
                                                        nullptr, nullptr, ENCT, 4608, DIMC, ENCT*DIMC, 6, DIMC, 0);
  rms_bf_k<0,0><<<dim3(STOK), 256, 0, stream>>>(P3, a2_nq, nullptr, nullptr, nullptr);
  rms_bf_k<0,0><<<dim3(ENCT), 256, 0, stream>>>(k2b, a2_nk, nullptr, nullptr, nullptr);
  xattn_k<<<dim3(STOK/64, NH), 256, 0, stream>>>(P3, k2b, v2b, P4);   // crb -> P4
  gemm_bt<4><<<gMN, 256, 0, stream>>>(P4, Wbig + 2*WSLOT, a2_ob, x2, nullptr, x1, nullptr, STOK, DIMC, DIMC, DIMC, 6, DIMC, 0);

  // ---- FF ----
  ln_mod_k<<<dim3(STOK), 256, 0, stream>>>(x2, modsb, 3, 4, nh2b);
  for (int q = 0; q < 2; ++q){                 // ff_inv in 2 column slices of 6720
    int c0 = q*6720;
    cvtT3(ff_inv_w, ff_inv_w, ff_inv_w, Wbig, DIMC, HID2, c0, 6720, 6912, DIMC, 0, 1);
    gemm_bt<1><<<gemm_grid(STOK, 6912), 256, 0, stream>>>(nh2b, Wbig, ff_inv_b + c0, nullptr, y1b + c0,
                                                          nullptr, nullptr, STOK, 6720, DIMC, HID2, 6, DIMC, 0);
  }
  dw_k<<<dim3(224, 14), 256, 0, stream>>>(y1b, ff_dw, ff_db, y2b);
  // y1b dead -> y3pad margins may be zeroed now
  zpad_k<<<dim3(490), 256, 0, stream>>>(y3pad, y3pad + (size_t)(448 + STOK)*DIMC);
  cvtT3(ff_pw, ff_pw, ff_pw, Wbig, HID1, DIMC, 0, DIMC, 2304, HID1, 0, 1);   // point conv weights
  gemm_bt<2><<<gMN, 256, 0, stream>>>(y2b, Wbig, nullptr, nullptr, y3,
                                      nullptr, nullptr, STOK, DIMC, HID1, DIMC, 2, HID1, 0);
  // temporal conv + final residual fused: out = x2 + g_mlp*(y3 + tc)  (one K=6720 GEMM)
  cvtT3(ff_tw, ff_tw + (size_t)DD, ff_tw + (size_t)2*DD, Wbig,
        DIMC, DIMC, 0, DIMC, 2304, 6720, 2240LL, 3);   // Bt [2304][6720], col-sec = W_sec
  gemm_bt<7><<<gMN, 256, 0, stream>>>(y3pad, Wbig, nullptr, out, y3, x2, modsb + 5*DIMC,
                                      STOK, DIMC, 6720, DIMC, 2, DIMC, 1);
}

// Round 13
// 1331.726 us; speedup vs baseline: 1.2807x; 1.0198x over previous
//
#include <hip/hip_runtime.h>

#define DIMC 2240
#define STOK 3584
#define ENCT 300
#define NH   20
#define HDIM 112
#define HID1 6720
#define HID2 13440
#define DD   (2240*2240)
#define SD   (3584*2240)

typedef short bf16x8 __attribute__((ext_vector_type(8)));   // guide-verified operand type
typedef float f32x4  __attribute__((ext_vector_type(4)));

__device__ __forceinline__ unsigned short f2bf(float f){
  unsigned int u = __float_as_uint(f);
  u += 0x7fffu + ((u >> 16) & 1u);          // RNE
  return (unsigned short)(u >> 16);
}
__device__ __forceinline__ float bf2f(unsigned short h){
  return __uint_as_float(((unsigned int)h) << 16);
}
__device__ __forceinline__ void gl_lds16(const unsigned short* g, unsigned short* l){
  __builtin_amdgcn_global_load_lds(
      (const __attribute__((address_space(1))) unsigned int*)(const void*)g,
      (__attribute__((address_space(3))) unsigned int*)(void*)l, 16, 0, 0);
}

// -------- prep: mods = sst + ts; pack 5 biases into [5][2304]; convert enc to bf16 ----
__global__ void prep_k(const float* __restrict__ sst, const float* __restrict__ ts,
    float* __restrict__ mods,
    const float* __restrict__ b0, const float* __restrict__ b1, const float* __restrict__ b2,
    const float* __restrict__ b3, const float* __restrict__ b4, float* __restrict__ bias5,
    const float4* __restrict__ encs, ushort4* __restrict__ encd){
  int i = blockIdx.x*256 + threadIdx.x;
  if (i < 168000){                       // ENCT*DIMC/4
    float4 v = encs[i];
    ushort4 o; o.x = f2bf(v.x); o.y = f2bf(v.y); o.z = f2bf(v.z); o.w = f2bf(v.w);
    encd[i] = o;
  }
  if (i < 6*DIMC) mods[i] = sst[i] + ts[i];
  if (i < 5*2304){
    int slot = i / 2304, d = i - slot*2304;
    const float* s = (slot==0)?b0 : (slot==1)?b1 : (slot==2)?b2 : (slot==3)?b3 : b4;
    bias5[i] = (d < 2240) ? s[d] : 0.f;
  }
}

// -- fp32 (rows x cols slice) -> bf16 TRANSPOSED [ncPad][ldd], zero-padded, multi-src --
__global__ __launch_bounds__(256) void cvtT3_k(const float* __restrict__ s0,
    const float* __restrict__ s1, const float* __restrict__ s2,
    unsigned short* __restrict__ dst, int rows, int ldsrc, int c0, int nc,
    int ldd, long long dzoff){
  const float* src = (blockIdx.z == 0) ? s0 : ((blockIdx.z == 1) ? s1 : s2);
  unsigned short* d = dst + (size_t)blockIdx.z * (size_t)dzoff;
  __shared__ float tile[32][33];
  const int tx = threadIdx.x & 31, ty = threadIdx.x >> 5;   // ty 0..7
  const int colBase = blockIdx.x*32;
  #pragma unroll
  for (int i = 0; i < 4; ++i){
    int rr = blockIdx.y*32 + ty + i*8;
    int cc = colBase + tx;
    tile[ty + i*8][tx] = (cc < nc) ? src[(size_t)rr*ldsrc + c0 + cc] : 0.f;
  }
  __syncthreads();
  #pragma unroll
  for (int i = 0; i < 4; ++i){
    int n = colBase + ty + i*8;          // < ncPad by grid
    int k = blockIdx.y*32 + tx;
    d[(size_t)n*ldd + k] = f2bf(tile[tx][ty + i*8]);
  }
}

// ---------------- zero the two 448-row margins of y3pad ----------------
__global__ void zpad_k(unsigned short* __restrict__ m0, unsigned short* __restrict__ m1){
  int i = blockIdx.x*256 + threadIdx.x;       // uint4 index; 448*2240/8 = 125440
  if (i < 125440){
    reinterpret_cast<uint4*>(m0)[i] = make_uint4(0u,0u,0u,0u);
    reinterpret_cast<uint4*>(m1)[i] = make_uint4(0u,0u,0u,0u);
  }
}

// ---------------- LayerNorm * (1+sc) + sh -> bf16 (fp32 input) ----------------
__global__ __launch_bounds__(256) void ln_mod_k(const float* __restrict__ x,
    const float* __restrict__ mods, int shj, int scj, unsigned short* __restrict__ out)
{
  const int s = blockIdx.x;
  const float4* row4 = reinterpret_cast<const float4*>(x + (size_t)s*DIMC);
  const float4* sh4 = reinterpret_cast<const float4*>(mods + shj*DIMC);
  const float4* sc4 = reinterpret_cast<const float4*>(mods + scj*DIMC);
  float sum = 0.f, sq = 0.f;
  for (int o = threadIdx.x; o < 560; o += 256){
    float4 v = row4[o];
    sum += v.x + v.y + v.z + v.w;
    sq  += v.x*v.x + v.y*v.y + v.z*v.z + v.w*v.w;
  }
  #pragma unroll
  for (int o = 32; o; o >>= 1){ sum += __shfl_down(sum, o); sq += __shfl_down(sq, o); }
  __shared__ float sA[4], sB[4];
  int w = threadIdx.x >> 6, l = threadIdx.x & 63;
  if (!l){ sA[w] = sum; sB[w] = sq; }
  __syncthreads();
  sum = sA[0]+sA[1]+sA[2]+sA[3];
  sq  = sB[0]+sB[1]+sB[2]+sB[3];
  float mean = sum * (1.f/DIMC);
  float rs = rsqrtf(sq*(1.f/DIMC) - mean*mean + 1e-6f);
  unsigned short* orow = out + (size_t)s*DIMC;
  for (int o = threadIdx.x; o < 560; o += 256){
    float4 v = row4[o], sc = sc4[o], sh = sh4[o];
    ushort4 r;
    r.x = f2bf((v.x-mean)*rs*(1.f + sc.x) + sh.x);
    r.y = f2bf((v.y-mean)*rs*(1.f + sc.y) + sh.y);
    r.z = f2bf((v.z-mean)*rs*(1.f + sc.z) + sh.z);
    r.w = f2bf((v.w-mean)*rs*(1.f + sc.w) + sh.w);
    *reinterpret_cast<ushort4*>(orow + o*4) = r;
  }
}

// ---------------- LayerNorm * (1+sc) + sh -> bf16 (bf16 input) ----------------
__global__ __launch_bounds__(256) void ln_mod_bf_k(const unsigned short* __restrict__ x,
    const float* __restrict__ mods, int shj, int scj, unsigned short* __restrict__ out)
{
  const int s = blockIdx.x;
  const unsigned short* row = x + (size_t)s*DIMC;
  float sum = 0.f, sq = 0.f;
  for (int o = threadIdx.x; o < 280; o += 256){
    uint4 v = *reinterpret_cast<const uint4*>(row + o*8);
    unsigned int uu[4] = {v.x, v.y, v.z, v.w};
    #pragma unroll
    for (int j = 0; j < 4; ++j){
      float lo = bf2f((unsigned short)(uu[j] & 0xffffu));
      float hi = bf2f((unsigned short)(uu[j] >> 16));
      sum += lo + hi; sq += lo*lo + hi*hi;
    }
  }
  #pragma unroll
  for (int o = 32; o; o >>= 1){ sum += __shfl_down(sum, o); sq += __shfl_down(sq, o); }
  __shared__ float sA[4], sB[4];
  int w = threadIdx.x >> 6, l = threadIdx.x & 63;
  if (!l){ sA[w] = sum; sB[w] = sq; }
  __syncthreads();
  sum = sA[0]+sA[1]+sA[2]+sA[3];
  sq  = sB[0]+sB[1]+sB[2]+sB[3];
  float mean = sum * (1.f/DIMC);
  float rs = rsqrtf(sq*(1.f/DIMC) - mean*mean + 1e-6f);
  unsigned short* orow = out + (size_t)s*DIMC;
  const float* sh = mods + shj*DIMC;
  const float* sc = mods + scj*DIMC;
  for (int o = threadIdx.x; o < 280; o += 256){
    uint4 v = *reinterpret_cast<const uint4*>(row + o*8);
    unsigned int uu[4] = {v.x, v.y, v.z, v.w};
    uint4 ov;
    unsigned int* po = &ov.x;
    #pragma unroll
    for (int j = 0; j < 4; ++j){
      int d0 = o*8 + 2*j;
      float lo = (bf2f((unsigned short)(uu[j] & 0xffffu)) - mean)*rs*(1.f + sc[d0])   + sh[d0];
      float hi = (bf2f((unsigned short)(uu[j] >> 16))     - mean)*rs*(1.f + sc[d0+1]) + sh[d0+1];
      po[j] = (unsigned int)f2bf(lo) | ((unsigned int)f2bf(hi) << 16);
    }
    *reinterpret_cast<uint4*>(orow + o*8) = ov;
  }
}

// -------- merged q/k RMS + ReLU + RoPE (grid.y = 0:q, 1:k), uint4-vectorized ---------
__global__ __launch_bounds__(256) void rmsqk_k(unsigned short* __restrict__ qx,
    unsigned short* __restrict__ kx, const float* __restrict__ nq, const float* __restrict__ nk,
    const float* __restrict__ cosb, const float* __restrict__ sinb,
    unsigned short* __restrict__ qr, unsigned short* __restrict__ kr)
{
  const int s = blockIdx.x;
  unsigned short* row = (blockIdx.y ? kx : qx) + (size_t)s*DIMC;
  const float* nw = blockIdx.y ? nk : nq;
  unsigned short* xr = (blockIdx.y ? kr : qr) + (size_t)s*DIMC;
  float sq = 0.f;
  for (int o = threadIdx.x; o < 280; o += 256){
    uint4 v = *reinterpret_cast<const uint4*>(row + o*8);
    unsigned int uu[4] = {v.x, v.y, v.z, v.w};
    #pragma unroll
    for (int j = 0; j < 4; ++j){
      float lo = bf2f((unsigned short)(uu[j] & 0xffffu));
      float hi = bf2f((unsigned short)(uu[j] >> 16));
      sq += lo*lo + hi*hi;
    }
  }
  #pragma unroll
  for (int o = 32; o; o >>= 1) sq += __shfl_down(sq, o);
  __shared__ float sB[4];
  int w = threadIdx.x >> 6, l = threadIdx.x & 63;
  if (!l) sB[w] = sq;
  __syncthreads();
  sq = sB[0]+sB[1]+sB[2]+sB[3];
  float rs = rsqrtf(sq*(1.f/DIMC) + 1e-5f);
  for (int o = threadIdx.x; o < 280; o += 256){
    uint4 v = *reinterpret_cast<const uint4*>(row + o*8);
    unsigned int uu[4] = {v.x, v.y, v.z, v.w};
    float4 n0 = *reinterpret_cast<const float4*>(nw + o*8);
    float4 n1 = *reinterpret_cast<const float4*>(nw + o*8 + 4);
    float nn[8] = {n0.x,n0.y,n0.z,n0.w,n1.x,n1.y,n1.z,n1.w};
    float vals[8];
    #pragma unroll
    for (int j = 0; j < 4; ++j){
      vals[2*j]   = fmaxf(bf2f((unsigned short)(uu[j] & 0xffffu))*rs*nn[2*j],   0.f);
      vals[2*j+1] = fmaxf(bf2f((unsigned short)(uu[j] >> 16))*rs*nn[2*j+1], 0.f);
    }
    uint4 o1;
    unsigned int* po = &o1.x;
    #pragma unroll
    for (int j = 0; j < 4; ++j)
      po[j] = (unsigned int)f2bf(vals[2*j]) | ((unsigned int)f2bf(vals[2*j+1]) << 16);
    *reinterpret_cast<uint4*>(row + o*8) = o1;
    int jb = (o*8) % HDIM;                      // octet stays within a head (112%8==0)
    uint4 o2;
    unsigned int* pr = &o2.x;
    #pragma unroll
    for (int p = 0; p < 4; ++p){
      float c  = cosb[(size_t)s*HDIM + jb + 2*p];
      float sn = sinb[(size_t)s*HDIM + jb + 2*p + 1];
      float r0 = vals[2*p]*c - vals[2*p+1]*sn;
      float r1 = vals[2*p]*sn + vals[2*p+1]*c;
      pr[p] = (unsigned int)f2bf(r0) | ((unsigned int)f2bf(r1) << 16);
    }
    *reinterpret_cast<uint4*>(xr + o*8) = o2;
  }
}

// -------- merged plain RMS: rows [0,STOK) -> xa/na, rows [STOK,STOK+ENCT) -> xb/nb ----
__global__ __launch_bounds__(256) void rmsnn_k(unsigned short* __restrict__ xa,
    const float* __restrict__ na, unsigned short* __restrict__ xb, const float* __restrict__ nb)
{
  int s = blockIdx.x;
  unsigned short* row; const float* nw;
  if (s < STOK){ row = xa + (size_t)s*DIMC; nw = na; }
  else         { row = xb + (size_t)(s - STOK)*DIMC; nw = nb; }
  float sq = 0.f;
  for (int o = threadIdx.x; o < 280; o += 256){
    uint4 v = *reinterpret_cast<const uint4*>(row + o*8);
    unsigned int uu[4] = {v.x, v.y, v.z, v.w};
    #pragma unroll
    for (int j = 0; j < 4; ++j){
      float lo = bf2f((unsigned short)(uu[j] & 0xffffu));
      float hi = bf2f((unsigned short)(uu[j] >> 16));
      sq += lo*lo + hi*hi;
    }
  }
  #pragma unroll
  for (int o = 32; o; o >>= 1) sq += __shfl_down(sq, o);
  __shared__ float sB[4];
  int w = threadIdx.x >> 6, l = threadIdx.x & 63;
  if (!l) sB[w] = sq;
  __syncthreads();
  sq = sB[0]+sB[1]+sB[2]+sB[3];
  float rs = rsqrtf(sq*(1.f/DIMC) + 1e-5f);
  for (int o = threadIdx.x; o < 280; o += 256){
    uint4 v = *reinterpret_cast<const uint4*>(row + o*8);
    unsigned int uu[4] = {v.x, v.y, v.z, v.w};
    float4 n0 = *reinterpret_cast<const float4*>(nw + o*8);
    float4 n1 = *reinterpret_cast<const float4*>(nw + o*8 + 4);
    float nn[8] = {n0.x,n0.y,n0.z,n0.w,n1.x,n1.y,n1.z,n1.w};
    uint4 o1;
    unsigned int* po = &o1.x;
    #pragma unroll
    for (int j = 0; j < 4; ++j){
      float lo = bf2f((unsigned short)(uu[j] & 0xffffu))*rs*nn[2*j];
      float hi = bf2f((unsigned short)(uu[j] >> 16))*rs*nn[2*j+1];
      po[j] = (unsigned int)f2bf(lo) | ((unsigned int)f2bf(hi) << 16);
    }
    *reinterpret_cast<uint4*>(row + o*8) = o1;
  }
}

// ------- bf16 MFMA GEMM: C = A(MxK) @ Bt^T, Bt is [Npad][K] (N-major), BK=64 ---------
// (round-7 proven structure) Both-sides swizzle; K % 64 == 0; PW | gridDim.x.
// lda: A row stride. tcsh=1: temporal-conv mode — K-section sec (2240 wide) reads A at
// row + sec*448; A must point at the PADDED base (row 0 = center_row - 448).
// EPI: 0 Cf=acc+bias | 1 Cb=bf16(silu(acc+bias)) | 2 Cb=bf16(acc+bias)
//      3 Cb=bf16(res+gate*(acc+bias))           [res fp32]
//      6 slot-split: slot=col/2304, d=col%2304; if d<2240: Cb[slot*ldc + row*2240 + d]
//      7 Cf = bf2f(resb[idx]) + gate[col]*(bf2f(Cb[idx]) + acc)   [resb = (ushort*)res]
//      8 Cb = bf16(bf2f(resb[idx]) + acc + bias)                   [resb = (ushort*)res]
template<int EPI>
__global__ __launch_bounds__(256) void gemm_bt(
  const unsigned short* __restrict__ A, const unsigned short* __restrict__ Bt,
  const float* __restrict__ bias, float* __restrict__ Cf, unsigned short* __restrict__ Cb,
  const float* __restrict__ res, const float* __restrict__ gate,
  int M, int N, int K, int ldc, int PW, int lda, int tcsh)
{
  __shared__ __align__(16) unsigned short Al[128*64];
  __shared__ __align__(16) unsigned short Bl[128*64];
  const int gx = gridDim.x, gy = gridDim.y;
  const int nwg = gx*gy;
  const int orig = blockIdx.y*gx + blockIdx.x;
  // bijective XCD-aware remap (m204)
  const int qq = nwg >> 3, rr = nwg & 7;
  const int xcd = orig & 7, li = orig >> 3;
  const int wg = (xcd < rr ? xcd*(qq+1) : rr*(qq+1) + (xcd-rr)*qq) + li;
  // N-panel rasterization: panel of PW n-tiles covers all gy m-rows before advancing
  const int ppw = gy*PW;
  const int panel = wg / ppw, rm = wg - panel*ppw;
  const int mrow = rm / PW;
  const int m0 = mrow*128;
  const int n0 = (panel*PW + (rm - mrow*PW))*128;

  const int t = threadIdx.x, lane = t & 63, w = t >> 6;
  const int wr = w >> 1, wc = w & 1;
  const int l16 = lane & 15, lk = lane >> 4;

  // staging: per wave 4 A-chunks + 4 B-chunks (each 1KB = 8 rows x 128B), swizzled src
  const int lr8 = lane >> 3;           // row within 8-row block (== row&7)
  const int sc  = (lane & 7) ^ lr8;    // pre-swizzled source chunk
  const unsigned short* Aps[4];
  const unsigned short* Bps[4];
  #pragma unroll
  for (int i = 0; i < 4; ++i){
    int ar = m0 + w*32 + i*8 + lr8;
    int br = n0 + w*32 + i*8 + lr8;
    Aps[i] = A  + (size_t)min(ar, M-1)*lda + sc*8;
    Bps[i] = Bt + (size_t)br*K + sc*8;
  }
  unsigned short* Ad = Al + w*2048;
  unsigned short* Bd = Bl + w*2048;

  f32x4 acc[4][4] = {};
  for (int k0 = 0; k0 < K; k0 += 64){
    size_t aoff;
    if (tcsh){
      int sec = (k0 >= 4480) ? 2 : ((k0 >= 2240) ? 1 : 0);
      aoff = (size_t)(sec*448)*lda + (unsigned)(k0 - sec*2240);
    } else {
      aoff = (size_t)k0;
    }
    __syncthreads();
    #pragma unroll
    for (int i = 0; i < 4; ++i){
      gl_lds16(Aps[i] + aoff, Ad + i*512);
      gl_lds16(Bps[i] + k0,   Bd + i*512);
    }
    __syncthreads();
    #pragma unroll
    for (int kk = 0; kk < 2; ++kk){
      bf16x8 af[4], bfr[4];
      const int chb = (kk*4 + lk) ^ (l16 & 7);   // swizzled read chunk
      #pragma unroll
      for (int m = 0; m < 4; ++m)
        af[m] = *reinterpret_cast<const bf16x8*>(Al + (wr*64 + m*16 + l16)*64 + chb*8);
      #pragma unroll
      for (int n = 0; n < 4; ++n)
        bfr[n] = *reinterpret_cast<const bf16x8*>(Bl + (wc*64 + n*16 + l16)*64 + chb*8);
      #pragma unroll
      for (int m = 0; m < 4; ++m)
        #pragma unroll
        for (int n = 0; n < 4; ++n)
          acc[m][n] = __builtin_amdgcn_mfma_f32_16x16x32_bf16(af[m], bfr[n], acc[m][n], 0, 0, 0);
    }
  }

  const int rb = m0 + wr*64 + lk*4;   // C/D: col = lane&15, row = (lane>>4)*4 + reg
  const int cb = n0 + wc*64 + l16;
  #pragma unroll
  for (int m = 0; m < 4; ++m){
    #pragma unroll
    for (int r = 0; r < 4; ++r){
      int row = rb + m*16 + r;
      if (row >= M) continue;
      #pragma unroll
      for (int n = 0; n < 4; ++n){
        int col = cb + n*16;
        if (col >= N) continue;
        float v = acc[m][n][r];
        float bv = bias ? bias[col] : 0.f;
        if constexpr (EPI == 6){
          int slot = col / 2304;
          int d = col - slot*2304;
          if (d < 2240)
            Cb[(size_t)slot*ldc + (size_t)row*2240 + d] = f2bf(v + bv);
        } else {
          size_t idx = (size_t)row*ldc + col;
          if constexpr (EPI == 0){ Cf[idx] = v + bv; }
          else if constexpr (EPI == 1){ float u = v + bv; Cb[idx] = f2bf(u / (1.f + __expf(-u))); }
          else if constexpr (EPI == 2){ Cb[idx] = f2bf(v + bv); }
          else if constexpr (EPI == 3){ float u = res[idx] + gate[col]*(v + bv); Cb[idx] = f2bf(u); }
          else if constexpr (EPI == 7){
            const unsigned short* resb = (const unsigned short*)(const void*)res;
            Cf[idx] = bf2f(resb[idx]) + gate[col]*(bf2f(Cb[idx]) + v);
          }
          else if constexpr (EPI == 8){
            const unsigned short* resb = (const unsigned short*)(const void*)res;
            Cb[idx] = f2bf(bf2f(resb[idx]) + v + bv);
          }
          else { Cf[idx] += v; }
        }
      }
    }
  }
}

// ---------------- linear attention helpers ----------------
__global__ void colsum_k(const unsigned short* __restrict__ k, float* __restrict__ kpart){
  int d = blockIdx.x*256 + threadIdx.x;
  if (d >= DIMC) return;
  int ch = blockIdx.y, s0 = ch*128;
  float acc = 0.f;
  for (int s = s0; s < s0+128; ++s) acc += bf2f(k[(size_t)s*DIMC + d]);
  kpart[(size_t)ch*DIMC + d] = acc;
}
__global__ void ksumred_k(const float* __restrict__ kpart, float* __restrict__ ksum){
  int d = blockIdx.x*256 + threadIdx.x;
  if (d >= DIMC) return;
  float a = 0.f;
  for (int c = 0; c < 28; ++c) a += kpart[(size_t)c*DIMC + d];
  ksum[d] = a;
}
__global__ __launch_bounds__(256) void denom_k(const unsigned short* __restrict__ q,
    const float* __restrict__ ksum, float* __restrict__ denom)
{
  int s = blockIdx.x; int w = threadIdx.x >> 6, l = threadIdx.x & 63;
  for (int h = w; h < NH; h += 4){
    const unsigned short* qb = q + (size_t)s*DIMC + h*HDIM;
    const float* kb = ksum + h*HDIM;
    float v = bf2f(qb[l])*kb[l];
    if (l < 48) v += bf2f(qb[64+l])*kb[64+l];
    #pragma unroll
    for (int o = 32; o; o >>= 1) v += __shfl_down(v, o);
    if (!l) denom[s*NH + h] = v + 1e-15f;
  }
}

// -------- MFMA scores: part[ch][h][e][d] = sum_{s in 128-chunk} V[s,h,e]*Kr[s,h,d] -----
#define SLSC 136
__device__ __forceinline__ int sc_idx(int e, int s){
  return e*SLSC + (s ^ (((e >> 3) & 7) << 3));
}
__global__ __launch_bounds__(256) void scores_k(const unsigned short* __restrict__ v,
    const unsigned short* __restrict__ kr, float* __restrict__ part)
{
  const int h = blockIdx.x, ch = blockIdx.y;
  __shared__ __align__(16) unsigned short Vt[112*SLSC];
  __shared__ __align__(16) unsigned short Kt[112*SLSC];
  const int t = threadIdx.x, lane = t & 63, w = t >> 6;
  const int l16 = lane & 15, lk = lane >> 4;
  const int sbase = ch*128;

  for (int p = t; p < 1792; p += 256){       // 128 tokens x 14 dim-octets
    int s = p / 14, oc = (p % 14) * 8;
    bf16x8 vv = *reinterpret_cast<const bf16x8*>(v  + (size_t)(sbase+s)*DIMC + h*HDIM + oc);
    bf16x8 kk = *reinterpret_cast<const bf16x8*>(kr + (size_t)(sbase+s)*DIMC + h*HDIM + oc);
    #pragma unroll
    for (int j = 0; j < 8; ++j){
      Vt[sc_idx(oc+j, s)] = (unsigned short)vv[j];
      Kt[sc_idx(oc+j, s)] = (unsigned short)kk[j];
    }
  }
  __syncthreads();

  f32x4 acc[2][7] = {};                      // wave w owns m-tiles {w, w+4}
  #pragma unroll
  for (int ks = 0; ks < 4; ++ks){
    const int sf = ks*32 + lk*8;
    bf16x8 bfrg[7];
    #pragma unroll
    for (int nt = 0; nt < 7; ++nt){
      int d = nt*16 + l16;
      bfrg[nt] = *reinterpret_cast<const bf16x8*>(&Kt[d*SLSC + (sf ^ (((d >> 3) & 7) << 3))]);
    }
    #pragma unroll
    for (int mi = 0; mi < 2; ++mi){
      int mt = w + mi*4;
      if (mt < 7){
        int e = mt*16 + l16;
        bf16x8 afrg = *reinterpret_cast<const bf16x8*>(&Vt[e*SLSC + (sf ^ (((e >> 3) & 7) << 3))]);
        #pragma unroll
        for (int nt = 0; nt < 7; ++nt)
          acc[mi][nt] = __builtin_amdgcn_mfma_f32_16x16x32_bf16(afrg, bfrg[nt], acc[mi][nt], 0, 0, 0);
      }
    }
  }

  float* pout = part + ((size_t)ch*NH + h)*12544;
  #pragma unroll
  for (int mi = 0; mi < 2; ++mi){
    int mt = w + mi*4;
    if (mt >= 7) continue;
    #pragma unroll
    for (int nt = 0; nt < 7; ++nt)
      #pragma unroll
      for (int r = 0; r < 4; ++r)
        pout[(size_t)(mt*16 + lk*4 + r)*HDIM + nt*16 + l16] = acc[mi][nt][r];
  }
}
__global__ void scred_k(const float* __restrict__ part, unsigned short* __restrict__ sc){
  int i = blockIdx.x*256 + threadIdx.x;
  if (i >= NH*HDIM*HDIM) return;
  float a = 0.f;
  #pragma unroll
  for (int c = 0; c < 28; ++c) a += part[(size_t)c*(NH*HDIM*HDIM) + i];
  sc[i] = f2bf(a);
}

// -------- MFMA linout: out[s,h*112+e] = (sum_d scores[h,e,d]*qr[s,h,d]) / denom[s,h] ---
__global__ __launch_bounds__(256) void linout_k(const unsigned short* __restrict__ qr,
    const unsigned short* __restrict__ scores, const float* __restrict__ denom,
    unsigned short* __restrict__ out)
{
  const int h = blockIdx.y;
  const int t = threadIdx.x, lane = t & 63, w = t >> 6;
  const int l16 = lane & 15, lk = lane >> 4;
  const int s0 = blockIdx.x*64 + w*16;
  const unsigned short* qrow = qr + (size_t)(s0 + l16)*DIMC + h*HDIM;
  const unsigned short* sb = scores + (size_t)h*12544;
  f32x4 acc[7] = {};
  #pragma unroll
  for (int ks = 0; ks < 4; ++ks){
    int d0 = ks*32 + lk*8;
    bf16x8 a = {};
    if (d0 < HDIM) a = *reinterpret_cast<const bf16x8*>(qrow + d0);
    #pragma unroll
    for (int nt = 0; nt < 7; ++nt){
      bf16x8 b = {};
      if (d0 < HDIM) b = *reinterpret_cast<const bf16x8*>(sb + (size_t)(nt*16 + l16)*HDIM + d0);
      acc[nt] = __builtin_amdgcn_mfma_f32_16x16x32_bf16(a, b, acc[nt], 0, 0, 0);
    }
  }
  #pragma unroll
  for (int r = 0; r < 4; ++r){
    int s = s0 + lk*4 + r;
    float dn = 1.f / denom[(size_t)s*NH + h];
    #pragma unroll
    for (int nt = 0; nt < 7; ++nt)
      out[(size_t)s*DIMC + h*HDIM + nt*16 + l16] = f2bf(acc[nt][r]*dn);
  }
}

// ---------------- fused cross-attention, MFMA (300 keys, head dim 112 padded to 128) ----
__global__ __launch_bounds__(256) void xattn_k(
    const unsigned short* __restrict__ q,   // S x DIM bf16 (rms-normed)
    const unsigned short* __restrict__ k2,  // ENCT x DIM bf16 (rms-normed)
    const unsigned short* __restrict__ v2,  // ENCT x DIM bf16
    unsigned short* __restrict__ outb)      // S x DIM bf16
{
  const int h = blockIdx.y;
  const int w = threadIdx.x >> 6, lane = threadIdx.x & 63;
  const int l16 = lane & 15, lk = lane >> 4;
  const float scale = 0.09449111825230679f;   // 1/sqrt(112)

  __shared__ __align__(16) unsigned short Kl[64][136];
  __shared__ __align__(16) unsigned short Vl[112][72];
  __shared__ __align__(16) unsigned short Pl[4][16][72];

  bf16x8 qf[4];
  const unsigned short* qbase = q + (size_t)(blockIdx.x*64 + w*16 + l16)*DIMC + h*HDIM;
  #pragma unroll
  for (int c = 0; c < 4; ++c){
    int d0 = c*32 + lk*8;
    bf16x8 z = {};
    qf[c] = (d0 < HDIM) ? *reinterpret_cast<const bf16x8*>(qbase + d0) : z;
  }

  f32x4 lg[5][4] = {};
  #pragma unroll
  for (int c = 0; c < 5; ++c){
    const int kbase = c*64;
    const int nk = (c == 4) ? (ENCT - 256) : 64;
    __syncthreads();
    #pragma unroll
    for (int it = 0; it < 4; ++it){
      int li = it*256 + threadIdx.x;
      int key = li >> 4, d0 = (li & 15) << 3;
      uint4 val = make_uint4(0u,0u,0u,0u);
      if (key < nk && d0 < HDIM)
        val = *reinterpret_cast<const uint4*>(k2 + (size_t)(kbase+key)*DIMC + h*HDIM + d0);
      *reinterpret_cast<uint4*>(&Kl[key][d0]) = val;
    }
    __syncthreads();
    #pragma unroll
    for (int nt = 0; nt < 4; ++nt){
      #pragma unroll
      for (int ks = 0; ks < 4; ++ks){
        bf16x8 kf = *reinterpret_cast<const bf16x8*>(&Kl[nt*16 + l16][ks*32 + lk*8]);
        lg[c][nt] = __builtin_amdgcn_mfma_f32_16x16x32_bf16(qf[ks], kf, lg[c][nt], 0, 0, 0);
      }
    }
  }

  float mx[4] = {-3e38f, -3e38f, -3e38f, -3e38f};
  #pragma unroll
  for (int c = 0; c < 5; ++c)
    #pragma unroll
    for (int nt = 0; nt < 4; ++nt){
      bool valid = (c*64 + nt*16 + l16) < ENCT;
      #pragma unroll
      for (int r = 0; r < 4; ++r){
        float v = valid ? lg[c][nt][r]*scale : -3e38f;
        lg[c][nt][r] = v;
        mx[r] = fmaxf(mx[r], v);
      }
    }
  #pragma unroll
  for (int o = 1; o < 16; o <<= 1)
    #pragma unroll
    for (int r = 0; r < 4; ++r) mx[r] = fmaxf(mx[r], __shfl_xor(mx[r], o));
  float sm[4] = {0.f, 0.f, 0.f, 0.f};
  #pragma unroll
  for (int c = 0; c < 5; ++c)
    #pragma unroll
    for (int nt = 0; nt < 4; ++nt)
      #pragma unroll
      for (int r = 0; r < 4; ++r){
        float e = __expf(lg[c][nt][r] - mx[r]);
        lg[c][nt][r] = e;
        sm[r] += e;
      }
  #pragma unroll
  for (int o = 1; o < 16; o <<= 1)
    #pragma unroll
    for (int r = 0; r < 4; ++r) sm[r] += __shfl_xor(sm[r], o);
  float inv[4];
  #pragma unroll
  for (int r = 0; r < 4; ++r) inv[r] = 1.f / sm[r];

  f32x4 oacc[7] = {};
  #pragma unroll
  for (int c = 0; c < 5; ++c){
    const int kbase = c*64;
    const int nk = (c == 4) ? (ENCT - 256) : 64;
    __syncthreads();
    #pragma unroll
    for (int it = 0; it < 4; ++it){
      int li = it*256 + threadIdx.x;
      if (li < 896){
        int key = li/14, d0 = (li%14)*8;
        if (key < nk){
          bf16x8 vv = *reinterpret_cast<const bf16x8*>(v2 + (size_t)(kbase+key)*DIMC + h*HDIM + d0);
          #pragma unroll
          for (int j = 0; j < 8; ++j) Vl[d0+j][key] = (unsigned short)vv[j];
        } else {
          #pragma unroll
          for (int j = 0; j < 8; ++j) Vl[d0+j][key] = 0;
        }
      }
    }
    #pragma unroll
    for (int nt = 0; nt < 4; ++nt)
      #pragma unroll
      for (int r = 0; r < 4; ++r)
        Pl[w][lk*4 + r][nt*16 + l16] = f2bf(lg[c][nt][r]);
    __syncthreads();
    #pragma unroll
    for (int ks = 0; ks < 2; ++ks){
      bf16x8 pf = *reinterpret_cast<const bf16x8*>(&Pl[w][l16][ks*32 + lk*8]);
      #pragma unroll
      for (int n = 0; n < 7; ++n){
        bf16x8 vf = *reinterpret_cast<const bf16x8*>(&Vl[n*16 + l16][ks*32 + lk*8]);
        oacc[n] = __builtin_amdgcn_mfma_f32_16x16x32_bf16(pf, vf, oacc[n], 0, 0, 0);
      }
    }
  }

  const int orow = blockIdx.x*64 + w*16 + lk*4;
  #pragma unroll
  for (int n = 0; n < 7; ++n)
    #pragma unroll
    for (int r = 0; r < 4; ++r)
      outb[(size_t)(orow + r)*DIMC + h*HDIM + n*16 + l16] = f2bf(oacc[n][r]*inv[r]);
}

// ------- depthwise 3x3 + bias + GLU(silu): 2 ch x 4 rows x 4 cols per thread ----------
// grid.x = f(8) x ytile(4) x xquad(7) = 224, grid.y = 14
__global__ __launch_bounds__(256) void dw_k(const unsigned short* __restrict__ y1,
    const float* __restrict__ dw, const float* __restrict__ db, unsigned short* __restrict__ y2)
{
  int c = (blockIdx.y*256 + threadIdx.x)*2;
  if (c >= HID1) return;
  int bx = blockIdx.x;
  int xq = bx % 7;
  int yt = (bx / 7) & 3;
  int f  = bx / 28;
  int x0 = xq*4, y0 = yt*4;

  float wa[9][2], wg[9][2];
  #pragma unroll
  for (int tp = 0; tp < 9; ++tp){
    float2 va = *reinterpret_cast<const float2*>(dw + tp*HID2 + c);
    float2 vg = *reinterpret_cast<const float2*>(dw + tp*HID2 + c + HID1);
    wa[tp][0] = va.x; wa[tp][1] = va.y;
    wg[tp][0] = vg.x; wg[tp][1] = vg.y;
  }
  float2 ba = *reinterpret_cast<const float2*>(db + c);
  float2 bg = *reinterpret_cast<const float2*>(db + c + HID1);
  float a[4][4][2], g[4][4][2];
  #pragma unroll
  for (int r = 0; r < 4; ++r)
    #pragma unroll
    for (int cc = 0; cc < 4; ++cc){
      a[r][cc][0] = ba.x; a[r][cc][1] = ba.y;
      g[r][cc][0] = bg.x; g[r][cc][1] = bg.y;
    }

  #pragma unroll
  for (int dy6 = 0; dy6 < 6; ++dy6){
    int y = y0 - 1 + dy6;
    if ((unsigned)y >= 16u) continue;
    #pragma unroll
    for (int dxc = 0; dxc < 6; ++dxc){
      int x = x0 - 1 + dxc;
      if ((unsigned)x >= 28u) continue;
      size_t base = ((size_t)(f*16 + y)*28 + x)*HID2;
      unsigned int a01 = *reinterpret_cast<const unsigned int*>(y1 + base + c);
      unsigned int g01 = *reinterpret_cast<const unsigned int*>(y1 + base + c + HID1);
      float fa0 = bf2f((unsigned short)(a01 & 0xffffu));
      float fa1 = bf2f((unsigned short)(a01 >> 16));
      float fg0 = bf2f((unsigned short)(g01 & 0xffffu));
      float fg1 = bf2f((unsigned short)(g01 >> 16));
      #pragma unroll
      for (int r = 0; r < 4; ++r){
        int kdy = dy6 - r;                    // compile-time after unroll
        if (kdy < 0 || kdy > 2) continue;
        #pragma unroll
        for (int cc = 0; cc < 4; ++cc){
          int kdx = dxc - cc;
          if (kdx < 0 || kdx > 2) continue;
          int tp = kdy*3 + kdx;
          a[r][cc][0] += fa0*wa[tp][0]; a[r][cc][1] += fa1*wa[tp][1];
          g[r][cc][0] += fg0*wg[tp][0]; g[r][cc][1] += fg1*wg[tp][1];
        }
      }
    }
  }
  #pragma unroll
  for (int r = 0; r < 4; ++r)
    #pragma unroll
    for (int cc = 0; cc < 4; ++cc){
      float s0 = g[r][cc][0] / (1.f + __expf(-g[r][cc][0]));
      float s1 = g[r][cc][1] / (1.f + __expf(-g[r][cc][1]));
      int pos = (f*16 + y0 + r)*28 + x0 + cc;
      unsigned int o = (unsigned int)f2bf(a[r][cc][0]*s0) | ((unsigned int)f2bf(a[r][cc][1]*s1) << 16);
      *reinterpret_cast<unsigned int*>(y2 + (size_t)pos*HID1 + c) = o;
    }
}

extern "C" void kernel_launch(void* const* d_in, const int* in_sizes, int n_in,
                              void* d_out, int out_size, void* d_ws, size_t ws_size,
                              hipStream_t stream)
{
  const float* hid   = (const float*)d_in[0];
  const float* enc   = (const float*)d_in[1];
  const float* tstep = (const float*)d_in[2];
  const float* fcos  = (const float*)d_in[3];
  const float* fsin  = (const float*)d_in[4];
  const float* sst   = (const float*)d_in[5];
  const float *a1_qw=(const float*)d_in[6],  *a1_qb=(const float*)d_in[7];
  const float *a1_kw=(const float*)d_in[8],  *a1_kb=(const float*)d_in[9];
  const float *a1_vw=(const float*)d_in[10], *a1_vb=(const float*)d_in[11];
  const float *a1_nq=(const float*)d_in[12], *a1_nk=(const float*)d_in[13];
  const float *a1_ow=(const float*)d_in[14], *a1_ob=(const float*)d_in[15];
  const float *a2_qw=(const float*)d_in[16], *a2_qb=(const float*)d_in[17];
  const float *a2_kw=(const float*)d_in[18], *a2_kb=(const float*)d_in[19];
  const float *a2_vw=(const float*)d_in[20], *a2_vb=(const float*)d_in[21];
  const float *a2_nq=(const float*)d_in[22], *a2_nk=(const float*)d_in[23];
  const float *a2_ow=(const float*)d_in[24], *a2_ob=(const float*)d_in[25];
  const float *ff_inv_w=(const float*)d_in[26], *ff_inv_b=(const float*)d_in[27];
  const float *ff_dw=(const float*)d_in[28], *ff_db=(const float*)d_in[29];
  const float *ff_pw=(const float*)d_in[30];
  const float *ff_tw=(const float*)d_in[31];
  float* out = (float*)d_out;

  // ---- workspace plan (~213 MB total; all sizes 256-multiple) ----
  const size_t SLOTB = (size_t)SD*2;        // 16,056,320 B  (one bf16 S x DIM slot)
  char* ws = (char*)d_ws;
  size_t off = 0;
  auto alloc = [&](size_t n){ void* p = ws + off; off += (n + 255) & ~(size_t)255; return p; };

  char* P = (char*)alloc(6*SLOTB);          // 6 bf16 activation slots (96.3 MB)
  float* x1    = (float*)alloc((size_t)SD*4);     // region reused: y2b spans x1+nh2b
  unsigned short* nh2b = (unsigned short*)alloc(SLOTB); // MUST follow x1 (y2b spans both)
  float* x2    = (float*)alloc((size_t)SD*4);     // first half used as bf16 x2b
  unsigned short* k2b = (unsigned short*)alloc((size_t)ENCT*DIMC*2);  // k2b+v2b contiguous
  unsigned short* v2b = (unsigned short*)alloc((size_t)ENCT*DIMC*2);
  unsigned short* encb = (unsigned short*)alloc((size_t)ENCT*DIMC*2);
  float* modsb = (float*)alloc(6*DIMC*4);
  float* ksum  = (float*)alloc(DIMC*4);
  float* kpart = (float*)alloc((size_t)28*DIMC*4);
  float* denom = (float*)alloc((size_t)STOK*NH*4);
  unsigned short* scorb = (unsigned short*)alloc((size_t)NH*HDIM*HDIM*2);
  float* bias5 = (float*)alloc(5*2304*4);
  unsigned short* Wbig = (unsigned short*)alloc((size_t)6912*DIMC*2);  // 31 MB weight staging

  // P-slot aliases (lifetimes verified disjoint)
  unsigned short* P0 = (unsigned short*)P;                 // nhb | y1b[0:] | y3pad
  unsigned short* P1 = (unsigned short*)(P + 1*SLOTB);     // qb | spart | lob | y1b | y3pad tail
  unsigned short* P2 = (unsigned short*)(P + 2*SLOTB);     // kb | spart | x1b | y1b
  unsigned short* P3 = (unsigned short*)(P + 3*SLOTB);     // vb | q2b | y1b
  unsigned short* P4 = (unsigned short*)(P + 4*SLOTB);     // qrb | crb | y1b
  unsigned short* P5 = (unsigned short*)(P + 5*SLOTB);     // krb | y1b
  unsigned short* nhb = P0;
  unsigned short* y1b = P0;                                // 96.34 MB = slots 0..5 exactly
  unsigned short* y2b = (unsigned short*)x1;               // 48.17 MB = x1 + nh2b exactly
  unsigned short* y3pad = P0;                              // (448+3584+448) x 2240 = 20.1 MB
  unsigned short* y3  = y3pad + (size_t)448*DIMC;          // center: point-conv output
  unsigned short* x2b = (unsigned short*)x2;               // bf16 residual spine (16 MB)
  float* spart = (float*)P1;   // 28 x NH x 112 x 112 fp32 = 28.1 MB, q/k dead by then

  // multi-source transpose-convert: z in [0,nz) -> dst + z*dzoff, [ncPad x ldd]
  auto cvtT3 = [&](const float* s0, const float* s1, const float* s2, unsigned short* d,
                   int rows, int ldsrc, int c0, int nc, int ncPad, int ldd, long long dzoff, int nz){
    cvtT3_k<<<dim3(ncPad/32, rows/32, nz), 256, 0, stream>>>(s0, s1, s2, d, rows, ldsrc, c0, nc, ldd, dzoff);
  };
  auto gemm_grid = [&](int M, int Npad){ return dim3(Npad/128, (M+127)/128); };
  const long long WSLOT = (long long)2304*DIMC;

  // prep: mods + 5-bias pack + enc convert (one launch)
  prep_k<<<dim3(657), 256, 0, stream>>>(sst, tstep, modsb,
      a1_qb, a1_kb, a1_vb, a2_kb, a2_vb, bias5, (const float4*)enc, (ushort4*)encb);

  // ---- attn1: fused QKV ----
  ln_mod_k<<<dim3(STOK), 256, 0, stream>>>(hid, modsb, 0, 1, nhb);
  cvtT3(a1_qw, a1_kw, a1_vw, Wbig, DIMC, DIMC, 0, DIMC, 2304, DIMC, WSLOT, 3);
  gemm_bt<6><<<gemm_grid(STOK, 6912), 256, 0, stream>>>(nhb, Wbig, bias5, nullptr, P1,
                                                        nullptr, nullptr, STOK, 6912, DIMC, SD, 6, DIMC, 0);
  rmsqk_k<<<dim3(STOK, 2), 256, 0, stream>>>(P1, P2, a1_nq, a1_nk, fcos, fsin, P4, P5);
  colsum_k<<<dim3(9, 28), 256, 0, stream>>>(P2, kpart);
  ksumred_k<<<dim3(9), 256, 0, stream>>>(kpart, ksum);
  denom_k<<<dim3(STOK), 256, 0, stream>>>(P1, ksum, denom);
  // q (P1) and k (P2) are dead now -> spart may overwrite them
  scores_k<<<dim3(NH, 28), 256, 0, stream>>>(P3, P5, spart);
  scred_k<<<dim3((NH*HDIM*HDIM+255)/256), 256, 0, stream>>>(spart, scorb);
  linout_k<<<dim3(STOK/64, NH), 256, 0, stream>>>(P4, scorb, denom, P1);   // lob -> P1
  dim3 gMN = gemm_grid(STOK, 2304);
  // batch-convert the three DIM x DIM weights: slot0=a1_ow, slot1=a2_qw, slot2=a2_ow
  cvtT3(a1_ow, a2_qw, a2_ow, Wbig, DIMC, DIMC, 0, DIMC, 2304, DIMC, WSLOT, 3);
  // EPI3: x1b(bf16) = hid + g_msa*(lob@ow + ob)   -> P2
  gemm_bt<3><<<gMN, 256, 0, stream>>>(P1, Wbig, a1_ob, nullptr, P2, hid, modsb + 2*DIMC, STOK, DIMC, DIMC, DIMC, 6, DIMC, 0);

  // ---- cross attn ----
  gemm_bt<2><<<gMN, 256, 0, stream>>>(P2, Wbig + WSLOT, a2_qb, nullptr, P3, nullptr, nullptr, STOK, DIMC, DIMC, DIMC, 6, DIMC, 0);
  cvtT3(a2_kw, a2_vw, a2_vw, Wbig, DIMC, DIMC, 0, DIMC, 2304, DIMC, WSLOT, 2);   // slots 0,1 (dead)
  gemm_bt<6><<<gemm_grid(ENCT, 4608), 256, 0, stream>>>(encb, Wbig, bias5 + 3*2304, nullptr, k2b,
                                                        nullptr, nullptr, ENCT, 4608, DIMC, ENCT*DIMC, 6, DIMC, 0);
  rmsnn_k<<<dim3(STOK + ENCT), 256, 0, stream>>>(P3, a2_nq, k2b, a2_nk);
  xattn_k<<<dim3(STOK/64, NH), 256, 0, stream>>>(P3, k2b, v2b, P4);   // crb -> P4
  // EPI8: x2b(bf16) = x1b + crb@ow2 + ob2
  gemm_bt<8><<<gMN, 256, 0, stream>>>(P4, Wbig + 2*WSLOT, a2_ob, nullptr, x2b,
                                      (const float*)(const void*)P2, nullptr, STOK, DIMC, DIMC, DIMC, 6, DIMC, 0);

  // ---- FF ----
  ln_mod_bf_k<<<dim3(STOK), 256, 0, stream>>>(x2b, modsb, 3, 4, nh2b);
  for (int q = 0; q < 2; ++q){                 // ff_inv in 2 column slices of 6720
    int c0 = q*6720;
    cvtT3(ff_inv_w, ff_inv_w, ff_inv_w, Wbig, DIMC, HID2, c0, 6720, 6912, DIMC, 0, 1);
    gemm_bt<1><<<gemm_grid(STOK, 6912), 256, 0, stream>>>(nh2b, Wbig, ff_inv_b + c0, nullptr, y1b + c0,
                                                          nullptr, nullptr, STOK, 6720, DIMC, HID2, 6, DIMC, 0);
  }
  dw_k<<<dim3(224, 14), 256, 0, stream>>>(y1b, ff_dw, ff_db, y2b);
  // y1b dead -> y3pad margins may be zeroed now
  zpad_k<<<dim3(490), 256, 0, stream>>>(y3pad, y3pad + (size_t)(448 + STOK)*DIMC);
  cvtT3(ff_pw, ff_pw, ff_pw, Wbig, HID1, DIMC, 0, DIMC, 2304, HID1, 0, 1);   // point conv weights
  gemm_bt<2><<<gMN, 256, 0, stream>>>(y2b, Wbig, nullptr, nullptr, y3,
                                      nullptr, nullptr, STOK, DIMC, HID1, DIMC, 2, HID1, 0);
  // temporal conv + final residual fused: out = x2 + g_mlp*(y3 + tc)  (one K=6720 GEMM)
  cvtT3(ff_tw, ff_tw + (size_t)DD, ff_tw + (size_t)2*DD, Wbig,
        DIMC, DIMC, 0, DIMC, 2304, 6720, 2240LL, 3);   // Bt [2304][6720], col-sec = W_sec
  gemm_bt<7><<<gMN, 256, 0, stream>>>(y3pad, Wbig, nullptr, out, y3,
                                      (const float*)(const void*)x2b, modsb + 5*DIMC,
                                      STOK, DIMC, 6720, DIMC, 2, DIMC, 1);
}

// Round 14
// 1305.041 us; speedup vs baseline: 1.3069x; 1.0204x over previous
//
#include <hip/hip_runtime.h>

#define DIMC 2240
#define STOK 3584
#define ENCT 300
#define NH   20
#define HDIM 112
#define HID1 6720
#define HID2 13440
#define DD   (2240*2240)
#define SD   (3584*2240)

typedef short bf16x8 __attribute__((ext_vector_type(8)));   // guide-verified operand type
typedef float f32x4  __attribute__((ext_vector_type(4)));

__device__ __forceinline__ unsigned short f2bf(float f){
  unsigned int u = __float_as_uint(f);
  u += 0x7fffu + ((u >> 16) & 1u);          // RNE
  return (unsigned short)(u >> 16);
}
__device__ __forceinline__ float bf2f(unsigned short h){
  return __uint_as_float(((unsigned int)h) << 16);
}
__device__ __forceinline__ void gl_lds16(const unsigned short* g, unsigned short* l){
  __builtin_amdgcn_global_load_lds(
      (const __attribute__((address_space(1))) unsigned int*)(const void*)g,
      (__attribute__((address_space(3))) unsigned int*)(void*)l, 16, 0, 0);
}

// -------- prep: mods = sst + ts; pack 5 biases into [5][2304]; convert enc to bf16 ----
__global__ void prep_k(const float* __restrict__ sst, const float* __restrict__ ts,
    float* __restrict__ mods,
    const float* __restrict__ b0, const float* __restrict__ b1, const float* __restrict__ b2,
    const float* __restrict__ b3, const float* __restrict__ b4, float* __restrict__ bias5,
    const float4* __restrict__ encs, ushort4* __restrict__ encd){
  int i = blockIdx.x*256 + threadIdx.x;
  if (i < 168000){                       // ENCT*DIMC/4
    float4 v = encs[i];
    ushort4 o; o.x = f2bf(v.x); o.y = f2bf(v.y); o.z = f2bf(v.z); o.w = f2bf(v.w);
    encd[i] = o;
  }
  if (i < 6*DIMC) mods[i] = sst[i] + ts[i];
  if (i < 5*2304){
    int slot = i / 2304, d = i - slot*2304;
    const float* s = (slot==0)?b0 : (slot==1)?b1 : (slot==2)?b2 : (slot==3)?b3 : b4;
    bias5[i] = (d < 2240) ? s[d] : 0.f;
  }
}

// -- fp32 (rows x cols slice) -> bf16 TRANSPOSED [ncPad][ldd], zero-padded, multi-src --
__global__ __launch_bounds__(256) void cvtT3_k(const float* __restrict__ s0,
    const float* __restrict__ s1, const float* __restrict__ s2,
    unsigned short* __restrict__ dst, int rows, int ldsrc, int c0, int nc,
    int ldd, long long dzoff){
  const float* src = (blockIdx.z == 0) ? s0 : ((blockIdx.z == 1) ? s1 : s2);
  unsigned short* d = dst + (size_t)blockIdx.z * (size_t)dzoff;
  __shared__ float tile[32][33];
  const int tx = threadIdx.x & 31, ty = threadIdx.x >> 5;   // ty 0..7
  const int colBase = blockIdx.x*32;
  #pragma unroll
  for (int i = 0; i < 4; ++i){
    int rr = blockIdx.y*32 + ty + i*8;
    int cc = colBase + tx;
    tile[ty + i*8][tx] = (cc < nc) ? src[(size_t)rr*ldsrc + c0 + cc] : 0.f;
  }
  __syncthreads();
  #pragma unroll
  for (int i = 0; i < 4; ++i){
    int n = colBase + ty + i*8;          // < ncPad by grid
    int k = blockIdx.y*32 + tx;
    d[(size_t)n*ldd + k] = f2bf(tile[tx][ty + i*8]);
  }
}

// ---------------- zero the two 448-row margins of y3pad ----------------
__global__ void zpad_k(unsigned short* __restrict__ m0, unsigned short* __restrict__ m1){
  int i = blockIdx.x*256 + threadIdx.x;       // uint4 index; 448*2240/8 = 125440
  if (i < 125440){
    reinterpret_cast<uint4*>(m0)[i] = make_uint4(0u,0u,0u,0u);
    reinterpret_cast<uint4*>(m1)[i] = make_uint4(0u,0u,0u,0u);
  }
}

// ---------------- LayerNorm * (1+sc) + sh -> bf16 (fp32 input) ----------------
__global__ __launch_bounds__(256) void ln_mod_k(const float* __restrict__ x,
    const float* __restrict__ mods, int shj, int scj, unsigned short* __restrict__ out)
{
  const int s = blockIdx.x;
  const float4* row4 = reinterpret_cast<const float4*>(x + (size_t)s*DIMC);
  const float4* sh4 = reinterpret_cast<const float4*>(mods + shj*DIMC);
  const float4* sc4 = reinterpret_cast<const float4*>(mods + scj*DIMC);
  float sum = 0.f, sq = 0.f;
  for (int o = threadIdx.x; o < 560; o += 256){
    float4 v = row4[o];
    sum += v.x + v.y + v.z + v.w;
    sq  += v.x*v.x + v.y*v.y + v.z*v.z + v.w*v.w;
  }
  #pragma unroll
  for (int o = 32; o; o >>= 1){ sum += __shfl_down(sum, o); sq += __shfl_down(sq, o); }
  __shared__ float sA[4], sB[4];
  int w = threadIdx.x >> 6, l = threadIdx.x & 63;
  if (!l){ sA[w] = sum; sB[w] = sq; }
  __syncthreads();
  sum = sA[0]+sA[1]+sA[2]+sA[3];
  sq  = sB[0]+sB[1]+sB[2]+sB[3];
  float mean = sum * (1.f/DIMC);
  float rs = rsqrtf(sq*(1.f/DIMC) - mean*mean + 1e-6f);
  unsigned short* orow = out + (size_t)s*DIMC;
  for (int o = threadIdx.x; o < 560; o += 256){
    float4 v = row4[o], sc = sc4[o], sh = sh4[o];
    ushort4 r;
    r.x = f2bf((v.x-mean)*rs*(1.f + sc.x) + sh.x);
    r.y = f2bf((v.y-mean)*rs*(1.f + sc.y) + sh.y);
    r.z = f2bf((v.z-mean)*rs*(1.f + sc.z) + sh.z);
    r.w = f2bf((v.w-mean)*rs*(1.f + sc.w) + sh.w);
    *reinterpret_cast<ushort4*>(orow + o*4) = r;
  }
}

// ---------------- LayerNorm * (1+sc) + sh -> bf16 (bf16 input) ----------------
__global__ __launch_bounds__(256) void ln_mod_bf_k(const unsigned short* __restrict__ x,
    const float* __restrict__ mods, int shj, int scj, unsigned short* __restrict__ out)
{
  const int s = blockIdx.x;
  const unsigned short* row = x + (size_t)s*DIMC;
  float sum = 0.f, sq = 0.f;
  for (int o = threadIdx.x; o < 280; o += 256){
    uint4 v = *reinterpret_cast<const uint4*>(row + o*8);
    unsigned int uu[4] = {v.x, v.y, v.z, v.w};
    #pragma unroll
    for (int j = 0; j < 4; ++j){
      float lo = bf2f((unsigned short)(uu[j] & 0xffffu));
      float hi = bf2f((unsigned short)(uu[j] >> 16));
      sum += lo + hi; sq += lo*lo + hi*hi;
    }
  }
  #pragma unroll
  for (int o = 32; o; o >>= 1){ sum += __shfl_down(sum, o); sq += __shfl_down(sq, o); }
  __shared__ float sA[4], sB[4];
  int w = threadIdx.x >> 6, l = threadIdx.x & 63;
  if (!l){ sA[w] = sum; sB[w] = sq; }
  __syncthreads();
  sum = sA[0]+sA[1]+sA[2]+sA[3];
  sq  = sB[0]+sB[1]+sB[2]+sB[3];
  float mean = sum * (1.f/DIMC);
  float rs = rsqrtf(sq*(1.f/DIMC) - mean*mean + 1e-6f);
  unsigned short* orow = out + (size_t)s*DIMC;
  const float* sh = mods + shj*DIMC;
  const float* sc = mods + scj*DIMC;
  for (int o = threadIdx.x; o < 280; o += 256){
    uint4 v = *reinterpret_cast<const uint4*>(row + o*8);
    unsigned int uu[4] = {v.x, v.y, v.z, v.w};
    uint4 ov;
    unsigned int* po = &ov.x;
    #pragma unroll
    for (int j = 0; j < 4; ++j){
      int d0 = o*8 + 2*j;
      float lo = (bf2f((unsigned short)(uu[j] & 0xffffu)) - mean)*rs*(1.f + sc[d0])   + sh[d0];
      float hi = (bf2f((unsigned short)(uu[j] >> 16))     - mean)*rs*(1.f + sc[d0+1]) + sh[d0+1];
      po[j] = (unsigned int)f2bf(lo) | ((unsigned int)f2bf(hi) << 16);
    }
    *reinterpret_cast<uint4*>(orow + o*8) = ov;
  }
}

// -------- merged q/k RMS + ReLU + RoPE (grid.y = 0:q, 1:k), uint4-vectorized ---------
__global__ __launch_bounds__(256) void rmsqk_k(unsigned short* __restrict__ qx,
    unsigned short* __restrict__ kx, const float* __restrict__ nq, const float* __restrict__ nk,
    const float* __restrict__ cosb, const float* __restrict__ sinb,
    unsigned short* __restrict__ qr, unsigned short* __restrict__ kr)
{
  const int s = blockIdx.x;
  unsigned short* row = (blockIdx.y ? kx : qx) + (size_t)s*DIMC;
  const float* nw = blockIdx.y ? nk : nq;
  unsigned short* xr = (blockIdx.y ? kr : qr) + (size_t)s*DIMC;
  float sq = 0.f;
  for (int o = threadIdx.x; o < 280; o += 256){
    uint4 v = *reinterpret_cast<const uint4*>(row + o*8);
    unsigned int uu[4] = {v.x, v.y, v.z, v.w};
    #pragma unroll
    for (int j = 0; j < 4; ++j){
      float lo = bf2f((unsigned short)(uu[j] & 0xffffu));
      float hi = bf2f((unsigned short)(uu[j] >> 16));
      sq += lo*lo + hi*hi;
    }
  }
  #pragma unroll
  for (int o = 32; o; o >>= 1) sq += __shfl_down(sq, o);
  __shared__ float sB[4];
  int w = threadIdx.x >> 6, l = threadIdx.x & 63;
  if (!l) sB[w] = sq;
  __syncthreads();
  sq = sB[0]+sB[1]+sB[2]+sB[3];
  float rs = rsqrtf(sq*(1.f/DIMC) + 1e-5f);
  for (int o = threadIdx.x; o < 280; o += 256){
    uint4 v = *reinterpret_cast<const uint4*>(row + o*8);
    unsigned int uu[4] = {v.x, v.y, v.z, v.w};
    float4 n0 = *reinterpret_cast<const float4*>(nw + o*8);
    float4 n1 = *reinterpret_cast<const float4*>(nw + o*8 + 4);
    float nn[8] = {n0.x,n0.y,n0.z,n0.w,n1.x,n1.y,n1.z,n1.w};
    float vals[8];
    #pragma unroll
    for (int j = 0; j < 4; ++j){
      vals[2*j]   = fmaxf(bf2f((unsigned short)(uu[j] & 0xffffu))*rs*nn[2*j],   0.f);
      vals[2*j+1] = fmaxf(bf2f((unsigned short)(uu[j] >> 16))*rs*nn[2*j+1], 0.f);
    }
    uint4 o1;
    unsigned int* po = &o1.x;
    #pragma unroll
    for (int j = 0; j < 4; ++j)
      po[j] = (unsigned int)f2bf(vals[2*j]) | ((unsigned int)f2bf(vals[2*j+1]) << 16);
    *reinterpret_cast<uint4*>(row + o*8) = o1;
    int jb = (o*8) % HDIM;                      // octet stays within a head (112%8==0)
    uint4 o2;
    unsigned int* pr = &o2.x;
    #pragma unroll
    for (int p = 0; p < 4; ++p){
      float c  = cosb[(size_t)s*HDIM + jb + 2*p];
      float sn = sinb[(size_t)s*HDIM + jb + 2*p + 1];
      float r0 = vals[2*p]*c - vals[2*p+1]*sn;
      float r1 = vals[2*p]*sn + vals[2*p+1]*c;
      pr[p] = (unsigned int)f2bf(r0) | ((unsigned int)f2bf(r1) << 16);
    }
    *reinterpret_cast<uint4*>(xr + o*8) = o2;
  }
}

// -------- merged plain RMS: rows [0,STOK) -> xa/na, rows [STOK,STOK+ENCT) -> xb/nb ----
__global__ __launch_bounds__(256) void rmsnn_k(unsigned short* __restrict__ xa,
    const float* __restrict__ na, unsigned short* __restrict__ xb, const float* __restrict__ nb)
{
  int s = blockIdx.x;
  unsigned short* row; const float* nw;
  if (s < STOK){ row = xa + (size_t)s*DIMC; nw = na; }
  else         { row = xb + (size_t)(s - STOK)*DIMC; nw = nb; }
  float sq = 0.f;
  for (int o = threadIdx.x; o < 280; o += 256){
    uint4 v = *reinterpret_cast<const uint4*>(row + o*8);
    unsigned int uu[4] = {v.x, v.y, v.z, v.w};
    #pragma unroll
    for (int j = 0; j < 4; ++j){
      float lo = bf2f((unsigned short)(uu[j] & 0xffffu));
      float hi = bf2f((unsigned short)(uu[j] >> 16));
      sq += lo*lo + hi*hi;
    }
  }
  #pragma unroll
  for (int o = 32; o; o >>= 1) sq += __shfl_down(sq, o);
  __shared__ float sB[4];
  int w = threadIdx.x >> 6, l = threadIdx.x & 63;
  if (!l) sB[w] = sq;
  __syncthreads();
  sq = sB[0]+sB[1]+sB[2]+sB[3];
  float rs = rsqrtf(sq*(1.f/DIMC) + 1e-5f);
  for (int o = threadIdx.x; o < 280; o += 256){
    uint4 v = *reinterpret_cast<const uint4*>(row + o*8);
    unsigned int uu[4] = {v.x, v.y, v.z, v.w};
    float4 n0 = *reinterpret_cast<const float4*>(nw + o*8);
    float4 n1 = *reinterpret_cast<const float4*>(nw + o*8 + 4);
    float nn[8] = {n0.x,n0.y,n0.z,n0.w,n1.x,n1.y,n1.z,n1.w};
    uint4 o1;
    unsigned int* po = &o1.x;
    #pragma unroll
    for (int j = 0; j < 4; ++j){
      float lo = bf2f((unsigned short)(uu[j] & 0xffffu))*rs*nn[2*j];
      float hi = bf2f((unsigned short)(uu[j] >> 16))*rs*nn[2*j+1];
      po[j] = (unsigned int)f2bf(lo) | ((unsigned int)f2bf(hi) << 16);
    }
    *reinterpret_cast<uint4*>(row + o*8) = o1;
  }
}

// ------- bf16 MFMA GEMM: C = A(MxK) @ Bt^T, Bt is [Npad][K] (N-major), BK=64 ---------
// (round-7 proven structure) Both-sides swizzle; K % 64 == 0; PW | gridDim.x.
// __launch_bounds__(256,4): cap total regs at 128 -> 4 blocks/CU (occupancy push).
// lda: A row stride. tcsh=1: temporal-conv mode — K-section sec (2240 wide) reads A at
// row + sec*448; A must point at the PADDED base (row 0 = center_row - 448).
// EPI: 0 Cf=acc+bias | 1 Cb=bf16(silu(acc+bias)) | 2 Cb=bf16(acc+bias)
//      3 Cb=bf16(res+gate*(acc+bias))           [res fp32]
//      6 slot-split: slot=col/2304, d=col%2304; if d<2240: Cb[slot*ldc + row*2240 + d]
//      7 Cf = bf2f(resb[idx]) + gate[col]*(bf2f(Cb[idx]) + acc)   [resb = (ushort*)res]
//      8 Cb = bf16(bf2f(resb[idx]) + acc + bias)                   [resb = (ushort*)res]
template<int EPI>
__global__ __launch_bounds__(256, 4) void gemm_bt(
  const unsigned short* __restrict__ A, const unsigned short* __restrict__ Bt,
  const float* __restrict__ bias, float* __restrict__ Cf, unsigned short* __restrict__ Cb,
  const float* __restrict__ res, const float* __restrict__ gate,
  int M, int N, int K, int ldc, int PW, int lda, int tcsh)
{
  __shared__ __align__(16) unsigned short Al[128*64];
  __shared__ __align__(16) unsigned short Bl[128*64];
  const int gx = gridDim.x, gy = gridDim.y;
  const int nwg = gx*gy;
  const int orig = blockIdx.y*gx + blockIdx.x;
  // bijective XCD-aware remap (m204)
  const int qq = nwg >> 3, rr = nwg & 7;
  const int xcd = orig & 7, li = orig >> 3;
  const int wg = (xcd < rr ? xcd*(qq+1) : rr*(qq+1) + (xcd-rr)*qq) + li;
  // N-panel rasterization: panel of PW n-tiles covers all gy m-rows before advancing
  const int ppw = gy*PW;
  const int panel = wg / ppw, rm = wg - panel*ppw;
  const int mrow = rm / PW;
  const int m0 = mrow*128;
  const int n0 = (panel*PW + (rm - mrow*PW))*128;

  const int t = threadIdx.x, lane = t & 63, w = t >> 6;
  const int wr = w >> 1, wc = w & 1;
  const int l16 = lane & 15, lk = lane >> 4;

  // staging geometry: per wave 4 A-chunks + 4 B-chunks (each 1KB = 8 rows x 128B),
  // pre-swizzled source chunk; addresses recomputed per issue (register diet).
  const int lr8 = lane >> 3;           // row within 8-row block (== row&7)
  const int sc  = (lane & 7) ^ lr8;    // pre-swizzled source chunk
  const int arb = m0 + w*32 + lr8;
  const int brb = n0 + w*32 + lr8;
  unsigned short* Ad = Al + w*2048;
  unsigned short* Bd = Bl + w*2048;

  f32x4 acc[4][4] = {};
  for (int k0 = 0; k0 < K; k0 += 64){
    size_t aoff;
    if (tcsh){
      int sec = (k0 >= 4480) ? 2 : ((k0 >= 2240) ? 1 : 0);
      aoff = (size_t)(sec*448)*lda + (unsigned)(k0 - sec*2240);
    } else {
      aoff = (size_t)k0;
    }
    __syncthreads();
    #pragma unroll
    for (int i = 0; i < 4; ++i){
      gl_lds16(A  + (size_t)min(arb + i*8, M-1)*lda + sc*8 + aoff, Ad + i*512);
      gl_lds16(Bt + (size_t)(brb + i*8)*K + sc*8 + k0,             Bd + i*512);
    }
    __syncthreads();
    #pragma unroll
    for (int kk = 0; kk < 2; ++kk){
      bf16x8 af[4], bfr[4];
      const int chb = (kk*4 + lk) ^ (l16 & 7);   // swizzled read chunk
      #pragma unroll
      for (int m = 0; m < 4; ++m)
        af[m] = *reinterpret_cast<const bf16x8*>(Al + (wr*64 + m*16 + l16)*64 + chb*8);
      #pragma unroll
      for (int n = 0; n < 4; ++n)
        bfr[n] = *reinterpret_cast<const bf16x8*>(Bl + (wc*64 + n*16 + l16)*64 + chb*8);
      #pragma unroll
      for (int m = 0; m < 4; ++m)
        #pragma unroll
        for (int n = 0; n < 4; ++n)
          acc[m][n] = __builtin_amdgcn_mfma_f32_16x16x32_bf16(af[m], bfr[n], acc[m][n], 0, 0, 0);
    }
  }

  const int rb = m0 + wr*64 + lk*4;   // C/D: col = lane&15, row = (lane>>4)*4 + reg
  const int cb = n0 + wc*64 + l16;
  #pragma unroll
  for (int m = 0; m < 4; ++m){
    #pragma unroll
    for (int r = 0; r < 4; ++r){
      int row = rb + m*16 + r;
      if (row >= M) continue;
      #pragma unroll
      for (int n = 0; n < 4; ++n){
        int col = cb + n*16;
        if (col >= N) continue;
        float v = acc[m][n][r];
        float bv = bias ? bias[col] : 0.f;
        if constexpr (EPI == 6){
          int slot = col / 2304;
          int d = col - slot*2304;
          if (d < 2240)
            Cb[(size_t)slot*ldc + (size_t)row*2240 + d] = f2bf(v + bv);
        } else {
          size_t idx = (size_t)row*ldc + col;
          if constexpr (EPI == 0){ Cf[idx] = v + bv; }
          else if constexpr (EPI == 1){ float u = v + bv; Cb[idx] = f2bf(u / (1.f + __expf(-u))); }
          else if constexpr (EPI == 2){ Cb[idx] = f2bf(v + bv); }
          else if constexpr (EPI == 3){ float u = res[idx] + gate[col]*(v + bv); Cb[idx] = f2bf(u); }
          else if constexpr (EPI == 7){
            const unsigned short* resb = (const unsigned short*)(const void*)res;
            Cf[idx] = bf2f(resb[idx]) + gate[col]*(bf2f(Cb[idx]) + v);
          }
          else if constexpr (EPI == 8){
            const unsigned short* resb = (const unsigned short*)(const void*)res;
            Cb[idx] = f2bf(bf2f(resb[idx]) + v + bv);
          }
          else { Cf[idx] += v; }
        }
      }
    }
  }
}

// ---------------- linear attention helpers ----------------
__global__ void colsum_k(const unsigned short* __restrict__ k, float* __restrict__ kpart){
  int d = blockIdx.x*256 + threadIdx.x;
  if (d >= DIMC) return;
  int ch = blockIdx.y, s0 = ch*128;
  float acc = 0.f;
  for (int s = s0; s < s0+128; ++s) acc += bf2f(k[(size_t)s*DIMC + d]);
  kpart[(size_t)ch*DIMC + d] = acc;
}
__global__ void ksumred_k(const float* __restrict__ kpart, float* __restrict__ ksum){
  int d = blockIdx.x*256 + threadIdx.x;
  if (d >= DIMC) return;
  float a = 0.f;
  for (int c = 0; c < 28; ++c) a += kpart[(size_t)c*DIMC + d];
  ksum[d] = a;
}
__global__ __launch_bounds__(256) void denom_k(const unsigned short* __restrict__ q,
    const float* __restrict__ ksum, float* __restrict__ denom)
{
  int s = blockIdx.x; int w = threadIdx.x >> 6, l = threadIdx.x & 63;
  for (int h = w; h < NH; h += 4){
    const unsigned short* qb = q + (size_t)s*DIMC + h*HDIM;
    const float* kb = ksum + h*HDIM;
    float v = bf2f(qb[l])*kb[l];
    if (l < 48) v += bf2f(qb[64+l])*kb[64+l];
    #pragma unroll
    for (int o = 32; o; o >>= 1) v += __shfl_down(v, o);
    if (!l) denom[s*NH + h] = v + 1e-15f;
  }
}

// -------- MFMA scores: part[ch][h][e][d] = sum_{s in 128-chunk} V[s,h,e]*Kr[s,h,d] -----
#define SLSC 136
__device__ __forceinline__ int sc_idx(int e, int s){
  return e*SLSC + (s ^ (((e >> 3) & 7) << 3));
}
__global__ __launch_bounds__(256) void scores_k(const unsigned short* __restrict__ v,
    const unsigned short* __restrict__ kr, float* __restrict__ part)
{
  const int h = blockIdx.x, ch = blockIdx.y;
  __shared__ __align__(16) unsigned short Vt[112*SLSC];
  __shared__ __align__(16) unsigned short Kt[112*SLSC];
  const int t = threadIdx.x, lane = t & 63, w = t >> 6;
  const int l16 = lane & 15, lk = lane >> 4;
  const int sbase = ch*128;

  for (int p = t; p < 1792; p += 256){       // 128 tokens x 14 dim-octets
    int s = p / 14, oc = (p % 14) * 8;
    bf16x8 vv = *reinterpret_cast<const bf16x8*>(v  + (size_t)(sbase+s)*DIMC + h*HDIM + oc);
    bf16x8 kk = *reinterpret_cast<const bf16x8*>(kr + (size_t)(sbase+s)*DIMC + h*HDIM + oc);
    #pragma unroll
    for (int j = 0; j < 8; ++j){
      Vt[sc_idx(oc+j, s)] = (unsigned short)vv[j];
      Kt[sc_idx(oc+j, s)] = (unsigned short)kk[j];
    }
  }
  __syncthreads();

  f32x4 acc[2][7] = {};                      // wave w owns m-tiles {w, w+4}
  #pragma unroll
  for (int ks = 0; ks < 4; ++ks){
    const int sf = ks*32 + lk*8;
    bf16x8 bfrg[7];
    #pragma unroll
    for (int nt = 0; nt < 7; ++nt){
      int d = nt*16 + l16;
      bfrg[nt] = *reinterpret_cast<const bf16x8*>(&Kt[d*SLSC + (sf ^ (((d >> 3) & 7) << 3))]);
    }
    #pragma unroll
    for (int mi = 0; mi < 2; ++mi){
      int mt = w + mi*4;
      if (mt < 7){
        int e = mt*16 + l16;
        bf16x8 afrg = *reinterpret_cast<const bf16x8*>(&Vt[e*SLSC + (sf ^ (((e >> 3) & 7) << 3))]);
        #pragma unroll
        for (int nt = 0; nt < 7; ++nt)
          acc[mi][nt] = __builtin_amdgcn_mfma_f32_16x16x32_bf16(afrg, bfrg[nt], acc[mi][nt], 0, 0, 0);
      }
    }
  }

  float* pout = part + ((size_t)ch*NH + h)*12544;
  #pragma unroll
  for (int mi = 0; mi < 2; ++mi){
    int mt = w + mi*4;
    if (mt >= 7) continue;
    #pragma unroll
    for (int nt = 0; nt < 7; ++nt)
      #pragma unroll
      for (int r = 0; r < 4; ++r)
        pout[(size_t)(mt*16 + lk*4 + r)*HDIM + nt*16 + l16] = acc[mi][nt][r];
  }
}
__global__ void scred_k(const float* __restrict__ part, unsigned short* __restrict__ sc){
  int i = blockIdx.x*256 + threadIdx.x;
  if (i >= NH*HDIM*HDIM) return;
  float a = 0.f;
  #pragma unroll
  for (int c = 0; c < 28; ++c) a += part[(size_t)c*(NH*HDIM*HDIM) + i];
  sc[i] = f2bf(a);
}

// -------- MFMA linout: out[s,h*112+e] = (sum_d scores[h,e,d]*qr[s,h,d]) / denom[s,h] ---
__global__ __launch_bounds__(256) void linout_k(const unsigned short* __restrict__ qr,
    const unsigned short* __restrict__ scores, const float* __restrict__ denom,
    unsigned short* __restrict__ out)
{
  const int h = blockIdx.y;
  const int t = threadIdx.x, lane = t & 63, w = t >> 6;
  const int l16 = lane & 15, lk = lane >> 4;
  const int s0 = blockIdx.x*64 + w*16;
  const unsigned short* qrow = qr + (size_t)(s0 + l16)*DIMC + h*HDIM;
  const unsigned short* sb = scores + (size_t)h*12544;
  f32x4 acc[7] = {};
  #pragma unroll
  for (int ks = 0; ks < 4; ++ks){
    int d0 = ks*32 + lk*8;
    bf16x8 a = {};
    if (d0 < HDIM) a = *reinterpret_cast<const bf16x8*>(qrow + d0);
    #pragma unroll
    for (int nt = 0; nt < 7; ++nt){
      bf16x8 b = {};
      if (d0 < HDIM) b = *reinterpret_cast<const bf16x8*>(sb + (size_t)(nt*16 + l16)*HDIM + d0);
      acc[nt] = __builtin_amdgcn_mfma_f32_16x16x32_bf16(a, b, acc[nt], 0, 0, 0);
    }
  }
  #pragma unroll
  for (int r = 0; r < 4; ++r){
    int s = s0 + lk*4 + r;
    float dn = 1.f / denom[(size_t)s*NH + h];
    #pragma unroll
    for (int nt = 0; nt < 7; ++nt)
      out[(size_t)s*DIMC + h*HDIM + nt*16 + l16] = f2bf(acc[nt][r]*dn);
  }
}

// ---------------- fused cross-attention, MFMA (300 keys, head dim 112 padded to 128) ----
__global__ __launch_bounds__(256) void xattn_k(
    const unsigned short* __restrict__ q,   // S x DIM bf16 (rms-normed)
    const unsigned short* __restrict__ k2,  // ENCT x DIM bf16 (rms-normed)
    const unsigned short* __restrict__ v2,  // ENCT x DIM bf16
    unsigned short* __restrict__ outb)      // S x DIM bf16
{
  const int h = blockIdx.y;
  const int w = threadIdx.x >> 6, lane = threadIdx.x & 63;
  const int l16 = lane & 15, lk = lane >> 4;
  const float scale = 0.09449111825230679f;   // 1/sqrt(112)

  __shared__ __align__(16) unsigned short Kl[64][136];
  __shared__ __align__(16) unsigned short Vl[112][72];
  __shared__ __align__(16) unsigned short Pl[4][16][72];

  bf16x8 qf[4];
  const unsigned short* qbase = q + (size_t)(blockIdx.x*64 + w*16 + l16)*DIMC + h*HDIM;
  #pragma unroll
  for (int c = 0; c < 4; ++c){
    int d0 = c*32 + lk*8;
    bf16x8 z = {};
    qf[c] = (d0 < HDIM) ? *reinterpret_cast<const bf16x8*>(qbase + d0) : z;
  }

  f32x4 lg[5][4] = {};
  #pragma unroll
  for (int c = 0; c < 5; ++c){
    const int kbase = c*64;
    const int nk = (c == 4) ? (ENCT - 256) : 64;
    __syncthreads();
    #pragma unroll
    for (int it = 0; it < 4; ++it){
      int li = it*256 + threadIdx.x;
      int key = li >> 4, d0 = (li & 15) << 3;
      uint4 val = make_uint4(0u,0u,0u,0u);
      if (key < nk && d0 < HDIM)
        val = *reinterpret_cast<const uint4*>(k2 + (size_t)(kbase+key)*DIMC + h*HDIM + d0);
      *reinterpret_cast<uint4*>(&Kl[key][d0]) = val;
    }
    __syncthreads();
    #pragma unroll
    for (int nt = 0; nt < 4; ++nt){
      #pragma unroll
      for (int ks = 0; ks < 4; ++ks){
        bf16x8 kf = *reinterpret_cast<const bf16x8*>(&Kl[nt*16 + l16][ks*32 + lk*8]);
        lg[c][nt] = __builtin_amdgcn_mfma_f32_16x16x32_bf16(qf[ks], kf, lg[c][nt], 0, 0, 0);
      }
    }
  }

  float mx[4] = {-3e38f, -3e38f, -3e38f, -3e38f};
  #pragma unroll
  for (int c = 0; c < 5; ++c)
    #pragma unroll
    for (int nt = 0; nt < 4; ++nt){
      bool valid = (c*64 + nt*16 + l16) < ENCT;
      #pragma unroll
      for (int r = 0; r < 4; ++r){
        float v = valid ? lg[c][nt][r]*scale : -3e38f;
        lg[c][nt][r] = v;
        mx[r] = fmaxf(mx[r], v);
      }
    }
  #pragma unroll
  for (int o = 1; o < 16; o <<= 1)
    #pragma unroll
    for (int r = 0; r < 4; ++r) mx[r] = fmaxf(mx[r], __shfl_xor(mx[r], o));
  float sm[4] = {0.f, 0.f, 0.f, 0.f};
  #pragma unroll
  for (int c = 0; c < 5; ++c)
    #pragma unroll
    for (int nt = 0; nt < 4; ++nt)
      #pragma unroll
      for (int r = 0; r < 4; ++r){
        float e = __expf(lg[c][nt][r] - mx[r]);
        lg[c][nt][r] = e;
        sm[r] += e;
      }
  #pragma unroll
  for (int o = 1; o < 16; o <<= 1)
    #pragma unroll
    for (int r = 0; r < 4; ++r) sm[r] += __shfl_xor(sm[r], o);
  float inv[4];
  #pragma unroll
  for (int r = 0; r < 4; ++r) inv[r] = 1.f / sm[r];

  f32x4 oacc[7] = {};
  #pragma unroll
  for (int c = 0; c < 5; ++c){
    const int kbase = c*64;
    const int nk = (c == 4) ? (ENCT - 256) : 64;
    __syncthreads();
    #pragma unroll
    for (int it = 0; it < 4; ++it){
      int li = it*256 + threadIdx.x;
      if (li < 896){
        int key = li/14, d0 = (li%14)*8;
        if (key < nk){
          bf16x8 vv = *reinterpret_cast<const bf16x8*>(v2 + (size_t)(kbase+key)*DIMC + h*HDIM + d0);
          #pragma unroll
          for (int j = 0; j < 8; ++j) Vl[d0+j][key] = (unsigned short)vv[j];
        } else {
          #pragma unroll
          for (int j = 0; j < 8; ++j) Vl[d0+j][key] = 0;
        }
      }
    }
    #pragma unroll
    for (int nt = 0; nt < 4; ++nt)
      #pragma unroll
      for (int r = 0; r < 4; ++r)
        Pl[w][lk*4 + r][nt*16 + l16] = f2bf(lg[c][nt][r]);
    __syncthreads();
    #pragma unroll
    for (int ks = 0; ks < 2; ++ks){
      bf16x8 pf = *reinterpret_cast<const bf16x8*>(&Pl[w][l16][ks*32 + lk*8]);
      #pragma unroll
      for (int n = 0; n < 7; ++n){
        bf16x8 vf = *reinterpret_cast<const bf16x8*>(&Vl[n*16 + l16][ks*32 + lk*8]);
        oacc[n] = __builtin_amdgcn_mfma_f32_16x16x32_bf16(pf, vf, oacc[n], 0, 0, 0);
      }
    }
  }

  const int orow = blockIdx.x*64 + w*16 + lk*4;
  #pragma unroll
  for (int n = 0; n < 7; ++n)
    #pragma unroll
    for (int r = 0; r < 4; ++r)
      outb[(size_t)(orow + r)*DIMC + h*HDIM + n*16 + l16] = f2bf(oacc[n][r]*inv[r]);
}

// ------- depthwise 3x3 + bias + GLU(silu): 2 ch x 4 rows x 4 cols per thread ----------
// grid.x = f(8) x ytile(4) x xquad(7) = 224, grid.y = 14
__global__ __launch_bounds__(256) void dw_k(const unsigned short* __restrict__ y1,
    const float* __restrict__ dw, const float* __restrict__ db, unsigned short* __restrict__ y2)
{
  int c = (blockIdx.y*256 + threadIdx.x)*2;
  if (c >= HID1) return;
  int bx = blockIdx.x;
  int xq = bx % 7;
  int yt = (bx / 7) & 3;
  int f  = bx / 28;
  int x0 = xq*4, y0 = yt*4;

  float wa[9][2], wg[9][2];
  #pragma unroll
  for (int tp = 0; tp < 9; ++tp){
    float2 va = *reinterpret_cast<const float2*>(dw + tp*HID2 + c);
    float2 vg = *reinterpret_cast<const float2*>(dw + tp*HID2 + c + HID1);
    wa[tp][0] = va.x; wa[tp][1] = va.y;
    wg[tp][0] = vg.x; wg[tp][1] = vg.y;
  }
  float2 ba = *reinterpret_cast<const float2*>(db + c);
  float2 bg = *reinterpret_cast<const float2*>(db + c + HID1);
  float a[4][4][2], g[4][4][2];
  #pragma unroll
  for (int r = 0; r < 4; ++r)
    #pragma unroll
    for (int cc = 0; cc < 4; ++cc){
      a[r][cc][0] = ba.x; a[r][cc][1] = ba.y;
      g[r][cc][0] = bg.x; g[r][cc][1] = bg.y;
    }

  #pragma unroll
  for (int dy6 = 0; dy6 < 6; ++dy6){
    int y = y0 - 1 + dy6;
    if ((unsigned)y >= 16u) continue;
    #pragma unroll
    for (int dxc = 0; dxc < 6; ++dxc){
      int x = x0 - 1 + dxc;
      if ((unsigned)x >= 28u) continue;
      size_t base = ((size_t)(f*16 + y)*28 + x)*HID2;
      unsigned int a01 = *reinterpret_cast<const unsigned int*>(y1 + base + c);
      unsigned int g01 = *reinterpret_cast<const unsigned int*>(y1 + base + c + HID1);
      float fa0 = bf2f((unsigned short)(a01 & 0xffffu));
      float fa1 = bf2f((unsigned short)(a01 >> 16));
      float fg0 = bf2f((unsigned short)(g01 & 0xffffu));
      float fg1 = bf2f((unsigned short)(g01 >> 16));
      #pragma unroll
      for (int r = 0; r < 4; ++r){
        int kdy = dy6 - r;                    // compile-time after unroll
        if (kdy < 0 || kdy > 2) continue;
        #pragma unroll
        for (int cc = 0; cc < 4; ++cc){
          int kdx = dxc - cc;
          if (kdx < 0 || kdx > 2) continue;
          int tp = kdy*3 + kdx;
          a[r][cc][0] += fa0*wa[tp][0]; a[r][cc][1] += fa1*wa[tp][1];
          g[r][cc][0] += fg0*wg[tp][0]; g[r][cc][1] += fg1*wg[tp][1];
        }
      }
    }
  }
  #pragma unroll
  for (int r = 0; r < 4; ++r)
    #pragma unroll
    for (int cc = 0; cc < 4; ++cc){
      float s0 = g[r][cc][0] / (1.f + __expf(-g[r][cc][0]));
      float s1 = g[r][cc][1] / (1.f + __expf(-g[r][cc][1]));
      int pos = (f*16 + y0 + r)*28 + x0 + cc;
      unsigned int o = (unsigned int)f2bf(a[r][cc][0]*s0) | ((unsigned int)f2bf(a[r][cc][1]*s1) << 16);
      *reinterpret_cast<unsigned int*>(y2 + (size_t)pos*HID1 + c) = o;
    }
}

extern "C" void kernel_launch(void* const* d_in, const int* in_sizes, int n_in,
                              void* d_out, int out_size, void* d_ws, size_t ws_size,
                              hipStream_t stream)
{
  const float* hid   = (const float*)d_in[0];
  const float* enc   = (const float*)d_in[1];
  const float* tstep = (const float*)d_in[2];
  const float* fcos  = (const float*)d_in[3];
  const float* fsin  = (const float*)d_in[4];
  const float* sst   = (const float*)d_in[5];
  const float *a1_qw=(const float*)d_in[6],  *a1_qb=(const float*)d_in[7];
  const float *a1_kw=(const float*)d_in[8],  *a1_kb=(const float*)d_in[9];
  const float *a1_vw=(const float*)d_in[10], *a1_vb=(const float*)d_in[11];
  const float *a1_nq=(const float*)d_in[12], *a1_nk=(const float*)d_in[13];
  const float *a1_ow=(const float*)d_in[14], *a1_ob=(const float*)d_in[15];
  const float *a2_qw=(const float*)d_in[16], *a2_qb=(const float*)d_in[17];
  const float *a2_kw=(const float*)d_in[18], *a2_kb=(const float*)d_in[19];
  const float *a2_vw=(const float*)d_in[20], *a2_vb=(const float*)d_in[21];
  const float *a2_nq=(const float*)d_in[22], *a2_nk=(const float*)d_in[23];
  const float *a2_ow=(const float*)d_in[24], *a2_ob=(const float*)d_in[25];
  const float *ff_inv_w=(const float*)d_in[26], *ff_inv_b=(const float*)d_in[27];
  const float *ff_dw=(const float*)d_in[28], *ff_db=(const float*)d_in[29];
  const float *ff_pw=(const float*)d_in[30];
  const float *ff_tw=(const float*)d_in[31];
  float* out = (float*)d_out;

  // ---- workspace plan (~213 MB total; all sizes 256-multiple) ----
  const size_t SLOTB = (size_t)SD*2;        // 16,056,320 B  (one bf16 S x DIM slot)
  char* ws = (char*)d_ws;
  size_t off = 0;
  auto alloc = [&](size_t n){ void* p = ws + off; off += (n + 255) & ~(size_t)255; return p; };

  char* P = (char*)alloc(6*SLOTB);          // 6 bf16 activation slots (96.3 MB)
  float* x1    = (float*)alloc((size_t)SD*4);     // region reused: y2b spans x1+nh2b
  unsigned short* nh2b = (unsigned short*)alloc(SLOTB); // MUST follow x1 (y2b spans both)
  float* x2    = (float*)alloc((size_t)SD*4);     // first half used as bf16 x2b
  unsigned short* k2b = (unsigned short*)alloc((size_t)ENCT*DIMC*2);  // k2b+v2b contiguous
  unsigned short* v2b = (unsigned short*)alloc((size_t)ENCT*DIMC*2);
  unsigned short* encb = (unsigned short*)alloc((size_t)ENCT*DIMC*2);
  float* modsb = (float*)alloc(6*DIMC*4);
  float* ksum  = (float*)alloc(DIMC*4);
  float* kpart = (float*)alloc((size_t)28*DIMC*4);
  float* denom = (float*)alloc((size_t)STOK*NH*4);
  unsigned short* scorb = (unsigned short*)alloc((size_t)NH*HDIM*HDIM*2);
  float* bias5 = (float*)alloc(5*2304*4);
  unsigned short* Wbig = (unsigned short*)alloc((size_t)6912*DIMC*2);  // 31 MB weight staging

  // P-slot aliases (lifetimes verified disjoint)
  unsigned short* P0 = (unsigned short*)P;                 // nhb | y1b[0:] | y3pad
  unsigned short* P1 = (unsigned short*)(P + 1*SLOTB);     // qb | spart | lob | y1b | y3pad tail
  unsigned short* P2 = (unsigned short*)(P + 2*SLOTB);     // kb | spart | x1b | y1b
  unsigned short* P3 = (unsigned short*)(P + 3*SLOTB);     // vb | q2b | y1b
  unsigned short* P4 = (unsigned short*)(P + 4*SLOTB);     // qrb | crb | y1b
  unsigned short* P5 = (unsigned short*)(P + 5*SLOTB);     // krb | y1b
  unsigned short* nhb = P0;
  unsigned short* y1b = P0;                                // 96.34 MB = slots 0..5 exactly
  unsigned short* y2b = (unsigned short*)x1;               // 48.17 MB = x1 + nh2b exactly
  unsigned short* y3pad = P0;                              // (448+3584+448) x 2240 = 20.1 MB
  unsigned short* y3  = y3pad + (size_t)448*DIMC;          // center: point-conv output
  unsigned short* x2b = (unsigned short*)x2;               // bf16 residual spine (16 MB)
  float* spart = (float*)P1;   // 28 x NH x 112 x 112 fp32 = 28.1 MB, q/k dead by then

  // multi-source transpose-convert: z in [0,nz) -> dst + z*dzoff, [ncPad x ldd]
  auto cvtT3 = [&](const float* s0, const float* s1, const float* s2, unsigned short* d,
                   int rows, int ldsrc, int c0, int nc, int ncPad, int ldd, long long dzoff, int nz){
    cvtT3_k<<<dim3(ncPad/32, rows/32, nz), 256, 0, stream>>>(s0, s1, s2, d, rows, ldsrc, c0, nc, ldd, dzoff);
  };
  auto gemm_grid = [&](int M, int Npad){ return dim3(Npad/128, (M+127)/128); };
  const long long WSLOT = (long long)2304*DIMC;

  // prep: mods + 5-bias pack + enc convert (one launch)
  prep_k<<<dim3(657), 256, 0, stream>>>(sst, tstep, modsb,
      a1_qb, a1_kb, a1_vb, a2_kb, a2_vb, bias5, (const float4*)enc, (ushort4*)encb);

  // ---- attn1: fused QKV ----
  ln_mod_k<<<dim3(STOK), 256, 0, stream>>>(hid, modsb, 0, 1, nhb);
  cvtT3(a1_qw, a1_kw, a1_vw, Wbig, DIMC, DIMC, 0, DIMC, 2304, DIMC, WSLOT, 3);
  gemm_bt<6><<<gemm_grid(STOK, 6912), 256, 0, stream>>>(nhb, Wbig, bias5, nullptr, P1,
                                                        nullptr, nullptr, STOK, 6912, DIMC, SD, 6, DIMC, 0);
  rmsqk_k<<<dim3(STOK, 2), 256, 0, stream>>>(P1, P2, a1_nq, a1_nk, fcos, fsin, P4, P5);
  colsum_k<<<dim3(9, 28), 256, 0, stream>>>(P2, kpart);
  ksumred_k<<<dim3(9), 256, 0, stream>>>(kpart, ksum);
  denom_k<<<dim3(STOK), 256, 0, stream>>>(P1, ksum, denom);
  // q (P1) and k (P2) are dead now -> spart may overwrite them
  scores_k<<<dim3(NH, 28), 256, 0, stream>>>(P3, P5, spart);
  scred_k<<<dim3((NH*HDIM*HDIM+255)/256), 256, 0, stream>>>(spart, scorb);
  linout_k<<<dim3(STOK/64, NH), 256, 0, stream>>>(P4, scorb, denom, P1);   // lob -> P1
  dim3 gMN = gemm_grid(STOK, 2304);
  // batch-convert the three DIM x DIM weights: slot0=a1_ow, slot1=a2_qw, slot2=a2_ow
  cvtT3(a1_ow, a2_qw, a2_ow, Wbig, DIMC, DIMC, 0, DIMC, 2304, DIMC, WSLOT, 3);
  // EPI3: x1b(bf16) = hid + g_msa*(lob@ow + ob)   -> P2
  gemm_bt<3><<<gMN, 256, 0, stream>>>(P1, Wbig, a1_ob, nullptr, P2, hid, modsb + 2*DIMC, STOK, DIMC, DIMC, DIMC, 6, DIMC, 0);

  // ---- cross attn ----
  gemm_bt<2><<<gMN, 256, 0, stream>>>(P2, Wbig + WSLOT, a2_qb, nullptr, P3, nullptr, nullptr, STOK, DIMC, DIMC, DIMC, 6, DIMC, 0);
  cvtT3(a2_kw, a2_vw, a2_vw, Wbig, DIMC, DIMC, 0, DIMC, 2304, DIMC, WSLOT, 2);   // slots 0,1 (dead)
  gemm_bt<6><<<gemm_grid(ENCT, 4608), 256, 0, stream>>>(encb, Wbig, bias5 + 3*2304, nullptr, k2b,
                                                        nullptr, nullptr, ENCT, 4608, DIMC, ENCT*DIMC, 6, DIMC, 0);
  rmsnn_k<<<dim3(STOK + ENCT), 256, 0, stream>>>(P3, a2_nq, k2b, a2_nk);
  xattn_k<<<dim3(STOK/64, NH), 256, 0, stream>>>(P3, k2b, v2b, P4);   // crb -> P4
  // EPI8: x2b(bf16) = x1b + crb@ow2 + ob2
  gemm_bt<8><<<gMN, 256, 0, stream>>>(P4, Wbig + 2*WSLOT, a2_ob, nullptr, x2b,
                                      (const float*)(const void*)P2, nullptr, STOK, DIMC, DIMC, DIMC, 6, DIMC, 0);

  // ---- FF ----
  ln_mod_bf_k<<<dim3(STOK), 256, 0, stream>>>(x2b, modsb, 3, 4, nh2b);
  for (int q = 0; q < 2; ++q){                 // ff_inv in 2 column slices of 6720
    int c0 = q*6720;
    cvtT3(ff_inv_w, ff_inv_w, ff_inv_w, Wbig, DIMC, HID2, c0, 6720, 6912, DIMC, 0, 1);
    gemm_bt<1><<<gemm_grid(STOK, 6912), 256, 0, stream>>>(nh2b, Wbig, ff_inv_b + c0, nullptr, y1b + c0,
                                                          nullptr, nullptr, STOK, 6720, DIMC, HID2, 6, DIMC, 0);
  }
  dw_k<<<dim3(224, 14), 256, 0, stream>>>(y1b, ff_dw, ff_db, y2b);
  // y1b dead -> y3pad margins may be zeroed now
  zpad_k<<<dim3(490), 256, 0, stream>>>(y3pad, y3pad + (size_t)(448 + STOK)*DIMC);
  cvtT3(ff_pw, ff_pw, ff_pw, Wbig, HID1, DIMC, 0, DIMC, 2304, HID1, 0, 1);   // point conv weights
  gemm_bt<2><<<gMN, 256, 0, stream>>>(y2b, Wbig, nullptr, nullptr, y3,
                                      nullptr, nullptr, STOK, DIMC, HID1, DIMC, 2, HID1, 0);
  // temporal conv + final residual fused: out = x2 + g_mlp*(y3 + tc)  (one K=6720 GEMM)
  cvtT3(ff_tw, ff_tw + (size_t)DD, ff_tw + (size_t)2*DD, Wbig,
        DIMC, DIMC, 0, DIMC, 2304, 6720, 2240LL, 3);   // Bt [2304][6720], col-sec = W_sec
  gemm_bt<7><<<gMN, 256, 0, stream>>>(y3pad, Wbig, nullptr, out, y3,
                                      (const float*)(const void*)x2b, modsb + 5*DIMC,
                                      STOK, DIMC, 6720, DIMC, 2, DIMC, 1);
}